// Round 1
// baseline (965.716 us; speedup 1.0000x reference)
//
#include <hip/hip_runtime.h>
#include <math.h>

#define NB_   8
#define INCH  512
#define OUTCH 256
#define NHEAD 8
#define DHEAD 32

// ---------------- generic pointwise (1x1) conv ----------------
// out[b,o,p] = sum_i in[b,i,p]*W[o*Ci+i] (+bias[o]) (+res[b,o,p])
// block: 256 threads, each thread -> 4 consecutive p, TO outputs.
template <int TO>
__global__ void pw_conv(const float* __restrict__ in, const float* __restrict__ W,
                        const float* __restrict__ bias, const float* __restrict__ res,
                        float* __restrict__ out, int Ci, int Co, int P) {
    __shared__ float wsh[8 * 512];
    const int b  = blockIdx.z;
    const int o0 = blockIdx.y * TO;
    const int p  = (blockIdx.x * 256 + threadIdx.x) * 4;

    // stage W rows [o0 .. o0+TO) into LDS (contiguous TO*Ci floats)
    for (int t = threadIdx.x; t < TO * Ci; t += 256) wsh[t] = W[(size_t)o0 * Ci + t];
    __syncthreads();

    const float* inb = in + (size_t)b * Ci * P;
    float4 acc[TO];
#pragma unroll
    for (int t = 0; t < TO; ++t) {
        float bv = bias ? bias[o0 + t] : 0.f;
        acc[t] = make_float4(bv, bv, bv, bv);
    }
    for (int i = 0; i < Ci; ++i) {
        const float4 v = *reinterpret_cast<const float4*>(inb + (size_t)i * P + p);
#pragma unroll
        for (int t = 0; t < TO; ++t) {
            const float w = wsh[t * Ci + i];
            acc[t].x += v.x * w; acc[t].y += v.y * w;
            acc[t].z += v.z * w; acc[t].w += v.w * w;
        }
    }
#pragma unroll
    for (int t = 0; t < TO; ++t) {
        const size_t off = ((size_t)b * Co + o0 + t) * P + p;
        float4 r = acc[t];
        if (res) {
            const float4 rv = *reinterpret_cast<const float4*>(res + off);
            r.x += rv.x; r.y += rv.y; r.z += rv.z; r.w += rv.w;
        }
        *reinterpret_cast<float4*>(out + off) = r;
    }
}

// ---------------- bilinear resize (linspace endpoints-inclusive) ----------------
__global__ void resize_bilinear(const float* __restrict__ in, float* __restrict__ out,
                                int C, int ibs, int Hi, int Wi, int Ho, int Wo) {
    const int idx = blockIdx.x * 256 + threadIdx.x;
    const int total = NB_ * C * Ho * Wo;
    if (idx >= total) return;
    const int x = idx % Wo;
    const int y = (idx / Wo) % Ho;
    const int c = (idx / (Wo * Ho)) % C;
    const int b = idx / (Wo * Ho * C);
    const float fy = (float)y * (float)(Hi - 1) / (float)(Ho - 1);
    const float fx = (float)x * (float)(Wi - 1) / (float)(Wo - 1);
    int y0 = (int)floorf(fy); int y1 = min(y0 + 1, Hi - 1); const float wy = fy - (float)y0;
    int x0 = (int)floorf(fx); int x1 = min(x0 + 1, Wi - 1); const float wx = fx - (float)x0;
    const float* pc = in + (size_t)b * ibs + (size_t)c * Hi * Wi;
    const float r0 = pc[y0 * Wi + x0] * (1.f - wx) + pc[y0 * Wi + x1] * wx;
    const float r1 = pc[y1 * Wi + x0] * (1.f - wx) + pc[y1 * Wi + x1] * wx;
    out[idx] = r0 * (1.f - wy) + r1 * wy;
}

// ---------------- BN stats: per-channel scale/shift ----------------
__global__ void bn_stats(const float* __restrict__ in, const float* __restrict__ g,
                         const float* __restrict__ bt, float* __restrict__ scale,
                         float* __restrict__ shift, int C, int HW, float eps) {
    const int c = blockIdx.x;
    float s1 = 0.f, s2 = 0.f;
    for (int b = 0; b < NB_; ++b) {
        const float* p = in + ((size_t)b * C + c) * HW;
        for (int r = threadIdx.x; r < HW; r += 256) {
            const float v = p[r];
            s1 += v; s2 += v * v;
        }
    }
    __shared__ float sh1[256], sh2[256];
    sh1[threadIdx.x] = s1; sh2[threadIdx.x] = s2;
    __syncthreads();
    for (int s = 128; s > 0; s >>= 1) {
        if (threadIdx.x < s) { sh1[threadIdx.x] += sh1[threadIdx.x + s]; sh2[threadIdx.x] += sh2[threadIdx.x + s]; }
        __syncthreads();
    }
    if (threadIdx.x == 0) {
        const float N = (float)(NB_ * HW);
        const float m = sh1[0] / N;
        const float var = sh2[0] / N - m * m;
        const float sc = g[c] * rsqrtf(var + eps);
        scale[c] = sc;
        shift[c] = bt[c] - m * sc;
    }
}

// ---------------- fused (optional BN) + depthwise 3x3, pad=1 ----------------
__global__ void bn_dw3(const float* __restrict__ in, const float* __restrict__ scale,
                       const float* __restrict__ shift, const float* __restrict__ dw,
                       float* __restrict__ out, int C, int H, int W) {
    const int idx = blockIdx.x * 256 + threadIdx.x;
    const int total = NB_ * C * H * W;
    if (idx >= total) return;
    const int x = idx % W;
    const int y = (idx / W) % H;
    const int c = (idx / (W * H)) % C;
    const float sc = scale ? scale[c] : 1.f;
    const float sh = shift ? shift[c] : 0.f;
    const float* p = in + (size_t)(idx - (y * W + x)) ; // base of this (b,c) plane offset by 0
    const float* w = dw + c * 9;
    float acc = 0.f;
#pragma unroll
    for (int dy = 0; dy < 3; ++dy) {
        const int yy = y + dy - 1;
        if (yy < 0 || yy >= H) continue;
#pragma unroll
        for (int dx = 0; dx < 3; ++dx) {
            const int xx = x + dx - 1;
            if (xx < 0 || xx >= W) continue;
            acc += w[dy * 3 + dx] * (p[yy * W + xx] * sc + sh);
        }
    }
    out[idx] = acc;
}

// ---------------- LN (optional) + split heads: conv layout -> [b,h,j,d] ----------------
__global__ void ln_split(const float* __restrict__ in, const float* __restrict__ g,
                         const float* __restrict__ bt, float* __restrict__ out,
                         int HW, int applyLN, float eps) {
    const int row = blockIdx.x * 8 + (threadIdx.x >> 5);
    const int d = threadIdx.x & 31;
    const int j = row % HW;
    const int h = (row / HW) % NHEAD;
    const int b = row / (HW * NHEAD);
    float v = in[((size_t)b * OUTCH + d * NHEAD + h) * HW + j];
    if (applyLN) {
        float s1 = v, s2 = v * v;
#pragma unroll
        for (int o = 16; o >= 1; o >>= 1) {
            s1 += __shfl_xor(s1, o, 32);
            s2 += __shfl_xor(s2, o, 32);
        }
        const float m = s1 * (1.f / 32.f);
        const float var = s2 * (1.f / 32.f) - m * m;
        v = (v - m) * rsqrtf(var + eps) * g[h * 32 + d] + bt[h * 32 + d];
    }
    out[((size_t)(b * NHEAD + h) * HW + j) * 32 + d] = v;
}

// ---------------- M[bh,e,d] = sum_j kn[bh,j,e]*vh[bh,j,d] ----------------
__global__ void kv_outer(const float* __restrict__ kn, const float* __restrict__ vh,
                         float* __restrict__ M) {
    __shared__ float vs[256][32];
    const int bh = blockIdx.x;
    const float* kp = kn + (size_t)bh * 256 * 32;
    const float* vp = vh + (size_t)bh * 256 * 32;
    const int tid = threadIdx.y * 32 + threadIdx.x;
    for (int t = tid; t < 256 * 32; t += 1024) vs[t >> 5][t & 31] = vp[t];
    __syncthreads();
    const int e = threadIdx.x, dd = threadIdx.y;
    float acc = 0.f;
    for (int j = 0; j < 256; ++j) acc += kp[j * 32 + e] * vs[j][dd];
    M[((size_t)bh * 32 + e) * 32 + dd] = acc;
}

// ---------------- Bv[bh,qb,d] = sum_j relbias[h,qb,j]*vh[bh,j,d] ----------------
__global__ void bias_v(const float* __restrict__ rel, const float* __restrict__ vh,
                       float* __restrict__ Bv) {
    const int gid = blockIdx.x * 8 + (threadIdx.x >> 5);
    const int d = threadIdx.x & 31;
    const int qb = gid % 256;
    const int h = (gid / 256) % NHEAD;
    const int b = gid / (256 * NHEAD);
    const int qy = qb >> 4, qx = qb & 15;
    const float* vp = vh + (size_t)(b * NHEAD + h) * 256 * 32;
    float acc = 0.f;
    for (int j = 0; j < 256; ++j) {
        const int ky = j >> 4, kx = j & 15;
        const float bias = rel[((qy - ky + 15) * 31 + (qx - kx + 15)) * NHEAD + h];
        acc += bias * vp[j * 32 + d];
    }
    Bv[((size_t)(b * NHEAD + h) * 256 + qb) * 32 + d] = acc;
}

// ---------------- attention out: o = (LN(q) @ M + Bv)/32, conv layout ----------------
__global__ void attn_out(const float* __restrict__ q, const float* __restrict__ gq,
                         const float* __restrict__ bq, const float* __restrict__ M,
                         const float* __restrict__ Bv, float* __restrict__ o) {
    const int gid = blockIdx.x * 256 + threadIdx.x;
    const int i = gid % 4096;
    const int h = (gid / 4096) % NHEAD;
    const int b = gid / (4096 * NHEAD);
    const int y = i >> 6, x = i & 63;
    const int qb = (y >> 2) * 16 + (x >> 2);

    const float* qp = q + (size_t)b * OUTCH * 4096 + h * 4096 + i;
    float qv[32];
    float s1 = 0.f, s2 = 0.f;
#pragma unroll
    for (int d = 0; d < 32; ++d) {
        const float v = qp[(size_t)d * NHEAD * 4096];
        qv[d] = v; s1 += v; s2 += v * v;
    }
    const float m = s1 * (1.f / 32.f);
    const float var = s2 * (1.f / 32.f) - m * m;
    const float rs = rsqrtf(var + 1e-6f);
#pragma unroll
    for (int d = 0; d < 32; ++d)
        qv[d] = (qv[d] - m) * rs * gq[h * 32 + d] + bq[h * 32 + d];

    const float* Mp = M + (size_t)(b * NHEAD + h) * 32 * 32;
    const float* Bp = Bv + ((size_t)(b * NHEAD + h) * 256 + qb) * 32;
    float acc[32];
#pragma unroll
    for (int d = 0; d < 32; ++d) acc[d] = Bp[d];
#pragma unroll
    for (int e = 0; e < 32; ++e) {
        const float qe = qv[e];
#pragma unroll
        for (int d = 0; d < 32; ++d) acc[d] += qe * Mp[e * 32 + d];
    }
    float* op = o + (size_t)b * OUTCH * 4096 + h * 4096 + i;
#pragma unroll
    for (int d = 0; d < 32; ++d) op[(size_t)d * NHEAD * 4096] = acc[d] * (1.f / 32.f);
}

// ---------------- BN + ReLU elementwise ----------------
__global__ void bn_relu(const float* __restrict__ in, const float* __restrict__ scale,
                        const float* __restrict__ shift, float* __restrict__ out,
                        int C, int HW) {
    const int idx = blockIdx.x * 256 + threadIdx.x;
    const int total = NB_ * C * HW;
    if (idx >= total) return;
    const int c = (idx / HW) % C;
    const float v = in[idx] * scale[c] + shift[c];
    out[idx] = v > 0.f ? v : 0.f;
}

extern "C" void kernel_launch(void* const* d_in, const int* in_sizes, int n_in,
                              void* d_out, int out_size, void* d_ws, size_t ws_size,
                              hipStream_t stream) {
    const float* x1        = (const float*)d_in[0];
    const float* x2        = (const float*)d_in[1];
    const float* conv_ch_w = (const float*)d_in[2];
    const float* conv_ch_b = (const float*)d_in[3];
    const float* norm_l_g  = (const float*)d_in[4];
    const float* norm_l_b  = (const float*)d_in[5];
    const float* norm_h_g  = (const float*)d_in[6];
    const float* norm_h_b  = (const float*)d_in[7];
    const float* to_kv_dw  = (const float*)d_in[8];
    const float* to_kv_pw  = (const float*)d_in[9];
    const float* to_q_dw   = (const float*)d_in[10];
    const float* to_q_pw   = (const float*)d_in[11];
    const float* to_out_dw = (const float*)d_in[12];
    const float* to_out_pw = (const float*)d_in[13];
    const float* rel_table = (const float*)d_in[14];
    const float* normq_g   = (const float*)d_in[15];
    const float* normq_b   = (const float*)d_in[16];
    const float* normk_g   = (const float*)d_in[17];
    const float* normk_b   = (const float*)d_in[18];
    const float* norm2_g   = (const float*)d_in[19];
    const float* norm2_b   = (const float*)d_in[20];
    const float* mlp_w     = (const float*)d_in[21];
    float* Dout = (float*)d_out;

    float* ws = (float*)d_ws;
    const size_t NBIG = (size_t)NB_ * OUTCH * 4096; // 8388608 floats
    float* RES = ws;
    float* A   = ws + NBIG;
    float* Bb  = ws + 2 * NBIG;
    float* sm  = ws + 3 * NBIG;
    float* scale1 = sm;            float* shift1 = sm + 512;
    float* scale2 = sm + 1024;     float* shift2 = sm + 1280;
    float* scale3 = sm + 1536;     float* shift3 = sm + 1792;
    float* k16 = sm + 2048;
    float* v16 = k16 + 524288;
    float* kn  = v16 + 524288;
    float* vh  = kn  + 524288;
    float* Mm  = vh  + 524288;
    float* Bv  = Mm  + 65536;

    // 1. x1c = conv1x1(x1)+b -> A  (as [8,256,1024])
    pw_conv<8><<<dim3(1, 32, 8), 256, 0, stream>>>(x1, conv_ch_w, conv_ch_b, nullptr, A, 512, 256, 1024);
    // 2. residue = resize(x1c, 64,64) -> RES
    resize_bilinear<<<32768, 256, 0, stream>>>(A, RES, 256, 256 * 1024, 32, 32, 64, 64);
    // 3. BN stats x1
    bn_stats<<<512, 256, 0, stream>>>(x1, norm_l_g, norm_l_b, scale1, shift1, 512, 1024, 1e-5f);
    // 4. kv_dw = dw3(BN(x1)) -> A (4M floats)
    bn_dw3<<<16384, 256, 0, stream>>>(x1, scale1, shift1, to_kv_dw, A, 512, 32, 32);
    // 5. kv = pw(kv_dw) -> Bb (as [8,512,1024])
    pw_conv<8><<<dim3(1, 64, 8), 256, 0, stream>>>(A, to_kv_pw, nullptr, nullptr, Bb, 512, 512, 1024);
    // 6. k16, v16 = resize to 16x16
    resize_bilinear<<<2048, 256, 0, stream>>>(Bb, k16, 256, 512 * 1024, 32, 32, 16, 16);
    resize_bilinear<<<2048, 256, 0, stream>>>(Bb + 256 * 1024, v16, 256, 512 * 1024, 32, 32, 16, 16);
    // 7. BN stats x2
    bn_stats<<<256, 256, 0, stream>>>(x2, norm_h_g, norm_h_b, scale2, shift2, 256, 4096, 1e-5f);
    // 8. q_dw = dw3(BN(x2)) -> A (8M)
    bn_dw3<<<32768, 256, 0, stream>>>(x2, scale2, shift2, to_q_dw, A, 256, 64, 64);
    // 9. q = pw(q_dw) -> Bb (8M, conv layout [8,256,4096])
    pw_conv<8><<<dim3(4, 32, 8), 256, 0, stream>>>(A, to_q_pw, nullptr, nullptr, Bb, 256, 256, 4096);
    // 10. kn = LN(split(k16)); vh = split(v16)
    ln_split<<<2048, 256, 0, stream>>>(k16, normk_g, normk_b, kn, 256, 1, 1e-6f);
    ln_split<<<2048, 256, 0, stream>>>(v16, nullptr, nullptr, vh, 256, 0, 0.f);
    // 11. M = k^T v  (per b,h: 32x32)
    kv_outer<<<64, dim3(32, 32), 0, stream>>>(kn, vh, Mm);
    // 12. Bv = bias @ v (per b,h: 256x32)
    bias_v<<<2048, 256, 0, stream>>>(rel_table, vh, Bv);
    // 13. o = (LN(q) @ M + Bv)/32 -> A (conv layout)
    attn_out<<<1024, 256, 0, stream>>>(Bb, normq_g, normq_b, Mm, Bv, A);
    // 14. out_dw = dw3(o) -> d_out (scratch)
    bn_dw3<<<32768, 256, 0, stream>>>(A, nullptr, nullptr, to_out_dw, Dout, 256, 64, 64);
    // 15. o2 = pw(out_dw) + residue -> A   (this is res2)
    pw_conv<8><<<dim3(4, 32, 8), 256, 0, stream>>>(Dout, to_out_pw, nullptr, RES, A, 256, 256, 4096);
    // 16. BN stats o2
    bn_stats<<<256, 256, 0, stream>>>(A, norm2_g, norm2_b, scale3, shift3, 256, 4096, 1e-5f);
    // 17. r = relu(BN(o2)) -> Bb
    bn_relu<<<32768, 256, 0, stream>>>(A, scale3, shift3, Bb, 256, 4096);
    // 18. out = pw(r, mlp_w) + res2 -> d_out
    pw_conv<8><<<dim3(4, 32, 8), 256, 0, stream>>>(Bb, mlp_w, nullptr, A, Dout, 256, 256, 4096);
}

// Round 2
// 738.279 us; speedup vs baseline: 1.3081x; 1.3081x over previous
//
#include <hip/hip_runtime.h>
#include <math.h>

#define NB_   8
#define INCH  512
#define OUTCH 256
#define NHEAD 8
#define DHEAD 32

// ---------------- generic pointwise (1x1) conv, unroll-4, TO outputs/thread ----------------
template <int TO>
__global__ __launch_bounds__(256, 4)
void pw_conv(const float* __restrict__ in, const float* __restrict__ W,
             const float* __restrict__ bias, const float* __restrict__ res,
             float* __restrict__ out, int Ci, int Co, int P) {
    __shared__ float wsh[TO * 512];
    const int b  = blockIdx.z;
    const int o0 = blockIdx.y * TO;
    const int p  = (blockIdx.x * 256 + threadIdx.x) * 4;

    for (int t = threadIdx.x; t < TO * Ci; t += 256) wsh[t] = W[(size_t)o0 * Ci + t];
    __syncthreads();

    const float* inb = in + (size_t)b * Ci * P + p;
    float4 acc[TO];
#pragma unroll
    for (int t = 0; t < TO; ++t) {
        float bv = bias ? bias[o0 + t] : 0.f;
        acc[t] = make_float4(bv, bv, bv, bv);
    }
    for (int i = 0; i < Ci; i += 4) {
        const float4 v0 = *reinterpret_cast<const float4*>(inb + (size_t)(i + 0) * P);
        const float4 v1 = *reinterpret_cast<const float4*>(inb + (size_t)(i + 1) * P);
        const float4 v2 = *reinterpret_cast<const float4*>(inb + (size_t)(i + 2) * P);
        const float4 v3 = *reinterpret_cast<const float4*>(inb + (size_t)(i + 3) * P);
#pragma unroll
        for (int t = 0; t < TO; ++t) {
            const float* wr = &wsh[t * Ci + i];
            const float w0 = wr[0], w1 = wr[1], w2 = wr[2], w3 = wr[3];
            acc[t].x += v0.x * w0 + v1.x * w1 + v2.x * w2 + v3.x * w3;
            acc[t].y += v0.y * w0 + v1.y * w1 + v2.y * w2 + v3.y * w3;
            acc[t].z += v0.z * w0 + v1.z * w1 + v2.z * w2 + v3.z * w3;
            acc[t].w += v0.w * w0 + v1.w * w1 + v2.w * w2 + v3.w * w3;
        }
    }
#pragma unroll
    for (int t = 0; t < TO; ++t) {
        const size_t off = ((size_t)b * Co + o0 + t) * P + p;
        float4 r = acc[t];
        if (res) {
            const float4 rv = *reinterpret_cast<const float4*>(res + off);
            r.x += rv.x; r.y += rv.y; r.z += rv.z; r.w += rv.w;
        }
        *reinterpret_cast<float4*>(out + off) = r;
    }
}

// ---------------- split-K pointwise conv: writes partial sums ----------------
// grid.x = KS (P fits in one 256-thread*float4 chunk), grid.y = Co/TO, grid.z = B
template <int TO, int KS>
__global__ __launch_bounds__(256, 4)
void pw_ks(const float* __restrict__ in, const float* __restrict__ W,
           float* __restrict__ partial, int Ci, int Co, int P) {
    __shared__ float wsh[TO * 256];
    const int ks = blockIdx.x % KS;
    const int pc = blockIdx.x / KS;
    const int b  = blockIdx.z;
    const int o0 = blockIdx.y * TO;
    const int p  = (pc * 256 + threadIdx.x) * 4;
    const int ciN = Ci / KS;
    const int ci0 = ks * ciN;

    for (int t = threadIdx.x; t < TO * ciN; t += 256)
        wsh[t] = W[(size_t)(o0 + t / ciN) * Ci + ci0 + (t % ciN)];
    __syncthreads();

    const float* inb = in + (size_t)b * Ci * P + (size_t)ci0 * P + p;
    float4 acc[TO];
#pragma unroll
    for (int t = 0; t < TO; ++t) acc[t] = make_float4(0.f, 0.f, 0.f, 0.f);

    for (int i = 0; i < ciN; i += 4) {
        const float4 v0 = *reinterpret_cast<const float4*>(inb + (size_t)(i + 0) * P);
        const float4 v1 = *reinterpret_cast<const float4*>(inb + (size_t)(i + 1) * P);
        const float4 v2 = *reinterpret_cast<const float4*>(inb + (size_t)(i + 2) * P);
        const float4 v3 = *reinterpret_cast<const float4*>(inb + (size_t)(i + 3) * P);
#pragma unroll
        for (int t = 0; t < TO; ++t) {
            const float* wr = &wsh[t * ciN + i];
            const float w0 = wr[0], w1 = wr[1], w2 = wr[2], w3 = wr[3];
            acc[t].x += v0.x * w0 + v1.x * w1 + v2.x * w2 + v3.x * w3;
            acc[t].y += v0.y * w0 + v1.y * w1 + v2.y * w2 + v3.y * w3;
            acc[t].z += v0.z * w0 + v1.z * w1 + v2.z * w2 + v3.z * w3;
            acc[t].w += v0.w * w0 + v1.w * w1 + v2.w * w2 + v3.w * w3;
        }
    }
#pragma unroll
    for (int t = 0; t < TO; ++t) {
        const size_t off = (((size_t)ks * NB_ + b) * Co + o0 + t) * P + p;
        *reinterpret_cast<float4*>(partial + off) = acc[t];
    }
}

// ---------------- reduce KS partial buffers (+optional bias) ----------------
__global__ void reduce_partials(const float* __restrict__ part, const float* __restrict__ bias,
                                float* __restrict__ out, int KS, int Co, int P, int n4) {
    const int idx = blockIdx.x * 256 + threadIdx.x;
    if (idx >= n4) return;
    const size_t e = (size_t)idx * 4;
    const size_t n = (size_t)NB_ * Co * P;
    float4 s = *reinterpret_cast<const float4*>(part + e);
    for (int ks = 1; ks < KS; ++ks) {
        const float4 v = *reinterpret_cast<const float4*>(part + ks * n + e);
        s.x += v.x; s.y += v.y; s.z += v.z; s.w += v.w;
    }
    if (bias) {
        const float bv = bias[(e / P) % Co];
        s.x += bv; s.y += bv; s.z += bv; s.w += bv;
    }
    *reinterpret_cast<float4*>(out + e) = s;
}

// ---------------- bilinear resize (linspace endpoints-inclusive) ----------------
__global__ void resize_bilinear(const float* __restrict__ in, float* __restrict__ out,
                                int C, int ibs, int Hi, int Wi, int Ho, int Wo) {
    const int idx = blockIdx.x * 256 + threadIdx.x;
    const int total = NB_ * C * Ho * Wo;
    if (idx >= total) return;
    const int x = idx % Wo;
    const int y = (idx / Wo) % Ho;
    const int c = (idx / (Wo * Ho)) % C;
    const int b = idx / (Wo * Ho * C);
    const float fy = (float)y * (float)(Hi - 1) / (float)(Ho - 1);
    const float fx = (float)x * (float)(Wi - 1) / (float)(Wo - 1);
    int y0 = (int)floorf(fy); int y1 = min(y0 + 1, Hi - 1); const float wy = fy - (float)y0;
    int x0 = (int)floorf(fx); int x1 = min(x0 + 1, Wi - 1); const float wx = fx - (float)x0;
    const float* pc = in + (size_t)b * ibs + (size_t)c * Hi * Wi;
    const float r0 = pc[y0 * Wi + x0] * (1.f - wx) + pc[y0 * Wi + x1] * wx;
    const float r1 = pc[y1 * Wi + x0] * (1.f - wx) + pc[y1 * Wi + x1] * wx;
    out[idx] = r0 * (1.f - wy) + r1 * wy;
}

// ---------------- BN stats: per-channel scale/shift ----------------
__global__ void bn_stats(const float* __restrict__ in, const float* __restrict__ g,
                         const float* __restrict__ bt, float* __restrict__ scale,
                         float* __restrict__ shift, int C, int HW, float eps) {
    const int c = blockIdx.x;
    float s1 = 0.f, s2 = 0.f;
    for (int b = 0; b < NB_; ++b) {
        const float* p = in + ((size_t)b * C + c) * HW;
        for (int r = threadIdx.x; r < HW; r += 256) {
            const float v = p[r];
            s1 += v; s2 += v * v;
        }
    }
    __shared__ float sh1[256], sh2[256];
    sh1[threadIdx.x] = s1; sh2[threadIdx.x] = s2;
    __syncthreads();
    for (int s = 128; s > 0; s >>= 1) {
        if (threadIdx.x < s) { sh1[threadIdx.x] += sh1[threadIdx.x + s]; sh2[threadIdx.x] += sh2[threadIdx.x + s]; }
        __syncthreads();
    }
    if (threadIdx.x == 0) {
        const float N = (float)(NB_ * HW);
        const float m = sh1[0] / N;
        const float var = sh2[0] / N - m * m;
        const float sc = g[c] * rsqrtf(var + eps);
        scale[c] = sc;
        shift[c] = bt[c] - m * sc;
    }
}

// ---------------- fused (optional BN) + depthwise 3x3, pad=1 ----------------
__global__ void bn_dw3(const float* __restrict__ in, const float* __restrict__ scale,
                       const float* __restrict__ shift, const float* __restrict__ dw,
                       float* __restrict__ out, int C, int H, int W) {
    const int idx = blockIdx.x * 256 + threadIdx.x;
    const int total = NB_ * C * H * W;
    if (idx >= total) return;
    const int x = idx % W;
    const int y = (idx / W) % H;
    const int c = (idx / (W * H)) % C;
    const float sc = scale ? scale[c] : 1.f;
    const float sh = shift ? shift[c] : 0.f;
    const float* p = in + (size_t)(idx - (y * W + x));
    const float* w = dw + c * 9;
    float acc = 0.f;
#pragma unroll
    for (int dy = 0; dy < 3; ++dy) {
        const int yy = y + dy - 1;
        if (yy < 0 || yy >= H) continue;
#pragma unroll
        for (int dx = 0; dx < 3; ++dx) {
            const int xx = x + dx - 1;
            if (xx < 0 || xx >= W) continue;
            acc += w[dy * 3 + dx] * (p[yy * W + xx] * sc + sh);
        }
    }
    out[idx] = acc;
}

// ---------------- LN (optional) + split heads: conv layout -> [b,h,j,d] ----------------
__global__ void ln_split(const float* __restrict__ in, const float* __restrict__ g,
                         const float* __restrict__ bt, float* __restrict__ out,
                         int HW, int applyLN, float eps) {
    const int row = blockIdx.x * 8 + (threadIdx.x >> 5);
    const int d = threadIdx.x & 31;
    const int j = row % HW;
    const int h = (row / HW) % NHEAD;
    const int b = row / (HW * NHEAD);
    float v = in[((size_t)b * OUTCH + d * NHEAD + h) * HW + j];
    if (applyLN) {
        float s1 = v, s2 = v * v;
#pragma unroll
        for (int o = 16; o >= 1; o >>= 1) {
            s1 += __shfl_xor(s1, o, 32);
            s2 += __shfl_xor(s2, o, 32);
        }
        const float m = s1 * (1.f / 32.f);
        const float var = s2 * (1.f / 32.f) - m * m;
        v = (v - m) * rsqrtf(var + eps) * g[h * 32 + d] + bt[h * 32 + d];
    }
    out[((size_t)(b * NHEAD + h) * HW + j) * 32 + d] = v;
}

// ---------------- M[bh,e,d] = sum_j kn[bh,j,e]*vh[bh,j,d] ----------------
__global__ void kv_outer(const float* __restrict__ kn, const float* __restrict__ vh,
                         float* __restrict__ M) {
    __shared__ float vs[256][32];
    const int bh = blockIdx.x;
    const float* kp = kn + (size_t)bh * 256 * 32;
    const float* vp = vh + (size_t)bh * 256 * 32;
    const int tid = threadIdx.y * 32 + threadIdx.x;
    for (int t = tid; t < 256 * 32; t += 1024) vs[t >> 5][t & 31] = vp[t];
    __syncthreads();
    const int e = threadIdx.x, dd = threadIdx.y;
    float acc = 0.f;
    for (int j = 0; j < 256; ++j) acc += kp[j * 32 + e] * vs[j][dd];
    M[((size_t)bh * 32 + e) * 32 + dd] = acc;
}

// ---------------- Bv[bh,qb,d] = sum_j relbias[h,qb,j]*vh[bh,j,d] ----------------
__global__ void bias_v(const float* __restrict__ rel, const float* __restrict__ vh,
                       float* __restrict__ Bv) {
    const int gid = blockIdx.x * 8 + (threadIdx.x >> 5);
    const int d = threadIdx.x & 31;
    const int qb = gid % 256;
    const int h = (gid / 256) % NHEAD;
    const int b = gid / (256 * NHEAD);
    const int qy = qb >> 4, qx = qb & 15;
    const float* vp = vh + (size_t)(b * NHEAD + h) * 256 * 32;
    float acc = 0.f;
    for (int j = 0; j < 256; ++j) {
        const int ky = j >> 4, kx = j & 15;
        const float bias = rel[((qy - ky + 15) * 31 + (qx - kx + 15)) * NHEAD + h];
        acc += bias * vp[j * 32 + d];
    }
    Bv[((size_t)(b * NHEAD + h) * 256 + qb) * 32 + d] = acc;
}

// ---------------- attention out: o = (LN(q) @ M + Bv)/32, conv layout ----------------
__global__ void attn_out(const float* __restrict__ q, const float* __restrict__ gq,
                         const float* __restrict__ bq, const float* __restrict__ M,
                         const float* __restrict__ Bv, float* __restrict__ o) {
    const int gid = blockIdx.x * 256 + threadIdx.x;
    const int i = gid % 4096;
    const int h = (gid / 4096) % NHEAD;
    const int b = gid / (4096 * NHEAD);
    const int y = i >> 6, x = i & 63;
    const int qb = (y >> 2) * 16 + (x >> 2);

    const float* qp = q + (size_t)b * OUTCH * 4096 + h * 4096 + i;
    float qv[32];
    float s1 = 0.f, s2 = 0.f;
#pragma unroll
    for (int d = 0; d < 32; ++d) {
        const float v = qp[(size_t)d * NHEAD * 4096];
        qv[d] = v; s1 += v; s2 += v * v;
    }
    const float m = s1 * (1.f / 32.f);
    const float var = s2 * (1.f / 32.f) - m * m;
    const float rs = rsqrtf(var + 1e-6f);
#pragma unroll
    for (int d = 0; d < 32; ++d)
        qv[d] = (qv[d] - m) * rs * gq[h * 32 + d] + bq[h * 32 + d];

    const float* Mp = M + (size_t)(b * NHEAD + h) * 32 * 32;
    const float* Bp = Bv + ((size_t)(b * NHEAD + h) * 256 + qb) * 32;
    float acc[32];
#pragma unroll
    for (int d = 0; d < 32; ++d) acc[d] = Bp[d];
#pragma unroll
    for (int e = 0; e < 32; ++e) {
        const float qe = qv[e];
#pragma unroll
        for (int d = 0; d < 32; ++d) acc[d] += qe * Mp[e * 32 + d];
    }
    float* op = o + (size_t)b * OUTCH * 4096 + h * 4096 + i;
#pragma unroll
    for (int d = 0; d < 32; ++d) op[(size_t)d * NHEAD * 4096] = acc[d] * (1.f / 32.f);
}

// ---------------- BN + ReLU elementwise ----------------
__global__ void bn_relu(const float* __restrict__ in, const float* __restrict__ scale,
                        const float* __restrict__ shift, float* __restrict__ out,
                        int C, int HW) {
    const int idx = blockIdx.x * 256 + threadIdx.x;
    const int total = NB_ * C * HW;
    if (idx >= total) return;
    const int c = (idx / HW) % C;
    const float v = in[idx] * scale[c] + shift[c];
    out[idx] = v > 0.f ? v : 0.f;
}

extern "C" void kernel_launch(void* const* d_in, const int* in_sizes, int n_in,
                              void* d_out, int out_size, void* d_ws, size_t ws_size,
                              hipStream_t stream) {
    const float* x1        = (const float*)d_in[0];
    const float* x2        = (const float*)d_in[1];
    const float* conv_ch_w = (const float*)d_in[2];
    const float* conv_ch_b = (const float*)d_in[3];
    const float* norm_l_g  = (const float*)d_in[4];
    const float* norm_l_b  = (const float*)d_in[5];
    const float* norm_h_g  = (const float*)d_in[6];
    const float* norm_h_b  = (const float*)d_in[7];
    const float* to_kv_dw  = (const float*)d_in[8];
    const float* to_kv_pw  = (const float*)d_in[9];
    const float* to_q_dw   = (const float*)d_in[10];
    const float* to_q_pw   = (const float*)d_in[11];
    const float* to_out_dw = (const float*)d_in[12];
    const float* to_out_pw = (const float*)d_in[13];
    const float* rel_table = (const float*)d_in[14];
    const float* normq_g   = (const float*)d_in[15];
    const float* normq_b   = (const float*)d_in[16];
    const float* normk_g   = (const float*)d_in[17];
    const float* normk_b   = (const float*)d_in[18];
    const float* norm2_g   = (const float*)d_in[19];
    const float* norm2_b   = (const float*)d_in[20];
    const float* mlp_w     = (const float*)d_in[21];
    float* Dout = (float*)d_out;

    float* ws = (float*)d_ws;
    const size_t NBIG = (size_t)NB_ * OUTCH * 4096; // 8388608 floats (32 MB)
    float* RES = ws;
    float* A   = ws + NBIG;
    float* Bb  = ws + 2 * NBIG;
    float* sm  = ws + 3 * NBIG;
    float* scale1 = sm;            float* shift1 = sm + 512;
    float* scale2 = sm + 1024;     float* shift2 = sm + 1280;
    float* scale3 = sm + 1536;     float* shift3 = sm + 1792;
    float* k16 = sm + 2048;
    float* v16 = k16 + 524288;
    float* kn  = v16 + 524288;
    float* vh  = kn  + 524288;
    float* Mm  = vh  + 524288;
    float* Bv  = Mm  + 65536;

    float* kv_dw = A;                 // 4 M floats (16 MB) at A[0:16MB]
    float* kv    = A + 4 * 1048576;   // 4 M floats (16 MB) at A[16:32MB]

    // 1. x1c = conv1x1(x1)+b : split-K=4 partials -> Bb, reduce -> A
    pw_ks<8, 4><<<dim3(4, 32, 8), 256, 0, stream>>>(x1, conv_ch_w, Bb, 512, 256, 1024);
    reduce_partials<<<2048, 256, 0, stream>>>(Bb, conv_ch_b, A, 4, 256, 1024, 524288);
    // 2. residue = resize(x1c, 64,64) -> RES
    resize_bilinear<<<32768, 256, 0, stream>>>(A, RES, 256, 256 * 1024, 32, 32, 64, 64);
    // 3. BN stats x1
    bn_stats<<<512, 256, 0, stream>>>(x1, norm_l_g, norm_l_b, scale1, shift1, 512, 1024, 1e-5f);
    // 4. kv_dw = dw3(BN(x1)) -> A[0:16MB]  (x1c in A[0:8MB] is dead after step 2)
    bn_dw3<<<16384, 256, 0, stream>>>(x1, scale1, shift1, to_kv_dw, kv_dw, 512, 32, 32);
    // 5. kv = pw(kv_dw) : split-K=2 partials -> Bb, reduce -> A[16:32MB]
    pw_ks<8, 2><<<dim3(2, 64, 8), 256, 0, stream>>>(kv_dw, to_kv_pw, Bb, 512, 512, 1024);
    reduce_partials<<<4096, 256, 0, stream>>>(Bb, nullptr, kv, 2, 512, 1024, 1048576);
    // 6. k16, v16 = resize to 16x16
    resize_bilinear<<<2048, 256, 0, stream>>>(kv, k16, 256, 512 * 1024, 32, 32, 16, 16);
    resize_bilinear<<<2048, 256, 0, stream>>>(kv + 256 * 1024, v16, 256, 512 * 1024, 32, 32, 16, 16);
    // 7. BN stats x2
    bn_stats<<<256, 256, 0, stream>>>(x2, norm_h_g, norm_h_b, scale2, shift2, 256, 4096, 1e-5f);
    // 8. q_dw = dw3(BN(x2)) -> Bb (32 MB)
    bn_dw3<<<32768, 256, 0, stream>>>(x2, scale2, shift2, to_q_dw, Bb, 256, 64, 64);
    // 9. q = pw(q_dw) -> A (32 MB, conv layout [8,256,4096])
    pw_conv<8><<<dim3(4, 32, 8), 256, 0, stream>>>(Bb, to_q_pw, nullptr, nullptr, A, 256, 256, 4096);
    // 10. kn = LN(split(k16)); vh = split(v16)
    ln_split<<<2048, 256, 0, stream>>>(k16, normk_g, normk_b, kn, 256, 1, 1e-6f);
    ln_split<<<2048, 256, 0, stream>>>(v16, nullptr, nullptr, vh, 256, 0, 0.f);
    // 11. M = k^T v  (per b,h: 32x32)
    kv_outer<<<64, dim3(32, 32), 0, stream>>>(kn, vh, Mm);
    // 12. Bv = bias @ v (per b,h: 256x32)
    bias_v<<<2048, 256, 0, stream>>>(rel_table, vh, Bv);
    // 13. o = (LN(q) @ M + Bv)/32 -> Bb (conv layout)
    attn_out<<<1024, 256, 0, stream>>>(A, normq_g, normq_b, Mm, Bv, Bb);
    // 14. out_dw = dw3(o) -> d_out (scratch)
    bn_dw3<<<32768, 256, 0, stream>>>(Bb, nullptr, nullptr, to_out_dw, Dout, 256, 64, 64);
    // 15. o2 = pw(out_dw) + residue -> A   (this is res2)
    pw_conv<8><<<dim3(4, 32, 8), 256, 0, stream>>>(Dout, to_out_pw, nullptr, RES, A, 256, 256, 4096);
    // 16. BN stats o2
    bn_stats<<<256, 256, 0, stream>>>(A, norm2_g, norm2_b, scale3, shift3, 256, 4096, 1e-5f);
    // 17. r = relu(BN(o2)) -> Bb
    bn_relu<<<32768, 256, 0, stream>>>(A, scale3, shift3, Bb, 256, 4096);
    // 18. out = pw(r, mlp_w) + res2 -> d_out
    pw_conv<8><<<dim3(4, 32, 8), 256, 0, stream>>>(Bb, mlp_w, nullptr, A, Dout, 256, 256, 4096);
}

// Round 3
// 734.718 us; speedup vs baseline: 1.3144x; 1.0048x over previous
//
#include <hip/hip_runtime.h>
#include <math.h>

#define NB_   8
#define INCH  512
#define OUTCH 256
#define NHEAD 8
#define DHEAD 32

// ---------------- pointwise (1x1) conv, TO outputs/thread, reg-prefetch ----------------
// Only used with Ci<=256 (wsh sized for it). grid: (P/1024, Co/TO, B)
template <int TO>
__global__ __launch_bounds__(256, 2)
void pw_conv(const float* __restrict__ in, const float* __restrict__ W,
             const float* __restrict__ bias, const float* __restrict__ res,
             float* __restrict__ out, int Ci, int Co, int P) {
    __shared__ float wsh[TO * 256];
    const int b  = blockIdx.z;
    const int o0 = blockIdx.y * TO;
    const int p  = (blockIdx.x * 256 + threadIdx.x) * 4;

    for (int t = threadIdx.x; t < TO * Ci; t += 256) wsh[t] = W[(size_t)o0 * Ci + t];
    __syncthreads();

    const float* inb = in + (size_t)b * Ci * P + p;
    float4 acc[TO];
#pragma unroll
    for (int t = 0; t < TO; ++t) {
        float bv = bias ? bias[o0 + t] : 0.f;
        acc[t] = make_float4(bv, bv, bv, bv);
    }

    auto fmab = [&](int i, const float4 v0, const float4 v1, const float4 v2, const float4 v3) {
#pragma unroll
        for (int t = 0; t < TO; ++t) {
            const float* wr = &wsh[t * Ci + i];
            const float w0 = wr[0], w1 = wr[1], w2 = wr[2], w3 = wr[3];
            acc[t].x += v0.x * w0 + v1.x * w1 + v2.x * w2 + v3.x * w3;
            acc[t].y += v0.y * w0 + v1.y * w1 + v2.y * w2 + v3.y * w3;
            acc[t].z += v0.z * w0 + v1.z * w1 + v2.z * w2 + v3.z * w3;
            acc[t].w += v0.w * w0 + v1.w * w1 + v2.w * w2 + v3.w * w3;
        }
    };

    float4 v0 = *reinterpret_cast<const float4*>(inb + (size_t)0 * P);
    float4 v1 = *reinterpret_cast<const float4*>(inb + (size_t)1 * P);
    float4 v2 = *reinterpret_cast<const float4*>(inb + (size_t)2 * P);
    float4 v3 = *reinterpret_cast<const float4*>(inb + (size_t)3 * P);
    for (int i = 0; i < Ci - 4; i += 4) {
        const float4 n0 = *reinterpret_cast<const float4*>(inb + (size_t)(i + 4) * P);
        const float4 n1 = *reinterpret_cast<const float4*>(inb + (size_t)(i + 5) * P);
        const float4 n2 = *reinterpret_cast<const float4*>(inb + (size_t)(i + 6) * P);
        const float4 n3 = *reinterpret_cast<const float4*>(inb + (size_t)(i + 7) * P);
        fmab(i, v0, v1, v2, v3);
        v0 = n0; v1 = n1; v2 = n2; v3 = n3;
    }
    fmab(Ci - 4, v0, v1, v2, v3);

#pragma unroll
    for (int t = 0; t < TO; ++t) {
        const size_t off = ((size_t)b * Co + o0 + t) * P + p;
        float4 r = acc[t];
        if (res) {
            const float4 rv = *reinterpret_cast<const float4*>(res + off);
            r.x += rv.x; r.y += rv.y; r.z += rv.z; r.w += rv.w;
        }
        *reinterpret_cast<float4*>(out + off) = r;
    }
}

// ---------------- split-K pointwise conv: writes partial sums ----------------
// grid.x = KS (P=1024 in one chunk), grid.y = Co/TO, grid.z = B
template <int TO, int KS>
__global__ __launch_bounds__(256, 2)
void pw_ks(const float* __restrict__ in, const float* __restrict__ W,
           float* __restrict__ partial, int Ci, int Co, int P) {
    __shared__ float wsh[TO * 256];
    const int ks = blockIdx.x;
    const int b  = blockIdx.z;
    const int o0 = blockIdx.y * TO;
    const int p  = threadIdx.x * 4;
    const int ciN = Ci / KS;
    const int ci0 = ks * ciN;

    for (int t = threadIdx.x; t < TO * ciN; t += 256)
        wsh[t] = W[(size_t)(o0 + t / ciN) * Ci + ci0 + (t % ciN)];
    __syncthreads();

    const float* inb = in + (size_t)b * Ci * P + (size_t)ci0 * P + p;
    float4 acc[TO];
#pragma unroll
    for (int t = 0; t < TO; ++t) acc[t] = make_float4(0.f, 0.f, 0.f, 0.f);

    auto fmab = [&](int i, const float4 v0, const float4 v1, const float4 v2, const float4 v3) {
#pragma unroll
        for (int t = 0; t < TO; ++t) {
            const float* wr = &wsh[t * ciN + i];
            const float w0 = wr[0], w1 = wr[1], w2 = wr[2], w3 = wr[3];
            acc[t].x += v0.x * w0 + v1.x * w1 + v2.x * w2 + v3.x * w3;
            acc[t].y += v0.y * w0 + v1.y * w1 + v2.y * w2 + v3.y * w3;
            acc[t].z += v0.z * w0 + v1.z * w1 + v2.z * w2 + v3.z * w3;
            acc[t].w += v0.w * w0 + v1.w * w1 + v2.w * w2 + v3.w * w3;
        }
    };

    float4 v0 = *reinterpret_cast<const float4*>(inb + (size_t)0 * P);
    float4 v1 = *reinterpret_cast<const float4*>(inb + (size_t)1 * P);
    float4 v2 = *reinterpret_cast<const float4*>(inb + (size_t)2 * P);
    float4 v3 = *reinterpret_cast<const float4*>(inb + (size_t)3 * P);
    for (int i = 0; i < ciN - 4; i += 4) {
        const float4 n0 = *reinterpret_cast<const float4*>(inb + (size_t)(i + 4) * P);
        const float4 n1 = *reinterpret_cast<const float4*>(inb + (size_t)(i + 5) * P);
        const float4 n2 = *reinterpret_cast<const float4*>(inb + (size_t)(i + 6) * P);
        const float4 n3 = *reinterpret_cast<const float4*>(inb + (size_t)(i + 7) * P);
        fmab(i, v0, v1, v2, v3);
        v0 = n0; v1 = n1; v2 = n2; v3 = n3;
    }
    fmab(ciN - 4, v0, v1, v2, v3);

#pragma unroll
    for (int t = 0; t < TO; ++t) {
        const size_t off = (((size_t)ks * NB_ + b) * Co + o0 + t) * P + p;
        *reinterpret_cast<float4*>(partial + off) = acc[t];
    }
}

// ---------------- reduce KS partial buffers (+optional bias) ----------------
__global__ void reduce_partials(const float* __restrict__ part, const float* __restrict__ bias,
                                float* __restrict__ out, int KS, int Co, int P, int n4) {
    const int idx = blockIdx.x * 256 + threadIdx.x;
    if (idx >= n4) return;
    const size_t e = (size_t)idx * 4;
    const size_t n = (size_t)NB_ * Co * P;
    float4 s = *reinterpret_cast<const float4*>(part + e);
    for (int ks = 1; ks < KS; ++ks) {
        const float4 v = *reinterpret_cast<const float4*>(part + ks * n + e);
        s.x += v.x; s.y += v.y; s.z += v.z; s.w += v.w;
    }
    if (bias) {
        const float bv = bias[(e / P) % Co];
        s.x += bv; s.y += bv; s.z += bv; s.w += bv;
    }
    *reinterpret_cast<float4*>(out + e) = s;
}

// ---------------- bilinear resize (linspace endpoints-inclusive) ----------------
__global__ void resize_bilinear(const float* __restrict__ in, float* __restrict__ out,
                                int C, int ibs, int Hi, int Wi, int Ho, int Wo) {
    const int idx = blockIdx.x * 256 + threadIdx.x;
    const int total = NB_ * C * Ho * Wo;
    if (idx >= total) return;
    const int x = idx % Wo;
    const int y = (idx / Wo) % Ho;
    const int c = (idx / (Wo * Ho)) % C;
    const int b = idx / (Wo * Ho * C);
    const float fy = (float)y * (float)(Hi - 1) / (float)(Ho - 1);
    const float fx = (float)x * (float)(Wi - 1) / (float)(Wo - 1);
    int y0 = (int)floorf(fy); int y1 = min(y0 + 1, Hi - 1); const float wy = fy - (float)y0;
    int x0 = (int)floorf(fx); int x1 = min(x0 + 1, Wi - 1); const float wx = fx - (float)x0;
    const float* pc = in + (size_t)b * ibs + (size_t)c * Hi * Wi;
    const float r0 = pc[y0 * Wi + x0] * (1.f - wx) + pc[y0 * Wi + x1] * wx;
    const float r1 = pc[y1 * Wi + x0] * (1.f - wx) + pc[y1 * Wi + x1] * wx;
    out[idx] = r0 * (1.f - wy) + r1 * wy;
}

// ---------------- BN stats: per-channel scale/shift ----------------
__global__ void bn_stats(const float* __restrict__ in, const float* __restrict__ g,
                         const float* __restrict__ bt, float* __restrict__ scale,
                         float* __restrict__ shift, int C, int HW, float eps) {
    const int c = blockIdx.x;
    float s1 = 0.f, s2 = 0.f;
    for (int b = 0; b < NB_; ++b) {
        const float* p = in + ((size_t)b * C + c) * HW;
        for (int r = threadIdx.x; r < HW; r += 256) {
            const float v = p[r];
            s1 += v; s2 += v * v;
        }
    }
    __shared__ float sh1[256], sh2[256];
    sh1[threadIdx.x] = s1; sh2[threadIdx.x] = s2;
    __syncthreads();
    for (int s = 128; s > 0; s >>= 1) {
        if (threadIdx.x < s) { sh1[threadIdx.x] += sh1[threadIdx.x + s]; sh2[threadIdx.x] += sh2[threadIdx.x + s]; }
        __syncthreads();
    }
    if (threadIdx.x == 0) {
        const float N = (float)(NB_ * HW);
        const float m = sh1[0] / N;
        const float var = sh2[0] / N - m * m;
        const float sc = g[c] * rsqrtf(var + eps);
        scale[c] = sc;
        shift[c] = bt[c] - m * sc;
    }
}

// ---------------- fused (optional BN) + depthwise 3x3, pad=1 ----------------
__global__ void bn_dw3(const float* __restrict__ in, const float* __restrict__ scale,
                       const float* __restrict__ shift, const float* __restrict__ dw,
                       float* __restrict__ out, int C, int H, int W) {
    const int idx = blockIdx.x * 256 + threadIdx.x;
    const int total = NB_ * C * H * W;
    if (idx >= total) return;
    const int x = idx % W;
    const int y = (idx / W) % H;
    const int c = (idx / (W * H)) % C;
    const float sc = scale ? scale[c] : 1.f;
    const float sh = shift ? shift[c] : 0.f;
    const float* p = in + (size_t)(idx - (y * W + x));
    const float* w = dw + c * 9;
    float acc = 0.f;
#pragma unroll
    for (int dy = 0; dy < 3; ++dy) {
        const int yy = y + dy - 1;
        if (yy < 0 || yy >= H) continue;
#pragma unroll
        for (int dx = 0; dx < 3; ++dx) {
            const int xx = x + dx - 1;
            if (xx < 0 || xx >= W) continue;
            acc += w[dy * 3 + dx] * (p[yy * W + xx] * sc + sh);
        }
    }
    out[idx] = acc;
}

// ---------------- LN (optional) + split heads: conv layout -> [b,h,j,d] ----------------
__global__ void ln_split(const float* __restrict__ in, const float* __restrict__ g,
                         const float* __restrict__ bt, float* __restrict__ out,
                         int HW, int applyLN, float eps) {
    const int row = blockIdx.x * 8 + (threadIdx.x >> 5);
    const int d = threadIdx.x & 31;
    const int j = row % HW;
    const int h = (row / HW) % NHEAD;
    const int b = row / (HW * NHEAD);
    float v = in[((size_t)b * OUTCH + d * NHEAD + h) * HW + j];
    if (applyLN) {
        float s1 = v, s2 = v * v;
#pragma unroll
        for (int o = 16; o >= 1; o >>= 1) {
            s1 += __shfl_xor(s1, o, 32);
            s2 += __shfl_xor(s2, o, 32);
        }
        const float m = s1 * (1.f / 32.f);
        const float var = s2 * (1.f / 32.f) - m * m;
        v = (v - m) * rsqrtf(var + eps) * g[h * 32 + d] + bt[h * 32 + d];
    }
    out[((size_t)(b * NHEAD + h) * HW + j) * 32 + d] = v;
}

// ---------------- M[bh,e,d] = sum_j kn[bh,j,e]*vh[bh,j,d] ----------------
__global__ void kv_outer(const float* __restrict__ kn, const float* __restrict__ vh,
                         float* __restrict__ M) {
    __shared__ float vs[256][32];
    const int bh = blockIdx.x;
    const float* kp = kn + (size_t)bh * 256 * 32;
    const float* vp = vh + (size_t)bh * 256 * 32;
    const int tid = threadIdx.y * 32 + threadIdx.x;
    for (int t = tid; t < 256 * 32; t += 1024) vs[t >> 5][t & 31] = vp[t];
    __syncthreads();
    const int e = threadIdx.x, dd = threadIdx.y;
    float acc = 0.f;
    for (int j = 0; j < 256; ++j) acc += kp[j * 32 + e] * vs[j][dd];
    M[((size_t)bh * 32 + e) * 32 + dd] = acc;
}

// ---------------- Bv[bh,qb,d] = sum_j relbias[h,qb,j]*vh[bh,j,d] ----------------
__global__ void bias_v(const float* __restrict__ rel, const float* __restrict__ vh,
                       float* __restrict__ Bv) {
    const int gid = blockIdx.x * 8 + (threadIdx.x >> 5);
    const int d = threadIdx.x & 31;
    const int qb = gid % 256;
    const int h = (gid / 256) % NHEAD;
    const int b = gid / (256 * NHEAD);
    const int qy = qb >> 4, qx = qb & 15;
    const float* vp = vh + (size_t)(b * NHEAD + h) * 256 * 32;
    float acc = 0.f;
    for (int j = 0; j < 256; ++j) {
        const int ky = j >> 4, kx = j & 15;
        const float bias = rel[((qy - ky + 15) * 31 + (qx - kx + 15)) * NHEAD + h];
        acc += bias * vp[j * 32 + d];
    }
    Bv[((size_t)(b * NHEAD + h) * 256 + qb) * 32 + d] = acc;
}

// ---------------- attention out: o = (LN(q) @ M + Bv)/32, conv layout ----------------
__global__ void attn_out(const float* __restrict__ q, const float* __restrict__ gq,
                         const float* __restrict__ bq, const float* __restrict__ M,
                         const float* __restrict__ Bv, float* __restrict__ o) {
    const int gid = blockIdx.x * 256 + threadIdx.x;
    const int i = gid % 4096;
    const int h = (gid / 4096) % NHEAD;
    const int b = gid / (4096 * NHEAD);
    const int y = i >> 6, x = i & 63;
    const int qb = (y >> 2) * 16 + (x >> 2);

    const float* qp = q + (size_t)b * OUTCH * 4096 + h * 4096 + i;
    float qv[32];
    float s1 = 0.f, s2 = 0.f;
#pragma unroll
    for (int d = 0; d < 32; ++d) {
        const float v = qp[(size_t)d * NHEAD * 4096];
        qv[d] = v; s1 += v; s2 += v * v;
    }
    const float m = s1 * (1.f / 32.f);
    const float var = s2 * (1.f / 32.f) - m * m;
    const float rs = rsqrtf(var + 1e-6f);
#pragma unroll
    for (int d = 0; d < 32; ++d)
        qv[d] = (qv[d] - m) * rs * gq[h * 32 + d] + bq[h * 32 + d];

    const float* Mp = M + (size_t)(b * NHEAD + h) * 32 * 32;
    const float* Bp = Bv + ((size_t)(b * NHEAD + h) * 256 + qb) * 32;
    float acc[32];
#pragma unroll
    for (int d = 0; d < 32; ++d) acc[d] = Bp[d];
#pragma unroll
    for (int e = 0; e < 32; ++e) {
        const float qe = qv[e];
#pragma unroll
        for (int d = 0; d < 32; ++d) acc[d] += qe * Mp[e * 32 + d];
    }
    float* op = o + (size_t)b * OUTCH * 4096 + h * 4096 + i;
#pragma unroll
    for (int d = 0; d < 32; ++d) op[(size_t)d * NHEAD * 4096] = acc[d] * (1.f / 32.f);
}

// ---------------- BN + ReLU elementwise ----------------
__global__ void bn_relu(const float* __restrict__ in, const float* __restrict__ scale,
                        const float* __restrict__ shift, float* __restrict__ out,
                        int C, int HW) {
    const int idx = blockIdx.x * 256 + threadIdx.x;
    const int total = NB_ * C * HW;
    if (idx >= total) return;
    const int c = (idx / HW) % C;
    const float v = in[idx] * scale[c] + shift[c];
    out[idx] = v > 0.f ? v : 0.f;
}

extern "C" void kernel_launch(void* const* d_in, const int* in_sizes, int n_in,
                              void* d_out, int out_size, void* d_ws, size_t ws_size,
                              hipStream_t stream) {
    const float* x1        = (const float*)d_in[0];
    const float* x2        = (const float*)d_in[1];
    const float* conv_ch_w = (const float*)d_in[2];
    const float* conv_ch_b = (const float*)d_in[3];
    const float* norm_l_g  = (const float*)d_in[4];
    const float* norm_l_b  = (const float*)d_in[5];
    const float* norm_h_g  = (const float*)d_in[6];
    const float* norm_h_b  = (const float*)d_in[7];
    const float* to_kv_dw  = (const float*)d_in[8];
    const float* to_kv_pw  = (const float*)d_in[9];
    const float* to_q_dw   = (const float*)d_in[10];
    const float* to_q_pw   = (const float*)d_in[11];
    const float* to_out_dw = (const float*)d_in[12];
    const float* to_out_pw = (const float*)d_in[13];
    const float* rel_table = (const float*)d_in[14];
    const float* normq_g   = (const float*)d_in[15];
    const float* normq_b   = (const float*)d_in[16];
    const float* normk_g   = (const float*)d_in[17];
    const float* normk_b   = (const float*)d_in[18];
    const float* norm2_g   = (const float*)d_in[19];
    const float* norm2_b   = (const float*)d_in[20];
    const float* mlp_w     = (const float*)d_in[21];
    float* Dout = (float*)d_out;

    float* ws = (float*)d_ws;
    const size_t NBIG = (size_t)NB_ * OUTCH * 4096; // 8388608 floats (32 MB)
    float* RES = ws;
    float* A   = ws + NBIG;
    float* Bb  = ws + 2 * NBIG;
    float* sm  = ws + 3 * NBIG;
    float* scale1 = sm;            float* shift1 = sm + 512;
    float* scale2 = sm + 1024;     float* shift2 = sm + 1280;
    float* scale3 = sm + 1536;     float* shift3 = sm + 1792;
    float* k16 = sm + 2048;
    float* v16 = k16 + 524288;
    float* kn  = v16 + 524288;
    float* vh  = kn  + 524288;
    float* Mm  = vh  + 524288;
    float* Bv  = Mm  + 65536;

    float* kv_dw = A;                 // 4 M floats (16 MB) at A[0:16MB]
    float* kv    = A + 4 * 1048576;   // 4 M floats (16 MB) at A[16:32MB]

    // 1. x1c = conv1x1(x1)+b : split-K=4 partials -> Bb, reduce -> A
    pw_ks<16, 4><<<dim3(4, 16, 8), 256, 0, stream>>>(x1, conv_ch_w, Bb, 512, 256, 1024);
    reduce_partials<<<2048, 256, 0, stream>>>(Bb, conv_ch_b, A, 4, 256, 1024, 524288);
    // 2. residue = resize(x1c, 64,64) -> RES
    resize_bilinear<<<32768, 256, 0, stream>>>(A, RES, 256, 256 * 1024, 32, 32, 64, 64);
    // 3. BN stats x1
    bn_stats<<<512, 256, 0, stream>>>(x1, norm_l_g, norm_l_b, scale1, shift1, 512, 1024, 1e-5f);
    // 4. kv_dw = dw3(BN(x1)) -> A[0:16MB]  (x1c in A[0:8MB] is dead after step 2)
    bn_dw3<<<16384, 256, 0, stream>>>(x1, scale1, shift1, to_kv_dw, kv_dw, 512, 32, 32);
    // 5. kv = pw(kv_dw) : split-K=2 partials -> Bb, reduce -> A[16:32MB]
    pw_ks<16, 2><<<dim3(2, 32, 8), 256, 0, stream>>>(kv_dw, to_kv_pw, Bb, 512, 512, 1024);
    reduce_partials<<<4096, 256, 0, stream>>>(Bb, nullptr, kv, 2, 512, 1024, 1048576);
    // 6. k16, v16 = resize to 16x16
    resize_bilinear<<<2048, 256, 0, stream>>>(kv, k16, 256, 512 * 1024, 32, 32, 16, 16);
    resize_bilinear<<<2048, 256, 0, stream>>>(kv + 256 * 1024, v16, 256, 512 * 1024, 32, 32, 16, 16);
    // 7. BN stats x2
    bn_stats<<<256, 256, 0, stream>>>(x2, norm_h_g, norm_h_b, scale2, shift2, 256, 4096, 1e-5f);
    // 8. q_dw = dw3(BN(x2)) -> Bb (32 MB)
    bn_dw3<<<32768, 256, 0, stream>>>(x2, scale2, shift2, to_q_dw, Bb, 256, 64, 64);
    // 9. q = pw(q_dw) -> A (32 MB, conv layout [8,256,4096])
    pw_conv<16><<<dim3(4, 16, 8), 256, 0, stream>>>(Bb, to_q_pw, nullptr, nullptr, A, 256, 256, 4096);
    // 10. kn = LN(split(k16)); vh = split(v16)
    ln_split<<<2048, 256, 0, stream>>>(k16, normk_g, normk_b, kn, 256, 1, 1e-6f);
    ln_split<<<2048, 256, 0, stream>>>(v16, nullptr, nullptr, vh, 256, 0, 0.f);
    // 11. M = k^T v  (per b,h: 32x32)
    kv_outer<<<64, dim3(32, 32), 0, stream>>>(kn, vh, Mm);
    // 12. Bv = bias @ v (per b,h: 256x32)
    bias_v<<<2048, 256, 0, stream>>>(rel_table, vh, Bv);
    // 13. o = (LN(q) @ M + Bv)/32 -> Bb (conv layout)
    attn_out<<<1024, 256, 0, stream>>>(A, normq_g, normq_b, Mm, Bv, Bb);
    // 14. out_dw = dw3(o) -> d_out (scratch)
    bn_dw3<<<32768, 256, 0, stream>>>(Bb, nullptr, nullptr, to_out_dw, Dout, 256, 64, 64);
    // 15. o2 = pw(out_dw) + residue -> A   (this is res2)
    pw_conv<16><<<dim3(4, 16, 8), 256, 0, stream>>>(Dout, to_out_pw, nullptr, RES, A, 256, 256, 4096);
    // 16. BN stats o2
    bn_stats<<<256, 256, 0, stream>>>(A, norm2_g, norm2_b, scale3, shift3, 256, 4096, 1e-5f);
    // 17. r = relu(BN(o2)) -> Bb
    bn_relu<<<32768, 256, 0, stream>>>(A, scale3, shift3, Bb, 256, 4096);
    // 18. out = pw(r, mlp_w) + res2 -> d_out
    pw_conv<16><<<dim3(4, 16, 8), 256, 0, stream>>>(Bb, mlp_w, nullptr, A, Dout, 256, 256, 4096);
}

// Round 4
// 639.752 us; speedup vs baseline: 1.5095x; 1.1484x over previous
//
#include <hip/hip_runtime.h>
#include <math.h>

#define NB_   8
#define INCH  512
#define OUTCH 256
#define NHEAD 8
#define DHEAD 32

typedef __attribute__((ext_vector_type(8))) short short8v;
typedef __attribute__((ext_vector_type(4))) float f32x4;

__device__ inline short f2bf(float f) {
    unsigned u = __float_as_uint(f);
    unsigned r = u + 0x7FFFu + ((u >> 16) & 1u);
    return (short)(r >> 16);
}

// ---------------- pack fp32 weight [Co][Ci] -> bf16 packed-k layout ----------------
// packed pos within 32-k tile: (q = (k%16)/4, h = k/16, r = k%4) -> q*8 + h*4 + r
__global__ void pack_w(const float* __restrict__ W, short* __restrict__ Wp, int Co, int Ci) {
    const int idx = blockIdx.x * 256 + threadIdx.x;
    if (idx >= Co * Ci) return;
    const int m = idx / Ci, i = idx % Ci;
    const int kt = i >> 5, w32 = i & 31;
    const int h = w32 >> 4, q = (w32 & 15) >> 2, r = w32 & 3;
    Wp[m * Ci + kt * 32 + q * 8 + h * 4 + r] = f2bf(W[idx]);
}

// ---------------- MFMA bf16 pointwise conv (GEMM): out[b,m,p] = sum_i W[m,i] X[b,i,p] ----------------
// Xp: [B][P][Ci] bf16 packed-k; Wp: [Co][Ci] bf16 packed-k.
// BM=128, BN=64, BK=32; 4 waves (2x2), wave tile 64x32.
template <int HAS_RES>
__global__ __launch_bounds__(256, 4)
void mfma_pw(const short* __restrict__ Xp, const short* __restrict__ Wp,
             const float* __restrict__ res, float* __restrict__ out,
             int Ci, int Co, int P) {
    __shared__ short Ash[4096];  // [q(4)][m(128)] 16B chunks = 8KB
    __shared__ short Bsh[2048];  // [q(4)][n(64)]  16B chunks = 4KB
    const int b   = blockIdx.z;
    const int m0  = blockIdx.y * 128;
    const int n0  = blockIdx.x * 64;
    const int tid = threadIdx.x;
    const int lane = tid & 63;
    const int wid  = tid >> 6;
    const int wr = wid >> 1, wc = wid & 1;
    const int ql = lane >> 4, l16 = lane & 15;

    f32x4 acc[4][2];
#pragma unroll
    for (int mb = 0; mb < 4; ++mb)
#pragma unroll
        for (int nb = 0; nb < 2; ++nb) acc[mb][nb] = (f32x4){0.f, 0.f, 0.f, 0.f};

    const int sm_ = tid & 127;  // A stage: m
    const int sq_ = tid >> 7;   // A stage: q sub
    const int bn_ = tid & 63;   // B stage: n
    const int bq_ = tid >> 6;   // B stage: q

    const size_t wrow = (size_t)(m0 + sm_) * Ci;
    const size_t xrow = ((size_t)b * P + n0 + bn_) * Ci;

    const int nkt = Ci >> 5;
    for (int kt = 0; kt < nkt; ++kt) {
        const int kof = kt * 32;
#pragma unroll
        for (int r = 0; r < 2; ++r) {
            const int q = r * 2 + sq_;
            __builtin_amdgcn_global_load_lds(Wp + wrow + kof + q * 8, &Ash[r * 2048 + tid * 8], 16, 0, 0);
        }
        __builtin_amdgcn_global_load_lds(Xp + xrow + kof + bq_ * 8, &Bsh[tid * 8], 16, 0, 0);
        __syncthreads();

        short8v a[4], bf[2];
#pragma unroll
        for (int mb = 0; mb < 4; ++mb)
            a[mb] = *reinterpret_cast<const short8v*>(&Ash[ql * 1024 + (wr * 64 + mb * 16 + l16) * 8]);
#pragma unroll
        for (int nb = 0; nb < 2; ++nb)
            bf[nb] = *reinterpret_cast<const short8v*>(&Bsh[ql * 512 + (wc * 32 + nb * 16 + l16) * 8]);
#pragma unroll
        for (int mb = 0; mb < 4; ++mb)
#pragma unroll
            for (int nb = 0; nb < 2; ++nb)
                acc[mb][nb] = __builtin_amdgcn_mfma_f32_16x16x32_bf16(a[mb], bf[nb], acc[mb][nb], 0, 0, 0);
        __syncthreads();
    }

#pragma unroll
    for (int mb = 0; mb < 4; ++mb) {
        const int row = m0 + wr * 64 + mb * 16 + ql * 4;
#pragma unroll
        for (int nb = 0; nb < 2; ++nb) {
            const int col = n0 + wc * 32 + nb * 16 + l16;
            const size_t base = ((size_t)b * Co + row) * P + col;
#pragma unroll
            for (int j = 0; j < 4; ++j) {
                float v = acc[mb][nb][j];
                if (HAS_RES) v += res[base + (size_t)j * P];
                out[base + (size_t)j * P] = v;
            }
        }
    }
}

// ---------------- (optional BN) + depthwise 3x3 -> packed bf16 X layout ----------------
// grid: (P/256, C/32, B). thread = pixel; handles 32 channels (one 32-k tile).
__global__ void bn_dw3_packed(const float* __restrict__ in, const float* __restrict__ scale,
                              const float* __restrict__ shift, const float* __restrict__ dw,
                              short* __restrict__ outp, int C, int H, int W) {
    const int p  = blockIdx.x * 256 + threadIdx.x;
    const int kt = blockIdx.y;
    const int b  = blockIdx.z;
    const int y = p / W, x = p % W;
    const int P = H * W;
#pragma unroll
    for (int q = 0; q < 4; ++q) {
        short tmp[8];
#pragma unroll
        for (int h = 0; h < 2; ++h)
#pragma unroll
            for (int r = 0; r < 4; ++r) {
                const int c = kt * 32 + h * 16 + q * 4 + r;
                const float sc = scale ? scale[c] : 1.f;
                const float sh = shift ? shift[c] : 0.f;
                const float* base = in + ((size_t)b * C + c) * P;
                const float* w = dw + c * 9;
                float acc = 0.f;
#pragma unroll
                for (int dy = 0; dy < 3; ++dy) {
                    const int yy = y + dy - 1;
                    if (yy < 0 || yy >= H) continue;
#pragma unroll
                    for (int dx = 0; dx < 3; ++dx) {
                        const int xx = x + dx - 1;
                        if (xx < 0 || xx >= W) continue;
                        acc += w[dy * 3 + dx] * (base[yy * W + xx] * sc + sh);
                    }
                }
                tmp[h * 4 + r] = f2bf(acc);
            }
        short8v v;
#pragma unroll
        for (int j = 0; j < 8; ++j) v[j] = tmp[j];
        *reinterpret_cast<short8v*>(&outp[((size_t)b * P + p) * C + kt * 32 + q * 8]) = v;
    }
}

// ---------------- BN + ReLU -> packed bf16 X layout ----------------
__global__ void bn_relu_packed(const float* __restrict__ in, const float* __restrict__ scale,
                               const float* __restrict__ shift, short* __restrict__ outp,
                               int C, int P) {
    const int p  = blockIdx.x * 256 + threadIdx.x;
    const int kt = blockIdx.y;
    const int b  = blockIdx.z;
#pragma unroll
    for (int q = 0; q < 4; ++q) {
        short tmp[8];
#pragma unroll
        for (int h = 0; h < 2; ++h)
#pragma unroll
            for (int r = 0; r < 4; ++r) {
                const int c = kt * 32 + h * 16 + q * 4 + r;
                const float v = in[((size_t)b * C + c) * P + p] * scale[c] + shift[c];
                tmp[h * 4 + r] = f2bf(v > 0.f ? v : 0.f);
            }
        short8v v;
#pragma unroll
        for (int j = 0; j < 8; ++j) v[j] = tmp[j];
        *reinterpret_cast<short8v*>(&outp[((size_t)b * P + p) * C + kt * 32 + q * 8]) = v;
    }
}

// ---------------- split-K fp32 pointwise conv (steps 1,5) ----------------
template <int TO, int KS>
__global__ __launch_bounds__(256, 2)
void pw_ks(const float* __restrict__ in, const float* __restrict__ W,
           float* __restrict__ partial, int Ci, int Co, int P) {
    __shared__ float wsh[TO * 256];
    const int ks = blockIdx.x;
    const int b  = blockIdx.z;
    const int o0 = blockIdx.y * TO;
    const int p  = threadIdx.x * 4;
    const int ciN = Ci / KS;
    const int ci0 = ks * ciN;

    for (int t = threadIdx.x; t < TO * ciN; t += 256)
        wsh[t] = W[(size_t)(o0 + t / ciN) * Ci + ci0 + (t % ciN)];
    __syncthreads();

    const float* inb = in + (size_t)b * Ci * P + (size_t)ci0 * P + p;
    float4 acc[TO];
#pragma unroll
    for (int t = 0; t < TO; ++t) acc[t] = make_float4(0.f, 0.f, 0.f, 0.f);

    auto fmab = [&](int i, const float4 v0, const float4 v1, const float4 v2, const float4 v3) {
#pragma unroll
        for (int t = 0; t < TO; ++t) {
            const float* wr = &wsh[t * ciN + i];
            const float w0 = wr[0], w1 = wr[1], w2 = wr[2], w3 = wr[3];
            acc[t].x += v0.x * w0 + v1.x * w1 + v2.x * w2 + v3.x * w3;
            acc[t].y += v0.y * w0 + v1.y * w1 + v2.y * w2 + v3.y * w3;
            acc[t].z += v0.z * w0 + v1.z * w1 + v2.z * w2 + v3.z * w3;
            acc[t].w += v0.w * w0 + v1.w * w1 + v2.w * w2 + v3.w * w3;
        }
    };

    float4 v0 = *reinterpret_cast<const float4*>(inb + (size_t)0 * P);
    float4 v1 = *reinterpret_cast<const float4*>(inb + (size_t)1 * P);
    float4 v2 = *reinterpret_cast<const float4*>(inb + (size_t)2 * P);
    float4 v3 = *reinterpret_cast<const float4*>(inb + (size_t)3 * P);
    for (int i = 0; i < ciN - 4; i += 4) {
        const float4 n0 = *reinterpret_cast<const float4*>(inb + (size_t)(i + 4) * P);
        const float4 n1 = *reinterpret_cast<const float4*>(inb + (size_t)(i + 5) * P);
        const float4 n2 = *reinterpret_cast<const float4*>(inb + (size_t)(i + 6) * P);
        const float4 n3 = *reinterpret_cast<const float4*>(inb + (size_t)(i + 7) * P);
        fmab(i, v0, v1, v2, v3);
        v0 = n0; v1 = n1; v2 = n2; v3 = n3;
    }
    fmab(ciN - 4, v0, v1, v2, v3);

#pragma unroll
    for (int t = 0; t < TO; ++t) {
        const size_t off = (((size_t)ks * NB_ + b) * Co + o0 + t) * P + p;
        *reinterpret_cast<float4*>(partial + off) = acc[t];
    }
}

__global__ void reduce_partials(const float* __restrict__ part, const float* __restrict__ bias,
                                float* __restrict__ out, int KS, int Co, int P, int n4) {
    const int idx = blockIdx.x * 256 + threadIdx.x;
    if (idx >= n4) return;
    const size_t e = (size_t)idx * 4;
    const size_t n = (size_t)NB_ * Co * P;
    float4 s = *reinterpret_cast<const float4*>(part + e);
    for (int ks = 1; ks < KS; ++ks) {
        const float4 v = *reinterpret_cast<const float4*>(part + ks * n + e);
        s.x += v.x; s.y += v.y; s.z += v.z; s.w += v.w;
    }
    if (bias) {
        const float bv = bias[(e / P) % Co];
        s.x += bv; s.y += bv; s.z += bv; s.w += bv;
    }
    *reinterpret_cast<float4*>(out + e) = s;
}

// ---------------- bilinear resize ----------------
__global__ void resize_bilinear(const float* __restrict__ in, float* __restrict__ out,
                                int C, int ibs, int Hi, int Wi, int Ho, int Wo) {
    const int idx = blockIdx.x * 256 + threadIdx.x;
    const int total = NB_ * C * Ho * Wo;
    if (idx >= total) return;
    const int x = idx % Wo;
    const int y = (idx / Wo) % Ho;
    const int c = (idx / (Wo * Ho)) % C;
    const int b = idx / (Wo * Ho * C);
    const float fy = (float)y * (float)(Hi - 1) / (float)(Ho - 1);
    const float fx = (float)x * (float)(Wi - 1) / (float)(Wo - 1);
    int y0 = (int)floorf(fy); int y1 = min(y0 + 1, Hi - 1); const float wy = fy - (float)y0;
    int x0 = (int)floorf(fx); int x1 = min(x0 + 1, Wi - 1); const float wx = fx - (float)x0;
    const float* pc = in + (size_t)b * ibs + (size_t)c * Hi * Wi;
    const float r0 = pc[y0 * Wi + x0] * (1.f - wx) + pc[y0 * Wi + x1] * wx;
    const float r1 = pc[y1 * Wi + x0] * (1.f - wx) + pc[y1 * Wi + x1] * wx;
    out[idx] = r0 * (1.f - wy) + r1 * wy;
}

// ---------------- BN stats ----------------
__global__ void bn_stats(const float* __restrict__ in, const float* __restrict__ g,
                         const float* __restrict__ bt, float* __restrict__ scale,
                         float* __restrict__ shift, int C, int HW, float eps) {
    const int c = blockIdx.x;
    float s1 = 0.f, s2 = 0.f;
    for (int b = 0; b < NB_; ++b) {
        const float* p = in + ((size_t)b * C + c) * HW;
        for (int r = threadIdx.x; r < HW; r += 256) {
            const float v = p[r];
            s1 += v; s2 += v * v;
        }
    }
    __shared__ float sh1[256], sh2[256];
    sh1[threadIdx.x] = s1; sh2[threadIdx.x] = s2;
    __syncthreads();
    for (int s = 128; s > 0; s >>= 1) {
        if (threadIdx.x < s) { sh1[threadIdx.x] += sh1[threadIdx.x + s]; sh2[threadIdx.x] += sh2[threadIdx.x + s]; }
        __syncthreads();
    }
    if (threadIdx.x == 0) {
        const float N = (float)(NB_ * HW);
        const float m = sh1[0] / N;
        const float var = sh2[0] / N - m * m;
        const float sc = g[c] * rsqrtf(var + eps);
        scale[c] = sc;
        shift[c] = bt[c] - m * sc;
    }
}

// ---------------- fp32 BN + depthwise 3x3 (step 4) ----------------
__global__ void bn_dw3(const float* __restrict__ in, const float* __restrict__ scale,
                       const float* __restrict__ shift, const float* __restrict__ dw,
                       float* __restrict__ out, int C, int H, int W) {
    const int idx = blockIdx.x * 256 + threadIdx.x;
    const int total = NB_ * C * H * W;
    if (idx >= total) return;
    const int x = idx % W;
    const int y = (idx / W) % H;
    const int c = (idx / (W * H)) % C;
    const float sc = scale ? scale[c] : 1.f;
    const float sh = shift ? shift[c] : 0.f;
    const float* p = in + (size_t)(idx - (y * W + x));
    const float* w = dw + c * 9;
    float acc = 0.f;
#pragma unroll
    for (int dy = 0; dy < 3; ++dy) {
        const int yy = y + dy - 1;
        if (yy < 0 || yy >= H) continue;
#pragma unroll
        for (int dx = 0; dx < 3; ++dx) {
            const int xx = x + dx - 1;
            if (xx < 0 || xx >= W) continue;
            acc += w[dy * 3 + dx] * (p[yy * W + xx] * sc + sh);
        }
    }
    out[idx] = acc;
}

// ---------------- LN (optional) + split heads ----------------
__global__ void ln_split(const float* __restrict__ in, const float* __restrict__ g,
                         const float* __restrict__ bt, float* __restrict__ out,
                         int HW, int applyLN, float eps) {
    const int row = blockIdx.x * 8 + (threadIdx.x >> 5);
    const int d = threadIdx.x & 31;
    const int j = row % HW;
    const int h = (row / HW) % NHEAD;
    const int b = row / (HW * NHEAD);
    float v = in[((size_t)b * OUTCH + d * NHEAD + h) * HW + j];
    if (applyLN) {
        float s1 = v, s2 = v * v;
#pragma unroll
        for (int o = 16; o >= 1; o >>= 1) {
            s1 += __shfl_xor(s1, o, 32);
            s2 += __shfl_xor(s2, o, 32);
        }
        const float m = s1 * (1.f / 32.f);
        const float var = s2 * (1.f / 32.f) - m * m;
        v = (v - m) * rsqrtf(var + eps) * g[h * 32 + d] + bt[h * 32 + d];
    }
    out[((size_t)(b * NHEAD + h) * HW + j) * 32 + d] = v;
}

// ---------------- M = k^T v ----------------
__global__ void kv_outer(const float* __restrict__ kn, const float* __restrict__ vh,
                         float* __restrict__ M) {
    __shared__ float vs[256][32];
    const int bh = blockIdx.x;
    const float* kp = kn + (size_t)bh * 256 * 32;
    const float* vp = vh + (size_t)bh * 256 * 32;
    const int tid = threadIdx.y * 32 + threadIdx.x;
    for (int t = tid; t < 256 * 32; t += 1024) vs[t >> 5][t & 31] = vp[t];
    __syncthreads();
    const int e = threadIdx.x, dd = threadIdx.y;
    float acc = 0.f;
    for (int j = 0; j < 256; ++j) acc += kp[j * 32 + e] * vs[j][dd];
    M[((size_t)bh * 32 + e) * 32 + dd] = acc;
}

// ---------------- Bv = bias @ v ----------------
__global__ void bias_v(const float* __restrict__ rel, const float* __restrict__ vh,
                       float* __restrict__ Bv) {
    const int gid = blockIdx.x * 8 + (threadIdx.x >> 5);
    const int d = threadIdx.x & 31;
    const int qb = gid % 256;
    const int h = (gid / 256) % NHEAD;
    const int b = gid / (256 * NHEAD);
    const int qy = qb >> 4, qx = qb & 15;
    const float* vp = vh + (size_t)(b * NHEAD + h) * 256 * 32;
    float acc = 0.f;
    for (int j = 0; j < 256; ++j) {
        const int ky = j >> 4, kx = j & 15;
        const float bias = rel[((qy - ky + 15) * 31 + (qx - kx + 15)) * NHEAD + h];
        acc += bias * vp[j * 32 + d];
    }
    Bv[((size_t)(b * NHEAD + h) * 256 + qb) * 32 + d] = acc;
}

// ---------------- attention out: o = (LN(q) @ M + Bv)/32 (in-place safe) ----------------
__global__ void attn_out(const float* __restrict__ q, const float* __restrict__ gq,
                         const float* __restrict__ bq, const float* __restrict__ M,
                         const float* __restrict__ Bv, float* __restrict__ o) {
    const int gid = blockIdx.x * 256 + threadIdx.x;
    const int i = gid % 4096;
    const int h = (gid / 4096) % NHEAD;
    const int b = gid / (4096 * NHEAD);
    const int y = i >> 6, x = i & 63;
    const int qb = (y >> 2) * 16 + (x >> 2);

    const float* qp = q + (size_t)b * OUTCH * 4096 + h * 4096 + i;
    float qv[32];
    float s1 = 0.f, s2 = 0.f;
#pragma unroll
    for (int d = 0; d < 32; ++d) {
        const float v = qp[(size_t)d * NHEAD * 4096];
        qv[d] = v; s1 += v; s2 += v * v;
    }
    const float m = s1 * (1.f / 32.f);
    const float var = s2 * (1.f / 32.f) - m * m;
    const float rs = rsqrtf(var + 1e-6f);
#pragma unroll
    for (int d = 0; d < 32; ++d)
        qv[d] = (qv[d] - m) * rs * gq[h * 32 + d] + bq[h * 32 + d];

    const float* Mp = M + (size_t)(b * NHEAD + h) * 32 * 32;
    const float* Bp = Bv + ((size_t)(b * NHEAD + h) * 256 + qb) * 32;
    float acc[32];
#pragma unroll
    for (int d = 0; d < 32; ++d) acc[d] = Bp[d];
#pragma unroll
    for (int e = 0; e < 32; ++e) {
        const float qe = qv[e];
#pragma unroll
        for (int d = 0; d < 32; ++d) acc[d] += qe * Mp[e * 32 + d];
    }
    float* op = o + (size_t)b * OUTCH * 4096 + h * 4096 + i;
#pragma unroll
    for (int d = 0; d < 32; ++d) op[(size_t)d * NHEAD * 4096] = acc[d] * (1.f / 32.f);
}

extern "C" void kernel_launch(void* const* d_in, const int* in_sizes, int n_in,
                              void* d_out, int out_size, void* d_ws, size_t ws_size,
                              hipStream_t stream) {
    const float* x1        = (const float*)d_in[0];
    const float* x2        = (const float*)d_in[1];
    const float* conv_ch_w = (const float*)d_in[2];
    const float* conv_ch_b = (const float*)d_in[3];
    const float* norm_l_g  = (const float*)d_in[4];
    const float* norm_l_b  = (const float*)d_in[5];
    const float* norm_h_g  = (const float*)d_in[6];
    const float* norm_h_b  = (const float*)d_in[7];
    const float* to_kv_dw  = (const float*)d_in[8];
    const float* to_kv_pw  = (const float*)d_in[9];
    const float* to_q_dw   = (const float*)d_in[10];
    const float* to_q_pw   = (const float*)d_in[11];
    const float* to_out_dw = (const float*)d_in[12];
    const float* to_out_pw = (const float*)d_in[13];
    const float* rel_table = (const float*)d_in[14];
    const float* normq_g   = (const float*)d_in[15];
    const float* normq_b   = (const float*)d_in[16];
    const float* normk_g   = (const float*)d_in[17];
    const float* normk_b   = (const float*)d_in[18];
    const float* norm2_g   = (const float*)d_in[19];
    const float* norm2_b   = (const float*)d_in[20];
    const float* mlp_w     = (const float*)d_in[21];
    float* Dout = (float*)d_out;

    float* ws = (float*)d_ws;
    const size_t NBIG = (size_t)NB_ * OUTCH * 4096;  // 8388608 floats (32 MB)
    float* RES = ws;
    float* A   = ws + NBIG;
    float* Bb  = ws + 2 * NBIG;
    float* sm  = ws + 3 * NBIG;
    float* scale1 = sm;            float* shift1 = sm + 512;
    float* scale2 = sm + 1024;     float* shift2 = sm + 1280;
    float* scale3 = sm + 1536;     float* shift3 = sm + 1792;
    float* k16 = sm + 2048;
    float* v16 = k16 + 524288;
    float* kn  = v16 + 524288;
    float* vh  = kn  + 524288;
    float* Mm  = vh  + 524288;
    float* Bv  = Mm  + 65536;
    short* Wq  = (short*)(Bv + 524288);
    short* Wo  = Wq + 65536;
    short* Wm  = Wo + 65536;

    float* kv_dw = A;                // 16 MB at A[0:16MB]
    float* kv    = A + 4 * 1048576;  // 16 MB at A[16:32MB]
    short* Xp    = (short*)Bb;       // 16 MB packed bf16 X (Bb free after step 5)

    // 0. pack the three 256x256 weights to bf16 packed layout
    pack_w<<<256, 256, 0, stream>>>(to_q_pw, Wq, 256, 256);
    pack_w<<<256, 256, 0, stream>>>(to_out_pw, Wo, 256, 256);
    pack_w<<<256, 256, 0, stream>>>(mlp_w, Wm, 256, 256);

    // 1. x1c = conv1x1(x1)+b : split-K=4 partials -> Bb, reduce -> A
    pw_ks<16, 4><<<dim3(4, 16, 8), 256, 0, stream>>>(x1, conv_ch_w, Bb, 512, 256, 1024);
    reduce_partials<<<2048, 256, 0, stream>>>(Bb, conv_ch_b, A, 4, 256, 1024, 524288);
    // 2. residue = resize(x1c, 64,64) -> RES
    resize_bilinear<<<32768, 256, 0, stream>>>(A, RES, 256, 256 * 1024, 32, 32, 64, 64);
    // 3. BN stats x1
    bn_stats<<<512, 256, 0, stream>>>(x1, norm_l_g, norm_l_b, scale1, shift1, 512, 1024, 1e-5f);
    // 4. kv_dw = dw3(BN(x1)) -> A[0:16MB]
    bn_dw3<<<16384, 256, 0, stream>>>(x1, scale1, shift1, to_kv_dw, kv_dw, 512, 32, 32);
    // 5. kv = pw(kv_dw) : split-K=2 partials -> Bb, reduce -> A[16:32MB]
    pw_ks<16, 2><<<dim3(2, 32, 8), 256, 0, stream>>>(kv_dw, to_kv_pw, Bb, 512, 512, 1024);
    reduce_partials<<<4096, 256, 0, stream>>>(Bb, nullptr, kv, 2, 512, 1024, 1048576);
    // 6. k16, v16 = resize to 16x16
    resize_bilinear<<<2048, 256, 0, stream>>>(kv, k16, 256, 512 * 1024, 32, 32, 16, 16);
    resize_bilinear<<<2048, 256, 0, stream>>>(kv + 256 * 1024, v16, 256, 512 * 1024, 32, 32, 16, 16);
    // 7. BN stats x2
    bn_stats<<<256, 256, 0, stream>>>(x2, norm_h_g, norm_h_b, scale2, shift2, 256, 4096, 1e-5f);
    // 8. q_dw = dw3(BN(x2)) -> Xp (packed bf16)
    bn_dw3_packed<<<dim3(16, 8, 8), 256, 0, stream>>>(x2, scale2, shift2, to_q_dw, Xp, 256, 64, 64);
    // 9. q = mfma(Xp, Wq) -> A (fp32 conv layout)
    mfma_pw<0><<<dim3(64, 2, 8), 256, 0, stream>>>(Xp, Wq, nullptr, A, 256, 256, 4096);
    // 10. kn = LN(split(k16)); vh = split(v16)
    ln_split<<<2048, 256, 0, stream>>>(k16, normk_g, normk_b, kn, 256, 1, 1e-6f);
    ln_split<<<2048, 256, 0, stream>>>(v16, nullptr, nullptr, vh, 256, 0, 0.f);
    // 11. M = k^T v
    kv_outer<<<64, dim3(32, 32), 0, stream>>>(kn, vh, Mm);
    // 12. Bv = bias @ v
    bias_v<<<2048, 256, 0, stream>>>(rel_table, vh, Bv);
    // 13. o = (LN(q) @ M + Bv)/32, in-place on A
    attn_out<<<1024, 256, 0, stream>>>(A, normq_g, normq_b, Mm, Bv, A);
    // 14. out_dw = dw3(o) -> Xp (packed bf16)
    bn_dw3_packed<<<dim3(16, 8, 8), 256, 0, stream>>>(A, nullptr, nullptr, to_out_dw, Xp, 256, 64, 64);
    // 15. o2 = mfma(Xp, Wo) + RES -> A  (res2)
    mfma_pw<1><<<dim3(64, 2, 8), 256, 0, stream>>>(Xp, Wo, RES, A, 256, 256, 4096);
    // 16. BN stats o2
    bn_stats<<<256, 256, 0, stream>>>(A, norm2_g, norm2_b, scale3, shift3, 256, 4096, 1e-5f);
    // 17. r = relu(BN(o2)) -> Xp (packed bf16)
    bn_relu_packed<<<dim3(16, 8, 8), 256, 0, stream>>>(A, scale3, shift3, Xp, 256, 4096);
    // 18. out = mfma(Xp, Wm) + res2(A) -> d_out
    mfma_pw<1><<<dim3(64, 2, 8), 256, 0, stream>>>(Xp, Wm, A, Dout, 256, 256, 4096);
}

// Round 5
// 588.050 us; speedup vs baseline: 1.6422x; 1.0879x over previous
//
#include <hip/hip_runtime.h>
#include <math.h>

#define NB_   8
#define INCH  512
#define OUTCH 256
#define NHEAD 8
#define DHEAD 32

typedef __attribute__((ext_vector_type(8))) short short8v;
typedef __attribute__((ext_vector_type(4))) float f32x4;

__device__ inline short f2bf(float f) {
    unsigned u = __float_as_uint(f);
    unsigned r = u + 0x7FFFu + ((u >> 16) & 1u);
    return (short)(r >> 16);
}

// ---------------- pack fp32 weight [Co][Ci] -> bf16 packed-k layout ----------------
// packed pos within 32-k tile: (q = (k%16)/4, h = k/16, r = k%4) -> q*8 + h*4 + r
__global__ void pack_w(const float* __restrict__ W, short* __restrict__ Wp, int Co, int Ci) {
    const int idx = blockIdx.x * 256 + threadIdx.x;
    if (idx >= Co * Ci) return;
    const int m = idx / Ci, i = idx % Ci;
    const int kt = i >> 5, w32 = i & 31;
    const int h = w32 >> 4, q = (w32 & 15) >> 2, r = w32 & 3;
    Wp[m * Ci + kt * 32 + q * 8 + h * 4 + r] = f2bf(W[idx]);
}

// ---------------- pack fp32 activation [B][C][P] -> packed bf16 [B][P][C] ----------------
// grid: (P/256, C/32, B)
__global__ void pack_x(const float* __restrict__ in, short* __restrict__ outp, int C, int P) {
    const int p  = blockIdx.x * 256 + threadIdx.x;
    const int kt = blockIdx.y;
    const int b  = blockIdx.z;
#pragma unroll
    for (int q = 0; q < 4; ++q) {
        short tmp[8];
#pragma unroll
        for (int h = 0; h < 2; ++h)
#pragma unroll
            for (int r = 0; r < 4; ++r) {
                const int c = kt * 32 + h * 16 + q * 4 + r;
                tmp[h * 4 + r] = f2bf(in[((size_t)b * C + c) * P + p]);
            }
        short8v v;
#pragma unroll
        for (int j = 0; j < 8; ++j) v[j] = tmp[j];
        *reinterpret_cast<short8v*>(&outp[((size_t)b * P + p) * C + kt * 32 + q * 8]) = v;
    }
}

// ---------------- MFMA bf16 pointwise conv (GEMM): out[b,m,p] = sum_i W[m,i] X[b,i,p] ----------------
// Xp: [B][P][Ci] bf16 packed-k; Wp: [Co][Ci] bf16 packed-k.
// BM=128, BN=64, BK=32; 4 waves (2x2), wave tile 64x32.
template <int HAS_RES>
__global__ __launch_bounds__(256, 4)
void mfma_pw(const short* __restrict__ Xp, const short* __restrict__ Wp,
             const float* __restrict__ bias, const float* __restrict__ res,
             float* __restrict__ out, int Ci, int Co, int P) {
    __shared__ short Ash[4096];  // [q(4)][m(128)] 16B chunks = 8KB
    __shared__ short Bsh[2048];  // [q(4)][n(64)]  16B chunks = 4KB
    const int b   = blockIdx.z;
    const int m0  = blockIdx.y * 128;
    const int n0  = blockIdx.x * 64;
    const int tid = threadIdx.x;
    const int lane = tid & 63;
    const int wid  = tid >> 6;
    const int wr = wid >> 1, wc = wid & 1;
    const int ql = lane >> 4, l16 = lane & 15;

    f32x4 acc[4][2];
#pragma unroll
    for (int mb = 0; mb < 4; ++mb)
#pragma unroll
        for (int nb = 0; nb < 2; ++nb) acc[mb][nb] = (f32x4){0.f, 0.f, 0.f, 0.f};

    const int sm_ = tid & 127;  // A stage: m
    const int sq_ = tid >> 7;   // A stage: q sub
    const int bn_ = tid & 63;   // B stage: n
    const int bq_ = tid >> 6;   // B stage: q

    const size_t wrow = (size_t)(m0 + sm_) * Ci;
    const size_t xrow = ((size_t)b * P + n0 + bn_) * Ci;

    const int nkt = Ci >> 5;
    for (int kt = 0; kt < nkt; ++kt) {
        const int kof = kt * 32;
#pragma unroll
        for (int r = 0; r < 2; ++r) {
            const int q = r * 2 + sq_;
            __builtin_amdgcn_global_load_lds(Wp + wrow + kof + q * 8, &Ash[r * 2048 + tid * 8], 16, 0, 0);
        }
        __builtin_amdgcn_global_load_lds(Xp + xrow + kof + bq_ * 8, &Bsh[tid * 8], 16, 0, 0);
        __syncthreads();

        short8v a[4], bf[2];
#pragma unroll
        for (int mb = 0; mb < 4; ++mb)
            a[mb] = *reinterpret_cast<const short8v*>(&Ash[ql * 1024 + (wr * 64 + mb * 16 + l16) * 8]);
#pragma unroll
        for (int nb = 0; nb < 2; ++nb)
            bf[nb] = *reinterpret_cast<const short8v*>(&Bsh[ql * 512 + (wc * 32 + nb * 16 + l16) * 8]);
#pragma unroll
        for (int mb = 0; mb < 4; ++mb)
#pragma unroll
            for (int nb = 0; nb < 2; ++nb)
                acc[mb][nb] = __builtin_amdgcn_mfma_f32_16x16x32_bf16(a[mb], bf[nb], acc[mb][nb], 0, 0, 0);
        __syncthreads();
    }

#pragma unroll
    for (int mb = 0; mb < 4; ++mb) {
        const int row = m0 + wr * 64 + mb * 16 + ql * 4;
#pragma unroll
        for (int nb = 0; nb < 2; ++nb) {
            const int col = n0 + wc * 32 + nb * 16 + l16;
            const size_t base = ((size_t)b * Co + row) * P + col;
#pragma unroll
            for (int j = 0; j < 4; ++j) {
                float v = acc[mb][nb][j];
                if (bias) v += bias[row + j];
                if (HAS_RES) v += res[base + (size_t)j * P];
                out[base + (size_t)j * P] = v;
            }
        }
    }
}

// ---------------- (optional BN) + depthwise 3x3 -> packed bf16 X layout ----------------
// grid: (P/256, C/32, B). thread = pixel; handles 32 channels (one 32-k tile).
__global__ void bn_dw3_packed(const float* __restrict__ in, const float* __restrict__ scale,
                              const float* __restrict__ shift, const float* __restrict__ dw,
                              short* __restrict__ outp, int C, int H, int W) {
    const int p  = blockIdx.x * 256 + threadIdx.x;
    const int kt = blockIdx.y;
    const int b  = blockIdx.z;
    const int y = p / W, x = p % W;
    const int P = H * W;
#pragma unroll
    for (int q = 0; q < 4; ++q) {
        short tmp[8];
#pragma unroll
        for (int h = 0; h < 2; ++h)
#pragma unroll
            for (int r = 0; r < 4; ++r) {
                const int c = kt * 32 + h * 16 + q * 4 + r;
                const float sc = scale ? scale[c] : 1.f;
                const float sh = shift ? shift[c] : 0.f;
                const float* base = in + ((size_t)b * C + c) * P;
                const float* w = dw + c * 9;
                float acc = 0.f;
#pragma unroll
                for (int dy = 0; dy < 3; ++dy) {
                    const int yy = y + dy - 1;
                    if (yy < 0 || yy >= H) continue;
#pragma unroll
                    for (int dx = 0; dx < 3; ++dx) {
                        const int xx = x + dx - 1;
                        if (xx < 0 || xx >= W) continue;
                        acc += w[dy * 3 + dx] * (base[yy * W + xx] * sc + sh);
                    }
                }
                tmp[h * 4 + r] = f2bf(acc);
            }
        short8v v;
#pragma unroll
        for (int j = 0; j < 8; ++j) v[j] = tmp[j];
        *reinterpret_cast<short8v*>(&outp[((size_t)b * P + p) * C + kt * 32 + q * 8]) = v;
    }
}

// ---------------- BN + ReLU -> packed bf16 X layout ----------------
__global__ void bn_relu_packed(const float* __restrict__ in, const float* __restrict__ scale,
                               const float* __restrict__ shift, short* __restrict__ outp,
                               int C, int P) {
    const int p  = blockIdx.x * 256 + threadIdx.x;
    const int kt = blockIdx.y;
    const int b  = blockIdx.z;
#pragma unroll
    for (int q = 0; q < 4; ++q) {
        short tmp[8];
#pragma unroll
        for (int h = 0; h < 2; ++h)
#pragma unroll
            for (int r = 0; r < 4; ++r) {
                const int c = kt * 32 + h * 16 + q * 4 + r;
                const float v = in[((size_t)b * C + c) * P + p] * scale[c] + shift[c];
                tmp[h * 4 + r] = f2bf(v > 0.f ? v : 0.f);
            }
        short8v v;
#pragma unroll
        for (int j = 0; j < 8; ++j) v[j] = tmp[j];
        *reinterpret_cast<short8v*>(&outp[((size_t)b * P + p) * C + kt * 32 + q * 8]) = v;
    }
}

// ---------------- bilinear resize ----------------
__global__ void resize_bilinear(const float* __restrict__ in, float* __restrict__ out,
                                int C, int ibs, int Hi, int Wi, int Ho, int Wo) {
    const int idx = blockIdx.x * 256 + threadIdx.x;
    const int total = NB_ * C * Ho * Wo;
    if (idx >= total) return;
    const int x = idx % Wo;
    const int y = (idx / Wo) % Ho;
    const int c = (idx / (Wo * Ho)) % C;
    const int b = idx / (Wo * Ho * C);
    const float fy = (float)y * (float)(Hi - 1) / (float)(Ho - 1);
    const float fx = (float)x * (float)(Wi - 1) / (float)(Wo - 1);
    int y0 = (int)floorf(fy); int y1 = min(y0 + 1, Hi - 1); const float wy = fy - (float)y0;
    int x0 = (int)floorf(fx); int x1 = min(x0 + 1, Wi - 1); const float wx = fx - (float)x0;
    const float* pc = in + (size_t)b * ibs + (size_t)c * Hi * Wi;
    const float r0 = pc[y0 * Wi + x0] * (1.f - wx) + pc[y0 * Wi + x1] * wx;
    const float r1 = pc[y1 * Wi + x0] * (1.f - wx) + pc[y1 * Wi + x1] * wx;
    out[idx] = r0 * (1.f - wy) + r1 * wy;
}

// ---------------- BN stats ----------------
__global__ void bn_stats(const float* __restrict__ in, const float* __restrict__ g,
                         const float* __restrict__ bt, float* __restrict__ scale,
                         float* __restrict__ shift, int C, int HW, float eps) {
    const int c = blockIdx.x;
    float s1 = 0.f, s2 = 0.f;
    for (int b = 0; b < NB_; ++b) {
        const float* p = in + ((size_t)b * C + c) * HW;
        for (int r = threadIdx.x; r < HW; r += 256) {
            const float v = p[r];
            s1 += v; s2 += v * v;
        }
    }
    __shared__ float sh1[256], sh2[256];
    sh1[threadIdx.x] = s1; sh2[threadIdx.x] = s2;
    __syncthreads();
    for (int s = 128; s > 0; s >>= 1) {
        if (threadIdx.x < s) { sh1[threadIdx.x] += sh1[threadIdx.x + s]; sh2[threadIdx.x] += sh2[threadIdx.x + s]; }
        __syncthreads();
    }
    if (threadIdx.x == 0) {
        const float N = (float)(NB_ * HW);
        const float m = sh1[0] / N;
        const float var = sh2[0] / N - m * m;
        const float sc = g[c] * rsqrtf(var + eps);
        scale[c] = sc;
        shift[c] = bt[c] - m * sc;
    }
}

// ---------------- LN (optional) + split heads ----------------
__global__ void ln_split(const float* __restrict__ in, const float* __restrict__ g,
                         const float* __restrict__ bt, float* __restrict__ out,
                         int HW, int applyLN, float eps) {
    const int row = blockIdx.x * 8 + (threadIdx.x >> 5);
    const int d = threadIdx.x & 31;
    const int j = row % HW;
    const int h = (row / HW) % NHEAD;
    const int b = row / (HW * NHEAD);
    float v = in[((size_t)b * OUTCH + d * NHEAD + h) * HW + j];
    if (applyLN) {
        float s1 = v, s2 = v * v;
#pragma unroll
        for (int o = 16; o >= 1; o >>= 1) {
            s1 += __shfl_xor(s1, o, 32);
            s2 += __shfl_xor(s2, o, 32);
        }
        const float m = s1 * (1.f / 32.f);
        const float var = s2 * (1.f / 32.f) - m * m;
        v = (v - m) * rsqrtf(var + eps) * g[h * 32 + d] + bt[h * 32 + d];
    }
    out[((size_t)(b * NHEAD + h) * HW + j) * 32 + d] = v;
}

// ---------------- M = k^T v ----------------
__global__ void kv_outer(const float* __restrict__ kn, const float* __restrict__ vh,
                         float* __restrict__ M) {
    __shared__ float vs[256][32];
    const int bh = blockIdx.x;
    const float* kp = kn + (size_t)bh * 256 * 32;
    const float* vp = vh + (size_t)bh * 256 * 32;
    const int tid = threadIdx.y * 32 + threadIdx.x;
    for (int t = tid; t < 256 * 32; t += 1024) vs[t >> 5][t & 31] = vp[t];
    __syncthreads();
    const int e = threadIdx.x, dd = threadIdx.y;
    float acc = 0.f;
    for (int j = 0; j < 256; ++j) acc += kp[j * 32 + e] * vs[j][dd];
    M[((size_t)bh * 32 + e) * 32 + dd] = acc;
}

// ---------------- Bv = bias @ v ----------------
__global__ void bias_v(const float* __restrict__ rel, const float* __restrict__ vh,
                       float* __restrict__ Bv) {
    const int gid = blockIdx.x * 8 + (threadIdx.x >> 5);
    const int d = threadIdx.x & 31;
    const int qb = gid % 256;
    const int h = (gid / 256) % NHEAD;
    const int b = gid / (256 * NHEAD);
    const int qy = qb >> 4, qx = qb & 15;
    const float* vp = vh + (size_t)(b * NHEAD + h) * 256 * 32;
    float acc = 0.f;
    for (int j = 0; j < 256; ++j) {
        const int ky = j >> 4, kx = j & 15;
        const float bias = rel[((qy - ky + 15) * 31 + (qx - kx + 15)) * NHEAD + h];
        acc += bias * vp[j * 32 + d];
    }
    Bv[((size_t)(b * NHEAD + h) * 256 + qb) * 32 + d] = acc;
}

// ---------------- attention out: o = (LN(q) @ M + Bv)/32 (in-place safe) ----------------
__global__ void attn_out(const float* __restrict__ q, const float* __restrict__ gq,
                         const float* __restrict__ bq, const float* __restrict__ M,
                         const float* __restrict__ Bv, float* __restrict__ o) {
    const int gid = blockIdx.x * 256 + threadIdx.x;
    const int i = gid % 4096;
    const int h = (gid / 4096) % NHEAD;
    const int b = gid / (4096 * NHEAD);
    const int y = i >> 6, x = i & 63;
    const int qb = (y >> 2) * 16 + (x >> 2);

    const float* qp = q + (size_t)b * OUTCH * 4096 + h * 4096 + i;
    float qv[32];
    float s1 = 0.f, s2 = 0.f;
#pragma unroll
    for (int d = 0; d < 32; ++d) {
        const float v = qp[(size_t)d * NHEAD * 4096];
        qv[d] = v; s1 += v; s2 += v * v;
    }
    const float m = s1 * (1.f / 32.f);
    const float var = s2 * (1.f / 32.f) - m * m;
    const float rs = rsqrtf(var + 1e-6f);
#pragma unroll
    for (int d = 0; d < 32; ++d)
        qv[d] = (qv[d] - m) * rs * gq[h * 32 + d] + bq[h * 32 + d];

    const float* Mp = M + (size_t)(b * NHEAD + h) * 32 * 32;
    const float* Bp = Bv + ((size_t)(b * NHEAD + h) * 256 + qb) * 32;
    float acc[32];
#pragma unroll
    for (int d = 0; d < 32; ++d) acc[d] = Bp[d];
#pragma unroll
    for (int e = 0; e < 32; ++e) {
        const float qe = qv[e];
#pragma unroll
        for (int d = 0; d < 32; ++d) acc[d] += qe * Mp[e * 32 + d];
    }
    float* op = o + (size_t)b * OUTCH * 4096 + h * 4096 + i;
#pragma unroll
    for (int d = 0; d < 32; ++d) op[(size_t)d * NHEAD * 4096] = acc[d] * (1.f / 32.f);
}

extern "C" void kernel_launch(void* const* d_in, const int* in_sizes, int n_in,
                              void* d_out, int out_size, void* d_ws, size_t ws_size,
                              hipStream_t stream) {
    const float* x1        = (const float*)d_in[0];
    const float* x2        = (const float*)d_in[1];
    const float* conv_ch_w = (const float*)d_in[2];
    const float* conv_ch_b = (const float*)d_in[3];
    const float* norm_l_g  = (const float*)d_in[4];
    const float* norm_l_b  = (const float*)d_in[5];
    const float* norm_h_g  = (const float*)d_in[6];
    const float* norm_h_b  = (const float*)d_in[7];
    const float* to_kv_dw  = (const float*)d_in[8];
    const float* to_kv_pw  = (const float*)d_in[9];
    const float* to_q_dw   = (const float*)d_in[10];
    const float* to_q_pw   = (const float*)d_in[11];
    const float* to_out_dw = (const float*)d_in[12];
    const float* to_out_pw = (const float*)d_in[13];
    const float* rel_table = (const float*)d_in[14];
    const float* normq_g   = (const float*)d_in[15];
    const float* normq_b   = (const float*)d_in[16];
    const float* normk_g   = (const float*)d_in[17];
    const float* normk_b   = (const float*)d_in[18];
    const float* norm2_g   = (const float*)d_in[19];
    const float* norm2_b   = (const float*)d_in[20];
    const float* mlp_w     = (const float*)d_in[21];
    float* Dout = (float*)d_out;

    float* ws = (float*)d_ws;
    const size_t NBIG = (size_t)NB_ * OUTCH * 4096;  // 8388608 floats (32 MB)
    float* RES = ws;
    float* A   = ws + NBIG;
    float* Bb  = ws + 2 * NBIG;
    float* sm  = ws + 3 * NBIG;
    float* scale1 = sm;            float* shift1 = sm + 512;
    float* scale2 = sm + 1024;     float* shift2 = sm + 1280;
    float* scale3 = sm + 1536;     float* shift3 = sm + 1792;
    float* k16 = sm + 2048;
    float* v16 = k16 + 524288;
    float* kn  = v16 + 524288;
    float* vh  = kn  + 524288;
    float* Mm  = vh  + 524288;
    float* Bv  = Mm  + 65536;
    short* Wq  = (short*)(Bv + 524288);
    short* Wo  = Wq + 65536;
    short* Wm  = Wo + 65536;
    short* Wc  = Wm + 65536;       // conv_ch_w packed: 256x512
    short* Wkv = Wc + 131072;      // to_kv_pw packed: 512x512

    short* Xp1 = (short*)Bb;             // x1 packed: 8 MB (4M shorts)
    short* Xp2 = (short*)Bb + 4194304;   // kv_dw packed: 8 MB
    short* Xp  = (short*)Bb;             // big packed X (16.8 MB), used steps 8+
    float* kv  = A;                      // 16 MB fp32 [8,512,1024] (after x1c dead)

    // 0. pack the five pointwise weights to bf16 packed layout
    pack_w<<<256, 256, 0, stream>>>(to_q_pw, Wq, 256, 256);
    pack_w<<<256, 256, 0, stream>>>(to_out_pw, Wo, 256, 256);
    pack_w<<<256, 256, 0, stream>>>(mlp_w, Wm, 256, 256);
    pack_w<<<512, 256, 0, stream>>>(conv_ch_w, Wc, 256, 512);
    pack_w<<<1024, 256, 0, stream>>>(to_kv_pw, Wkv, 512, 512);

    // 1. x1 -> packed bf16; x1c = mfma(x1p, Wc) + bias -> A (fp32 [8,256,1024])
    pack_x<<<dim3(4, 16, 8), 256, 0, stream>>>(x1, Xp1, 512, 1024);
    mfma_pw<0><<<dim3(16, 2, 8), 256, 0, stream>>>(Xp1, Wc, conv_ch_b, nullptr, A, 512, 256, 1024);
    // 2. residue = resize(x1c, 64,64) -> RES
    resize_bilinear<<<32768, 256, 0, stream>>>(A, RES, 256, 256 * 1024, 32, 32, 64, 64);
    // 3. BN stats x1
    bn_stats<<<512, 256, 0, stream>>>(x1, norm_l_g, norm_l_b, scale1, shift1, 512, 1024, 1e-5f);
    // 4. kv_dw = dw3(BN(x1)) -> Xp2 (packed bf16)
    bn_dw3_packed<<<dim3(4, 16, 8), 256, 0, stream>>>(x1, scale1, shift1, to_kv_dw, Xp2, 512, 32, 32);
    // 5. kv = mfma(Xp2, Wkv) -> A (fp32 [8,512,1024]; x1c region dead after step 2)
    mfma_pw<0><<<dim3(16, 4, 8), 256, 0, stream>>>(Xp2, Wkv, nullptr, nullptr, kv, 512, 512, 1024);
    // 6. k16, v16 = resize to 16x16
    resize_bilinear<<<2048, 256, 0, stream>>>(kv, k16, 256, 512 * 1024, 32, 32, 16, 16);
    resize_bilinear<<<2048, 256, 0, stream>>>(kv + 256 * 1024, v16, 256, 512 * 1024, 32, 32, 16, 16);
    // 7. BN stats x2
    bn_stats<<<256, 256, 0, stream>>>(x2, norm_h_g, norm_h_b, scale2, shift2, 256, 4096, 1e-5f);
    // 8. q_dw = dw3(BN(x2)) -> Xp (packed bf16; Xp1/Xp2 dead after step 5)
    bn_dw3_packed<<<dim3(16, 8, 8), 256, 0, stream>>>(x2, scale2, shift2, to_q_dw, Xp, 256, 64, 64);
    // 9. q = mfma(Xp, Wq) -> A (fp32 conv layout; kv dead after step 6)
    mfma_pw<0><<<dim3(64, 2, 8), 256, 0, stream>>>(Xp, Wq, nullptr, nullptr, A, 256, 256, 4096);
    // 10. kn = LN(split(k16)); vh = split(v16)
    ln_split<<<2048, 256, 0, stream>>>(k16, normk_g, normk_b, kn, 256, 1, 1e-6f);
    ln_split<<<2048, 256, 0, stream>>>(v16, nullptr, nullptr, vh, 256, 0, 0.f);
    // 11. M = k^T v
    kv_outer<<<64, dim3(32, 32), 0, stream>>>(kn, vh, Mm);
    // 12. Bv = bias @ v
    bias_v<<<2048, 256, 0, stream>>>(rel_table, vh, Bv);
    // 13. o = (LN(q) @ M + Bv)/32, in-place on A
    attn_out<<<1024, 256, 0, stream>>>(A, normq_g, normq_b, Mm, Bv, A);
    // 14. out_dw = dw3(o) -> Xp (packed bf16)
    bn_dw3_packed<<<dim3(16, 8, 8), 256, 0, stream>>>(A, nullptr, nullptr, to_out_dw, Xp, 256, 64, 64);
    // 15. o2 = mfma(Xp, Wo) + RES -> A  (res2)
    mfma_pw<1><<<dim3(64, 2, 8), 256, 0, stream>>>(Xp, Wo, nullptr, RES, A, 256, 256, 4096);
    // 16. BN stats o2
    bn_stats<<<256, 256, 0, stream>>>(A, norm2_g, norm2_b, scale3, shift3, 256, 4096, 1e-5f);
    // 17. r = relu(BN(o2)) -> Xp (packed bf16)
    bn_relu_packed<<<dim3(16, 8, 8), 256, 0, stream>>>(A, scale3, shift3, Xp, 256, 4096);
    // 18. out = mfma(Xp, Wm) + res2(A) -> d_out
    mfma_pw<1><<<dim3(64, 2, 8), 256, 0, stream>>>(Xp, Wm, nullptr, A, Dout, 256, 256, 4096);
}

// Round 6
// 493.107 us; speedup vs baseline: 1.9584x; 1.1925x over previous
//
#include <hip/hip_runtime.h>
#include <math.h>

#define NB_   8
#define INCH  512
#define OUTCH 256
#define NHEAD 8
#define DHEAD 32

typedef __attribute__((ext_vector_type(8))) short short8v;
typedef __attribute__((ext_vector_type(4))) float f32x4;

__device__ inline short f2bf(float f) {
    unsigned u = __float_as_uint(f);
    unsigned r = u + 0x7FFFu + ((u >> 16) & 1u);
    return (short)(r >> 16);
}

// ---------------- pack fp32 weight [Co][Ci] -> bf16 packed-k layout ----------------
// packed pos within 32-k tile: (q = (k%16)/4, h = k/16, r = k%4) -> q*8 + h*4 + r
__global__ void pack_w(const float* __restrict__ W, short* __restrict__ Wp, int Co, int Ci) {
    const int idx = blockIdx.x * 256 + threadIdx.x;
    if (idx >= Co * Ci) return;
    const int m = idx / Ci, i = idx % Ci;
    const int kt = i >> 5, w32 = i & 31;
    const int h = w32 >> 4, q = (w32 & 15) >> 2, r = w32 & 3;
    Wp[m * Ci + kt * 32 + q * 8 + h * 4 + r] = f2bf(W[idx]);
}

// ---------------- LDS-staged pack: fp32 [B][C][P] -> packed bf16 [B][P][C] ----------------
// optional BN(scale/shift) + ReLU at staging. grid: (P/256, C/32, B)
template <int BN_RELU>
__global__ __launch_bounds__(256, 4)
void pack_tile(const float* __restrict__ in, const float* __restrict__ scale,
               const float* __restrict__ shift, short* __restrict__ outp, int C, int P) {
    __shared__ float s[32][256];
    const int tid = threadIdx.x;
    const int p0 = blockIdx.x * 256;
    const int kt = blockIdx.y;
    const int b  = blockIdx.z;
#pragma unroll
    for (int c = 0; c < 32; ++c) {
        const int gc = kt * 32 + c;
        float v = in[((size_t)b * C + gc) * P + p0 + tid];
        if (BN_RELU) {
            v = v * scale[gc] + shift[gc];
            v = v > 0.f ? v : 0.f;
        }
        s[c][tid] = v;
    }
    __syncthreads();
    short* op = outp + ((size_t)b * P + p0 + tid) * C + kt * 32;
#pragma unroll
    for (int q = 0; q < 4; ++q) {
        short8v v;
#pragma unroll
        for (int h = 0; h < 2; ++h)
#pragma unroll
            for (int r = 0; r < 4; ++r)
                v[h * 4 + r] = f2bf(s[h * 16 + q * 4 + r][tid]);
        *reinterpret_cast<short8v*>(op + q * 8) = v;
    }
}

// ---------------- LDS-staged (optional BN) + depthwise 3x3 -> packed bf16 ----------------
// block: 32 channels x BH_ output rows (256 px). Stage (BH_+2)x(W_+2) BN'd tile per channel.
// grid: (H/BH_, C/32, B)
template <int W_, int BH_>
__global__ __launch_bounds__(256, 3)
void dw3_pack(const float* __restrict__ in, const float* __restrict__ scale,
              const float* __restrict__ shift, const float* __restrict__ dw,
              short* __restrict__ outp, int C, int H) {
    constexpr int PADW = W_ + 2;
    constexpr int ROWS = BH_ + 2;
    __shared__ float s[32][ROWS][PADW];
    const int tid = threadIdx.x;
    const int y0  = blockIdx.x * BH_;
    const int kt  = blockIdx.y;
    const int b   = blockIdx.z;
    const int P   = H * W_;

    // zero the x-halo columns
    for (int i = tid; i < 32 * ROWS; i += 256) {
        const int c = i / ROWS, row = i % ROWS;
        s[c][row][0] = 0.f;
        s[c][row][W_ + 1] = 0.f;
    }
    // stage interior (BN applied; y-halo rows zero)
    const int tot = 32 * ROWS * W_;
    for (int i = tid; i < tot; i += 256) {
        const int x   = i % W_;
        const int row = (i / W_) % ROWS;
        const int c   = i / (W_ * ROWS);
        const int gy  = y0 - 1 + row;
        const int gc  = kt * 32 + c;
        float v = 0.f;
        if (gy >= 0 && gy < H) {
            v = in[((size_t)b * C + gc) * P + gy * W_ + x];
            if (scale) v = v * scale[gc] + shift[gc];
        }
        s[c][row][x + 1] = v;
    }
    __syncthreads();

    const int ly = tid / W_;   // 0..BH_-1
    const int lx = tid % W_;
    float res[32];
#pragma unroll
    for (int c = 0; c < 32; ++c) {
        const float* wp = dw + (size_t)(kt * 32 + c) * 9;
        float acc = 0.f;
#pragma unroll
        for (int dy = 0; dy < 3; ++dy)
#pragma unroll
            for (int dx = 0; dx < 3; ++dx)
                acc += wp[dy * 3 + dx] * s[c][ly + dy][lx + dx];
        res[c] = acc;
    }
    const int p = (y0 + ly) * W_ + lx;
    short* op = outp + ((size_t)b * P + p) * C + kt * 32;
#pragma unroll
    for (int q = 0; q < 4; ++q) {
        short8v v;
#pragma unroll
        for (int h = 0; h < 2; ++h)
#pragma unroll
            for (int r = 0; r < 4; ++r)
                v[h * 4 + r] = f2bf(res[h * 16 + q * 4 + r]);
        *reinterpret_cast<short8v*>(op + q * 8) = v;
    }
}

// ---------------- MFMA bf16 pointwise conv (GEMM): out[b,m,p] = sum_i W[m,i] X[b,i,p] ----------------
// Xp: [B][P][Ci] bf16 packed-k; Wp: [Co][Ci] bf16 packed-k.
// BM=128, BN=64, BK=32; 4 waves (2x2), wave tile 64x32.
template <int HAS_RES>
__global__ __launch_bounds__(256, 4)
void mfma_pw(const short* __restrict__ Xp, const short* __restrict__ Wp,
             const float* __restrict__ bias, const float* __restrict__ res,
             float* __restrict__ out, int Ci, int Co, int P) {
    __shared__ short Ash[4096];  // [q(4)][m(128)] 16B chunks = 8KB
    __shared__ short Bsh[2048];  // [q(4)][n(64)]  16B chunks = 4KB
    const int b   = blockIdx.z;
    const int m0  = blockIdx.y * 128;
    const int n0  = blockIdx.x * 64;
    const int tid = threadIdx.x;
    const int lane = tid & 63;
    const int wid  = tid >> 6;
    const int wr = wid >> 1, wc = wid & 1;
    const int ql = lane >> 4, l16 = lane & 15;

    f32x4 acc[4][2];
#pragma unroll
    for (int mb = 0; mb < 4; ++mb)
#pragma unroll
        for (int nb = 0; nb < 2; ++nb) acc[mb][nb] = (f32x4){0.f, 0.f, 0.f, 0.f};

    const int sm_ = tid & 127;  // A stage: m
    const int sq_ = tid >> 7;   // A stage: q sub
    const int bn_ = tid & 63;   // B stage: n
    const int bq_ = tid >> 6;   // B stage: q

    const size_t wrow = (size_t)(m0 + sm_) * Ci;
    const size_t xrow = ((size_t)b * P + n0 + bn_) * Ci;

    const int nkt = Ci >> 5;
    for (int kt = 0; kt < nkt; ++kt) {
        const int kof = kt * 32;
#pragma unroll
        for (int r = 0; r < 2; ++r) {
            const int q = r * 2 + sq_;
            __builtin_amdgcn_global_load_lds(Wp + wrow + kof + q * 8, &Ash[r * 2048 + tid * 8], 16, 0, 0);
        }
        __builtin_amdgcn_global_load_lds(Xp + xrow + kof + bq_ * 8, &Bsh[tid * 8], 16, 0, 0);
        __syncthreads();

        short8v a[4], bf[2];
#pragma unroll
        for (int mb = 0; mb < 4; ++mb)
            a[mb] = *reinterpret_cast<const short8v*>(&Ash[ql * 1024 + (wr * 64 + mb * 16 + l16) * 8]);
#pragma unroll
        for (int nb = 0; nb < 2; ++nb)
            bf[nb] = *reinterpret_cast<const short8v*>(&Bsh[ql * 512 + (wc * 32 + nb * 16 + l16) * 8]);
#pragma unroll
        for (int mb = 0; mb < 4; ++mb)
#pragma unroll
            for (int nb = 0; nb < 2; ++nb)
                acc[mb][nb] = __builtin_amdgcn_mfma_f32_16x16x32_bf16(a[mb], bf[nb], acc[mb][nb], 0, 0, 0);
        __syncthreads();
    }

#pragma unroll
    for (int mb = 0; mb < 4; ++mb) {
        const int row = m0 + wr * 64 + mb * 16 + ql * 4;
#pragma unroll
        for (int nb = 0; nb < 2; ++nb) {
            const int col = n0 + wc * 32 + nb * 16 + l16;
            const size_t base = ((size_t)b * Co + row) * P + col;
#pragma unroll
            for (int j = 0; j < 4; ++j) {
                float v = acc[mb][nb][j];
                if (bias) v += bias[row + j];
                if (HAS_RES) v += res[base + (size_t)j * P];
                out[base + (size_t)j * P] = v;
            }
        }
    }
}

// ---------------- bilinear resize ----------------
__global__ void resize_bilinear(const float* __restrict__ in, float* __restrict__ out,
                                int C, int ibs, int Hi, int Wi, int Ho, int Wo) {
    const int idx = blockIdx.x * 256 + threadIdx.x;
    const int total = NB_ * C * Ho * Wo;
    if (idx >= total) return;
    const int x = idx % Wo;
    const int y = (idx / Wo) % Ho;
    const int c = (idx / (Wo * Ho)) % C;
    const int b = idx / (Wo * Ho * C);
    const float fy = (float)y * (float)(Hi - 1) / (float)(Ho - 1);
    const float fx = (float)x * (float)(Wi - 1) / (float)(Wo - 1);
    int y0 = (int)floorf(fy); int y1 = min(y0 + 1, Hi - 1); const float wy = fy - (float)y0;
    int x0 = (int)floorf(fx); int x1 = min(x0 + 1, Wi - 1); const float wx = fx - (float)x0;
    const float* pc = in + (size_t)b * ibs + (size_t)c * Hi * Wi;
    const float r0 = pc[y0 * Wi + x0] * (1.f - wx) + pc[y0 * Wi + x1] * wx;
    const float r1 = pc[y1 * Wi + x0] * (1.f - wx) + pc[y1 * Wi + x1] * wx;
    out[idx] = r0 * (1.f - wy) + r1 * wy;
}

// ---------------- BN stats ----------------
__global__ void bn_stats(const float* __restrict__ in, const float* __restrict__ g,
                         const float* __restrict__ bt, float* __restrict__ scale,
                         float* __restrict__ shift, int C, int HW, float eps) {
    const int c = blockIdx.x;
    float s1 = 0.f, s2 = 0.f;
    for (int b = 0; b < NB_; ++b) {
        const float* p = in + ((size_t)b * C + c) * HW;
        for (int r = threadIdx.x; r < HW; r += 256) {
            const float v = p[r];
            s1 += v; s2 += v * v;
        }
    }
    __shared__ float sh1[256], sh2[256];
    sh1[threadIdx.x] = s1; sh2[threadIdx.x] = s2;
    __syncthreads();
    for (int s = 128; s > 0; s >>= 1) {
        if (threadIdx.x < s) { sh1[threadIdx.x] += sh1[threadIdx.x + s]; sh2[threadIdx.x] += sh2[threadIdx.x + s]; }
        __syncthreads();
    }
    if (threadIdx.x == 0) {
        const float N = (float)(NB_ * HW);
        const float m = sh1[0] / N;
        const float var = sh2[0] / N - m * m;
        const float sc = g[c] * rsqrtf(var + eps);
        scale[c] = sc;
        shift[c] = bt[c] - m * sc;
    }
}

// ---------------- LN (optional) + split heads ----------------
__global__ void ln_split(const float* __restrict__ in, const float* __restrict__ g,
                         const float* __restrict__ bt, float* __restrict__ out,
                         int HW, int applyLN, float eps) {
    const int row = blockIdx.x * 8 + (threadIdx.x >> 5);
    const int d = threadIdx.x & 31;
    const int j = row % HW;
    const int h = (row / HW) % NHEAD;
    const int b = row / (HW * NHEAD);
    float v = in[((size_t)b * OUTCH + d * NHEAD + h) * HW + j];
    if (applyLN) {
        float s1 = v, s2 = v * v;
#pragma unroll
        for (int o = 16; o >= 1; o >>= 1) {
            s1 += __shfl_xor(s1, o, 32);
            s2 += __shfl_xor(s2, o, 32);
        }
        const float m = s1 * (1.f / 32.f);
        const float var = s2 * (1.f / 32.f) - m * m;
        v = (v - m) * rsqrtf(var + eps) * g[h * 32 + d] + bt[h * 32 + d];
    }
    out[((size_t)(b * NHEAD + h) * HW + j) * 32 + d] = v;
}

// ---------------- M = k^T v ----------------
__global__ void kv_outer(const float* __restrict__ kn, const float* __restrict__ vh,
                         float* __restrict__ M) {
    __shared__ float vs[256][32];
    const int bh = blockIdx.x;
    const float* kp = kn + (size_t)bh * 256 * 32;
    const float* vp = vh + (size_t)bh * 256 * 32;
    const int tid = threadIdx.y * 32 + threadIdx.x;
    for (int t = tid; t < 256 * 32; t += 1024) vs[t >> 5][t & 31] = vp[t];
    __syncthreads();
    const int e = threadIdx.x, dd = threadIdx.y;
    float acc = 0.f;
    for (int j = 0; j < 256; ++j) acc += kp[j * 32 + e] * vs[j][dd];
    M[((size_t)bh * 32 + e) * 32 + dd] = acc;
}

// ---------------- Bv = bias @ v ----------------
__global__ void bias_v(const float* __restrict__ rel, const float* __restrict__ vh,
                       float* __restrict__ Bv) {
    const int gid = blockIdx.x * 8 + (threadIdx.x >> 5);
    const int d = threadIdx.x & 31;
    const int qb = gid % 256;
    const int h = (gid / 256) % NHEAD;
    const int b = gid / (256 * NHEAD);
    const int qy = qb >> 4, qx = qb & 15;
    const float* vp = vh + (size_t)(b * NHEAD + h) * 256 * 32;
    float acc = 0.f;
    for (int j = 0; j < 256; ++j) {
        const int ky = j >> 4, kx = j & 15;
        const float bias = rel[((qy - ky + 15) * 31 + (qx - kx + 15)) * NHEAD + h];
        acc += bias * vp[j * 32 + d];
    }
    Bv[((size_t)(b * NHEAD + h) * 256 + qb) * 32 + d] = acc;
}

// ---------------- attention out: o = (LN(q) @ M + Bv)/32 (in-place safe) ----------------
__global__ void attn_out(const float* __restrict__ q, const float* __restrict__ gq,
                         const float* __restrict__ bq, const float* __restrict__ M,
                         const float* __restrict__ Bv, float* __restrict__ o) {
    const int gid = blockIdx.x * 256 + threadIdx.x;
    const int i = gid % 4096;
    const int h = (gid / 4096) % NHEAD;
    const int b = gid / (4096 * NHEAD);
    const int y = i >> 6, x = i & 63;
    const int qb = (y >> 2) * 16 + (x >> 2);

    const float* qp = q + (size_t)b * OUTCH * 4096 + h * 4096 + i;
    float qv[32];
    float s1 = 0.f, s2 = 0.f;
#pragma unroll
    for (int d = 0; d < 32; ++d) {
        const float v = qp[(size_t)d * NHEAD * 4096];
        qv[d] = v; s1 += v; s2 += v * v;
    }
    const float m = s1 * (1.f / 32.f);
    const float var = s2 * (1.f / 32.f) - m * m;
    const float rs = rsqrtf(var + 1e-6f);
#pragma unroll
    for (int d = 0; d < 32; ++d)
        qv[d] = (qv[d] - m) * rs * gq[h * 32 + d] + bq[h * 32 + d];

    const float* Mp = M + (size_t)(b * NHEAD + h) * 32 * 32;
    const float* Bp = Bv + ((size_t)(b * NHEAD + h) * 256 + qb) * 32;
    float acc[32];
#pragma unroll
    for (int d = 0; d < 32; ++d) acc[d] = Bp[d];
#pragma unroll
    for (int e = 0; e < 32; ++e) {
        const float qe = qv[e];
#pragma unroll
        for (int d = 0; d < 32; ++d) acc[d] += qe * Mp[e * 32 + d];
    }
    float* op = o + (size_t)b * OUTCH * 4096 + h * 4096 + i;
#pragma unroll
    for (int d = 0; d < 32; ++d) op[(size_t)d * NHEAD * 4096] = acc[d] * (1.f / 32.f);
}

extern "C" void kernel_launch(void* const* d_in, const int* in_sizes, int n_in,
                              void* d_out, int out_size, void* d_ws, size_t ws_size,
                              hipStream_t stream) {
    const float* x1        = (const float*)d_in[0];
    const float* x2        = (const float*)d_in[1];
    const float* conv_ch_w = (const float*)d_in[2];
    const float* conv_ch_b = (const float*)d_in[3];
    const float* norm_l_g  = (const float*)d_in[4];
    const float* norm_l_b  = (const float*)d_in[5];
    const float* norm_h_g  = (const float*)d_in[6];
    const float* norm_h_b  = (const float*)d_in[7];
    const float* to_kv_dw  = (const float*)d_in[8];
    const float* to_kv_pw  = (const float*)d_in[9];
    const float* to_q_dw   = (const float*)d_in[10];
    const float* to_q_pw   = (const float*)d_in[11];
    const float* to_out_dw = (const float*)d_in[12];
    const float* to_out_pw = (const float*)d_in[13];
    const float* rel_table = (const float*)d_in[14];
    const float* normq_g   = (const float*)d_in[15];
    const float* normq_b   = (const float*)d_in[16];
    const float* normk_g   = (const float*)d_in[17];
    const float* normk_b   = (const float*)d_in[18];
    const float* norm2_g   = (const float*)d_in[19];
    const float* norm2_b   = (const float*)d_in[20];
    const float* mlp_w     = (const float*)d_in[21];
    float* Dout = (float*)d_out;

    float* ws = (float*)d_ws;
    const size_t NBIG = (size_t)NB_ * OUTCH * 4096;  // 8388608 floats (32 MB)
    float* RES = ws;
    float* A   = ws + NBIG;
    float* Bb  = ws + 2 * NBIG;
    float* sm  = ws + 3 * NBIG;
    float* scale1 = sm;            float* shift1 = sm + 512;
    float* scale2 = sm + 1024;     float* shift2 = sm + 1280;
    float* scale3 = sm + 1536;     float* shift3 = sm + 1792;
    float* k16 = sm + 2048;
    float* v16 = k16 + 524288;
    float* kn  = v16 + 524288;
    float* vh  = kn  + 524288;
    float* Mm  = vh  + 524288;
    float* Bv  = Mm  + 65536;
    short* Wq  = (short*)(Bv + 524288);
    short* Wo  = Wq + 65536;
    short* Wm  = Wo + 65536;
    short* Wc  = Wm + 65536;       // conv_ch_w packed: 256x512
    short* Wkv = Wc + 131072;      // to_kv_pw packed: 512x512

    short* Xp1 = (short*)Bb;             // x1 packed: 8 MB (4M shorts)
    short* Xp2 = (short*)Bb + 4194304;   // kv_dw packed: 8 MB
    short* Xp  = (short*)Bb;             // big packed X (16 MB), used steps 8+
    float* kv  = A;                      // 16 MB fp32 [8,512,1024] (after x1c dead)

    // 0. pack the five pointwise weights to bf16 packed layout
    pack_w<<<256, 256, 0, stream>>>(to_q_pw, Wq, 256, 256);
    pack_w<<<256, 256, 0, stream>>>(to_out_pw, Wo, 256, 256);
    pack_w<<<256, 256, 0, stream>>>(mlp_w, Wm, 256, 256);
    pack_w<<<512, 256, 0, stream>>>(conv_ch_w, Wc, 256, 512);
    pack_w<<<1024, 256, 0, stream>>>(to_kv_pw, Wkv, 512, 512);

    // 1. x1 -> packed bf16; x1c = mfma(x1p, Wc) + bias -> A (fp32 [8,256,1024])
    pack_tile<0><<<dim3(4, 16, 8), 256, 0, stream>>>(x1, nullptr, nullptr, Xp1, 512, 1024);
    mfma_pw<0><<<dim3(16, 2, 8), 256, 0, stream>>>(Xp1, Wc, conv_ch_b, nullptr, A, 512, 256, 1024);
    // 2. residue = resize(x1c, 64,64) -> RES
    resize_bilinear<<<32768, 256, 0, stream>>>(A, RES, 256, 256 * 1024, 32, 32, 64, 64);
    // 3. BN stats x1
    bn_stats<<<512, 256, 0, stream>>>(x1, norm_l_g, norm_l_b, scale1, shift1, 512, 1024, 1e-5f);
    // 4. kv_dw = dw3(BN(x1)) -> Xp2 (packed bf16)
    dw3_pack<32, 8><<<dim3(4, 16, 8), 256, 0, stream>>>(x1, scale1, shift1, to_kv_dw, Xp2, 512, 32);
    // 5. kv = mfma(Xp2, Wkv) -> A (fp32 [8,512,1024]; x1c region dead after step 2)
    mfma_pw<0><<<dim3(16, 4, 8), 256, 0, stream>>>(Xp2, Wkv, nullptr, nullptr, kv, 512, 512, 1024);
    // 6. k16, v16 = resize to 16x16
    resize_bilinear<<<2048, 256, 0, stream>>>(kv, k16, 256, 512 * 1024, 32, 32, 16, 16);
    resize_bilinear<<<2048, 256, 0, stream>>>(kv + 256 * 1024, v16, 256, 512 * 1024, 32, 32, 16, 16);
    // 7. BN stats x2
    bn_stats<<<256, 256, 0, stream>>>(x2, norm_h_g, norm_h_b, scale2, shift2, 256, 4096, 1e-5f);
    // 8. q_dw = dw3(BN(x2)) -> Xp (packed bf16; Xp1/Xp2 dead after step 5)
    dw3_pack<64, 4><<<dim3(16, 8, 8), 256, 0, stream>>>(x2, scale2, shift2, to_q_dw, Xp, 256, 64);
    // 9. q = mfma(Xp, Wq) -> A (fp32 conv layout; kv dead after step 6)
    mfma_pw<0><<<dim3(64, 2, 8), 256, 0, stream>>>(Xp, Wq, nullptr, nullptr, A, 256, 256, 4096);
    // 10. kn = LN(split(k16)); vh = split(v16)
    ln_split<<<2048, 256, 0, stream>>>(k16, normk_g, normk_b, kn, 256, 1, 1e-6f);
    ln_split<<<2048, 256, 0, stream>>>(v16, nullptr, nullptr, vh, 256, 0, 0.f);
    // 11. M = k^T v
    kv_outer<<<64, dim3(32, 32), 0, stream>>>(kn, vh, Mm);
    // 12. Bv = bias @ v
    bias_v<<<2048, 256, 0, stream>>>(rel_table, vh, Bv);
    // 13. o = (LN(q) @ M + Bv)/32, in-place on A
    attn_out<<<1024, 256, 0, stream>>>(A, normq_g, normq_b, Mm, Bv, A);
    // 14. out_dw = dw3(o) -> Xp (packed bf16)
    dw3_pack<64, 4><<<dim3(16, 8, 8), 256, 0, stream>>>(A, nullptr, nullptr, to_out_dw, Xp, 256, 64);
    // 15. o2 = mfma(Xp, Wo) + RES -> A  (res2)
    mfma_pw<1><<<dim3(64, 2, 8), 256, 0, stream>>>(Xp, Wo, nullptr, RES, A, 256, 256, 4096);
    // 16. BN stats o2
    bn_stats<<<256, 256, 0, stream>>>(A, norm2_g, norm2_b, scale3, shift3, 256, 4096, 1e-5f);
    // 17. r = relu(BN(o2)) -> Xp (packed bf16)
    pack_tile<1><<<dim3(16, 8, 8), 256, 0, stream>>>(A, scale3, shift3, Xp, 256, 4096);
    // 18. out = mfma(Xp, Wm) + res2(A) -> d_out
    mfma_pw<1><<<dim3(64, 2, 8), 256, 0, stream>>>(Xp, Wm, nullptr, A, Dout, 256, 256, 4096);
}

// Round 7
// 437.417 us; speedup vs baseline: 2.2078x; 1.1273x over previous
//
#include <hip/hip_runtime.h>
#include <math.h>

#define NB_   8
#define INCH  512
#define OUTCH 256
#define NHEAD 8
#define DHEAD 32

typedef __attribute__((ext_vector_type(8))) short short8v;
typedef __attribute__((ext_vector_type(4))) short short4v;
typedef __attribute__((ext_vector_type(4))) float f32x4;

__device__ inline short f2bf(float f) {
    unsigned u = __float_as_uint(f);
    unsigned r = u + 0x7FFFu + ((u >> 16) & 1u);
    return (short)(r >> 16);
}

// ---------------- pack fp32 weight [Co][Ci] -> bf16 packed-k layout ----------------
// packed pos within 32-k tile: (q = (k%16)/4, h = k/16, r = k%4) -> q*8 + h*4 + r
__global__ void pack_w(const float* __restrict__ W, short* __restrict__ Wp, int Co, int Ci) {
    const int idx = blockIdx.x * 256 + threadIdx.x;
    if (idx >= Co * Ci) return;
    const int m = idx / Ci, i = idx % Ci;
    const int kt = i >> 5, w32 = i & 31;
    const int h = w32 >> 4, q = (w32 & 15) >> 2, r = w32 & 3;
    Wp[m * Ci + kt * 32 + q * 8 + h * 4 + r] = f2bf(W[idx]);
}

// ---------------- LDS-staged pack: fp32 [B][C][P] -> packed bf16 [B][P][C] ----------------
// optional BN(scale/shift) + ReLU at staging. grid: (P/256, C/32, B)
template <int BN_RELU>
__global__ __launch_bounds__(256, 4)
void pack_tile(const float* __restrict__ in, const float* __restrict__ scale,
               const float* __restrict__ shift, short* __restrict__ outp, int C, int P) {
    __shared__ float s[32][256];
    const int tid = threadIdx.x;
    const int p0 = blockIdx.x * 256;
    const int kt = blockIdx.y;
    const int b  = blockIdx.z;
#pragma unroll
    for (int c = 0; c < 32; ++c) {
        const int gc = kt * 32 + c;
        float v = in[((size_t)b * C + gc) * P + p0 + tid];
        if (BN_RELU) {
            v = v * scale[gc] + shift[gc];
            v = v > 0.f ? v : 0.f;
        }
        s[c][tid] = v;
    }
    __syncthreads();
    short* op = outp + ((size_t)b * P + p0 + tid) * C + kt * 32;
#pragma unroll
    for (int q = 0; q < 4; ++q) {
        short8v v;
#pragma unroll
        for (int h = 0; h < 2; ++h)
#pragma unroll
            for (int r = 0; r < 4; ++r)
                v[h * 4 + r] = f2bf(s[h * 16 + q * 4 + r][tid]);
        *reinterpret_cast<short8v*>(op + q * 8) = v;
    }
}

// ---------------- direct (optional BN) + depthwise 3x3 -> packed bf16 ----------------
// thread = 8 consecutive x-pixels of one row x 4 channels; register window, L2 serves reuse.
// LDS only for output transpose (packed 64B stores). grid: (H/RT, C/32, B)
template <int W_>
__global__ __launch_bounds__(256, 4)
void dw3_direct(const float* __restrict__ in, const float* __restrict__ scale,
                const float* __restrict__ shift, const float* __restrict__ dw,
                short* __restrict__ outp, int C, int H) {
    constexpr int XG = W_ / 8;    // x-groups per row
    constexpr int RT = 256 / W_;  // rows per block tile
    __shared__ __align__(16) short so[256][40];
    const int tid = threadIdx.x;
    const int cg  = tid & 7;       // channel group of 4
    const int pxg = tid >> 3;      // 0..31 (8-px group)
    const int row = pxg / XG;
    const int xg  = pxg % XG;
    const int x0  = xg * 8;
    const int y   = blockIdx.x * RT + row;
    const int kt  = blockIdx.y;
    const int b   = blockIdx.z;
    const int P   = H * W_;

    float acc[4][8];
#pragma unroll
    for (int r = 0; r < 4; ++r)
#pragma unroll
        for (int j = 0; j < 8; ++j) acc[r][j] = 0.f;

#pragma unroll
    for (int r = 0; r < 4; ++r) {
        const int gc = kt * 32 + cg * 4 + r;
        const float sc = scale ? scale[gc] : 1.f;
        const float sh = scale ? shift[gc] : 0.f;
        const float* wp = dw + gc * 9;
#pragma unroll
        for (int dy = 0; dy < 3; ++dy) {
            const int gy = y - 1 + dy;
            if (gy < 0 || gy >= H) continue;
            const float* bp = in + ((size_t)b * C + gc) * P + gy * W_;
            float w[10];
            w[0] = (x0 > 0) ? bp[x0 - 1] : 0.f;
            const float4 m0 = *reinterpret_cast<const float4*>(bp + x0);
            const float4 m1 = *reinterpret_cast<const float4*>(bp + x0 + 4);
            w[1] = m0.x; w[2] = m0.y; w[3] = m0.z; w[4] = m0.w;
            w[5] = m1.x; w[6] = m1.y; w[7] = m1.z; w[8] = m1.w;
            w[9] = (x0 + 8 < W_) ? bp[x0 + 8] : 0.f;
            if (scale) {
#pragma unroll
                for (int t = 0; t < 10; ++t) w[t] = w[t] * sc + sh;
                if (x0 == 0) w[0] = 0.f;          // zero-pad is pre-BN zero
                if (x0 + 8 >= W_) w[9] = 0.f;
            }
            const float t0 = wp[dy * 3 + 0], t1 = wp[dy * 3 + 1], t2 = wp[dy * 3 + 2];
#pragma unroll
            for (int j = 0; j < 8; ++j)
                acc[r][j] += t0 * w[j] + t1 * w[j + 1] + t2 * w[j + 2];
        }
    }

    // packed-k position for this thread's 4 channels (contiguous in r)
    const int posb = (cg & 3) * 8 + (cg >> 2) * 4;
#pragma unroll
    for (int j = 0; j < 8; ++j) {
        short4v v;
#pragma unroll
        for (int r = 0; r < 4; ++r) v[r] = f2bf(acc[r][j]);
        *reinterpret_cast<short4v*>(&so[pxg * 8 + j][posb]) = v;
    }
    __syncthreads();
    short* op = outp + ((size_t)b * P + blockIdx.x * 256 + tid) * C + kt * 32;
#pragma unroll
    for (int q = 0; q < 4; ++q)
        *reinterpret_cast<short8v*>(op + q * 8) = *reinterpret_cast<const short8v*>(&so[tid][q * 8]);
}

// ---------------- MFMA bf16 pointwise conv (GEMM): out[b,m,p] = sum_i W[m,i] X[b,i,p] ----------------
// Xp: [B][P][Ci] bf16 packed-k; Wp: [Co][Ci] bf16 packed-k.
// BM=128, BN=64, BK=32; 4 waves (2x2), wave tile 64x32.
template <int HAS_RES>
__global__ __launch_bounds__(256, 4)
void mfma_pw(const short* __restrict__ Xp, const short* __restrict__ Wp,
             const float* __restrict__ bias, const float* __restrict__ res,
             float* __restrict__ out, int Ci, int Co, int P) {
    __shared__ short Ash[4096];  // [q(4)][m(128)] 16B chunks = 8KB
    __shared__ short Bsh[2048];  // [q(4)][n(64)]  16B chunks = 4KB
    const int b   = blockIdx.z;
    const int m0  = blockIdx.y * 128;
    const int n0  = blockIdx.x * 64;
    const int tid = threadIdx.x;
    const int lane = tid & 63;
    const int wid  = tid >> 6;
    const int wr = wid >> 1, wc = wid & 1;
    const int ql = lane >> 4, l16 = lane & 15;

    f32x4 acc[4][2];
#pragma unroll
    for (int mb = 0; mb < 4; ++mb)
#pragma unroll
        for (int nb = 0; nb < 2; ++nb) acc[mb][nb] = (f32x4){0.f, 0.f, 0.f, 0.f};

    const int sm_ = tid & 127;  // A stage: m
    const int sq_ = tid >> 7;   // A stage: q sub
    const int bn_ = tid & 63;   // B stage: n
    const int bq_ = tid >> 6;   // B stage: q

    const size_t wrow = (size_t)(m0 + sm_) * Ci;
    const size_t xrow = ((size_t)b * P + n0 + bn_) * Ci;

    const int nkt = Ci >> 5;
    for (int kt = 0; kt < nkt; ++kt) {
        const int kof = kt * 32;
#pragma unroll
        for (int r = 0; r < 2; ++r) {
            const int q = r * 2 + sq_;
            __builtin_amdgcn_global_load_lds(Wp + wrow + kof + q * 8, &Ash[r * 2048 + tid * 8], 16, 0, 0);
        }
        __builtin_amdgcn_global_load_lds(Xp + xrow + kof + bq_ * 8, &Bsh[tid * 8], 16, 0, 0);
        __syncthreads();

        short8v a[4], bf[2];
#pragma unroll
        for (int mb = 0; mb < 4; ++mb)
            a[mb] = *reinterpret_cast<const short8v*>(&Ash[ql * 1024 + (wr * 64 + mb * 16 + l16) * 8]);
#pragma unroll
        for (int nb = 0; nb < 2; ++nb)
            bf[nb] = *reinterpret_cast<const short8v*>(&Bsh[ql * 512 + (wc * 32 + nb * 16 + l16) * 8]);
#pragma unroll
        for (int mb = 0; mb < 4; ++mb)
#pragma unroll
            for (int nb = 0; nb < 2; ++nb)
                acc[mb][nb] = __builtin_amdgcn_mfma_f32_16x16x32_bf16(a[mb], bf[nb], acc[mb][nb], 0, 0, 0);
        __syncthreads();
    }

#pragma unroll
    for (int mb = 0; mb < 4; ++mb) {
        const int row = m0 + wr * 64 + mb * 16 + ql * 4;
#pragma unroll
        for (int nb = 0; nb < 2; ++nb) {
            const int col = n0 + wc * 32 + nb * 16 + l16;
            const size_t base = ((size_t)b * Co + row) * P + col;
#pragma unroll
            for (int j = 0; j < 4; ++j) {
                float v = acc[mb][nb][j];
                if (bias) v += bias[row + j];
                if (HAS_RES) v += res[base + (size_t)j * P];
                out[base + (size_t)j * P] = v;
            }
        }
    }
}

// ---------------- bilinear resize ----------------
__global__ void resize_bilinear(const float* __restrict__ in, float* __restrict__ out,
                                int C, int ibs, int Hi, int Wi, int Ho, int Wo) {
    const int idx = blockIdx.x * 256 + threadIdx.x;
    const int total = NB_ * C * Ho * Wo;
    if (idx >= total) return;
    const int x = idx % Wo;
    const int y = (idx / Wo) % Ho;
    const int c = (idx / (Wo * Ho)) % C;
    const int b = idx / (Wo * Ho * C);
    const float fy = (float)y * (float)(Hi - 1) / (float)(Ho - 1);
    const float fx = (float)x * (float)(Wi - 1) / (float)(Wo - 1);
    int y0 = (int)floorf(fy); int y1 = min(y0 + 1, Hi - 1); const float wy = fy - (float)y0;
    int x0 = (int)floorf(fx); int x1 = min(x0 + 1, Wi - 1); const float wx = fx - (float)x0;
    const float* pc = in + (size_t)b * ibs + (size_t)c * Hi * Wi;
    const float r0 = pc[y0 * Wi + x0] * (1.f - wx) + pc[y0 * Wi + x1] * wx;
    const float r1 = pc[y1 * Wi + x0] * (1.f - wx) + pc[y1 * Wi + x1] * wx;
    out[idx] = r0 * (1.f - wy) + r1 * wy;
}

// ---------------- BN stats ----------------
__global__ void bn_stats(const float* __restrict__ in, const float* __restrict__ g,
                         const float* __restrict__ bt, float* __restrict__ scale,
                         float* __restrict__ shift, int C, int HW, float eps) {
    const int c = blockIdx.x;
    float s1 = 0.f, s2 = 0.f;
    for (int b = 0; b < NB_; ++b) {
        const float* p = in + ((size_t)b * C + c) * HW;
        for (int r = threadIdx.x; r < HW; r += 256) {
            const float v = p[r];
            s1 += v; s2 += v * v;
        }
    }
    __shared__ float sh1[256], sh2[256];
    sh1[threadIdx.x] = s1; sh2[threadIdx.x] = s2;
    __syncthreads();
    for (int s = 128; s > 0; s >>= 1) {
        if (threadIdx.x < s) { sh1[threadIdx.x] += sh1[threadIdx.x + s]; sh2[threadIdx.x] += sh2[threadIdx.x + s]; }
        __syncthreads();
    }
    if (threadIdx.x == 0) {
        const float N = (float)(NB_ * HW);
        const float m = sh1[0] / N;
        const float var = sh2[0] / N - m * m;
        const float sc = g[c] * rsqrtf(var + eps);
        scale[c] = sc;
        shift[c] = bt[c] - m * sc;
    }
}

// ---------------- LN (optional) + split heads ----------------
__global__ void ln_split(const float* __restrict__ in, const float* __restrict__ g,
                         const float* __restrict__ bt, float* __restrict__ out,
                         int HW, int applyLN, float eps) {
    const int row = blockIdx.x * 8 + (threadIdx.x >> 5);
    const int d = threadIdx.x & 31;
    const int j = row % HW;
    const int h = (row / HW) % NHEAD;
    const int b = row / (HW * NHEAD);
    float v = in[((size_t)b * OUTCH + d * NHEAD + h) * HW + j];
    if (applyLN) {
        float s1 = v, s2 = v * v;
#pragma unroll
        for (int o = 16; o >= 1; o >>= 1) {
            s1 += __shfl_xor(s1, o, 32);
            s2 += __shfl_xor(s2, o, 32);
        }
        const float m = s1 * (1.f / 32.f);
        const float var = s2 * (1.f / 32.f) - m * m;
        v = (v - m) * rsqrtf(var + eps) * g[h * 32 + d] + bt[h * 32 + d];
    }
    out[((size_t)(b * NHEAD + h) * HW + j) * 32 + d] = v;
}

// ---------------- M = k^T v ----------------
__global__ void kv_outer(const float* __restrict__ kn, const float* __restrict__ vh,
                         float* __restrict__ M) {
    __shared__ float vs[256][32];
    const int bh = blockIdx.x;
    const float* kp = kn + (size_t)bh * 256 * 32;
    const float* vp = vh + (size_t)bh * 256 * 32;
    const int tid = threadIdx.y * 32 + threadIdx.x;
    for (int t = tid; t < 256 * 32; t += 1024) vs[t >> 5][t & 31] = vp[t];
    __syncthreads();
    const int e = threadIdx.x, dd = threadIdx.y;
    float acc = 0.f;
    for (int j = 0; j < 256; ++j) acc += kp[j * 32 + e] * vs[j][dd];
    M[((size_t)bh * 32 + e) * 32 + dd] = acc;
}

// ---------------- Bv = bias @ v ----------------
__global__ void bias_v(const float* __restrict__ rel, const float* __restrict__ vh,
                       float* __restrict__ Bv) {
    const int gid = blockIdx.x * 8 + (threadIdx.x >> 5);
    const int d = threadIdx.x & 31;
    const int qb = gid % 256;
    const int h = (gid / 256) % NHEAD;
    const int b = gid / (256 * NHEAD);
    const int qy = qb >> 4, qx = qb & 15;
    const float* vp = vh + (size_t)(b * NHEAD + h) * 256 * 32;
    float acc = 0.f;
    for (int j = 0; j < 256; ++j) {
        const int ky = j >> 4, kx = j & 15;
        const float bias = rel[((qy - ky + 15) * 31 + (qx - kx + 15)) * NHEAD + h];
        acc += bias * vp[j * 32 + d];
    }
    Bv[((size_t)(b * NHEAD + h) * 256 + qb) * 32 + d] = acc;
}

// ---------------- attention out: o = (LN(q) @ M + Bv)/32 (in-place safe) ----------------
__global__ void attn_out(const float* __restrict__ q, const float* __restrict__ gq,
                         const float* __restrict__ bq, const float* __restrict__ M,
                         const float* __restrict__ Bv, float* __restrict__ o) {
    const int gid = blockIdx.x * 256 + threadIdx.x;
    const int i = gid % 4096;
    const int h = (gid / 4096) % NHEAD;
    const int b = gid / (4096 * NHEAD);
    const int y = i >> 6, x = i & 63;
    const int qb = (y >> 2) * 16 + (x >> 2);

    const float* qp = q + (size_t)b * OUTCH * 4096 + h * 4096 + i;
    float qv[32];
    float s1 = 0.f, s2 = 0.f;
#pragma unroll
    for (int d = 0; d < 32; ++d) {
        const float v = qp[(size_t)d * NHEAD * 4096];
        qv[d] = v; s1 += v; s2 += v * v;
    }
    const float m = s1 * (1.f / 32.f);
    const float var = s2 * (1.f / 32.f) - m * m;
    const float rs = rsqrtf(var + 1e-6f);
#pragma unroll
    for (int d = 0; d < 32; ++d)
        qv[d] = (qv[d] - m) * rs * gq[h * 32 + d] + bq[h * 32 + d];

    const float* Mp = M + (size_t)(b * NHEAD + h) * 32 * 32;
    const float* Bp = Bv + ((size_t)(b * NHEAD + h) * 256 + qb) * 32;
    float acc[32];
#pragma unroll
    for (int d = 0; d < 32; ++d) acc[d] = Bp[d];
#pragma unroll
    for (int e = 0; e < 32; ++e) {
        const float qe = qv[e];
#pragma unroll
        for (int d = 0; d < 32; ++d) acc[d] += qe * Mp[e * 32 + d];
    }
    float* op = o + (size_t)b * OUTCH * 4096 + h * 4096 + i;
#pragma unroll
    for (int d = 0; d < 32; ++d) op[(size_t)d * NHEAD * 4096] = acc[d] * (1.f / 32.f);
}

extern "C" void kernel_launch(void* const* d_in, const int* in_sizes, int n_in,
                              void* d_out, int out_size, void* d_ws, size_t ws_size,
                              hipStream_t stream) {
    const float* x1        = (const float*)d_in[0];
    const float* x2        = (const float*)d_in[1];
    const float* conv_ch_w = (const float*)d_in[2];
    const float* conv_ch_b = (const float*)d_in[3];
    const float* norm_l_g  = (const float*)d_in[4];
    const float* norm_l_b  = (const float*)d_in[5];
    const float* norm_h_g  = (const float*)d_in[6];
    const float* norm_h_b  = (const float*)d_in[7];
    const float* to_kv_dw  = (const float*)d_in[8];
    const float* to_kv_pw  = (const float*)d_in[9];
    const float* to_q_dw   = (const float*)d_in[10];
    const float* to_q_pw   = (const float*)d_in[11];
    const float* to_out_dw = (const float*)d_in[12];
    const float* to_out_pw = (const float*)d_in[13];
    const float* rel_table = (const float*)d_in[14];
    const float* normq_g   = (const float*)d_in[15];
    const float* normq_b   = (const float*)d_in[16];
    const float* normk_g   = (const float*)d_in[17];
    const float* normk_b   = (const float*)d_in[18];
    const float* norm2_g   = (const float*)d_in[19];
    const float* norm2_b   = (const float*)d_in[20];
    const float* mlp_w     = (const float*)d_in[21];
    float* Dout = (float*)d_out;

    float* ws = (float*)d_ws;
    const size_t NBIG = (size_t)NB_ * OUTCH * 4096;  // 8388608 floats (32 MB)
    float* RES = ws;
    float* A   = ws + NBIG;
    float* Bb  = ws + 2 * NBIG;
    float* sm  = ws + 3 * NBIG;
    float* scale1 = sm;            float* shift1 = sm + 512;
    float* scale2 = sm + 1024;     float* shift2 = sm + 1280;
    float* scale3 = sm + 1536;     float* shift3 = sm + 1792;
    float* k16 = sm + 2048;
    float* v16 = k16 + 524288;
    float* kn  = v16 + 524288;
    float* vh  = kn  + 524288;
    float* Mm  = vh  + 524288;
    float* Bv  = Mm  + 65536;
    short* Wq  = (short*)(Bv + 524288);
    short* Wo  = Wq + 65536;
    short* Wm  = Wo + 65536;
    short* Wc  = Wm + 65536;       // conv_ch_w packed: 256x512
    short* Wkv = Wc + 131072;      // to_kv_pw packed: 512x512

    short* Xp1 = (short*)Bb;             // x1 packed: 8 MB (4M shorts)
    short* Xp2 = (short*)Bb + 4194304;   // kv_dw packed: 8 MB
    short* Xp  = (short*)Bb;             // big packed X (16 MB), used steps 8+
    float* kv  = A;                      // 16 MB fp32 [8,512,1024] (after x1c dead)

    // 0. pack the five pointwise weights to bf16 packed layout
    pack_w<<<256, 256, 0, stream>>>(to_q_pw, Wq, 256, 256);
    pack_w<<<256, 256, 0, stream>>>(to_out_pw, Wo, 256, 256);
    pack_w<<<256, 256, 0, stream>>>(mlp_w, Wm, 256, 256);
    pack_w<<<512, 256, 0, stream>>>(conv_ch_w, Wc, 256, 512);
    pack_w<<<1024, 256, 0, stream>>>(to_kv_pw, Wkv, 512, 512);

    // 1. x1 -> packed bf16; x1c = mfma(x1p, Wc) + bias -> A (fp32 [8,256,1024])
    pack_tile<0><<<dim3(4, 16, 8), 256, 0, stream>>>(x1, nullptr, nullptr, Xp1, 512, 1024);
    mfma_pw<0><<<dim3(16, 2, 8), 256, 0, stream>>>(Xp1, Wc, conv_ch_b, nullptr, A, 512, 256, 1024);
    // 2. residue = resize(x1c, 64,64) -> RES
    resize_bilinear<<<32768, 256, 0, stream>>>(A, RES, 256, 256 * 1024, 32, 32, 64, 64);
    // 3. BN stats x1
    bn_stats<<<512, 256, 0, stream>>>(x1, norm_l_g, norm_l_b, scale1, shift1, 512, 1024, 1e-5f);
    // 4. kv_dw = dw3(BN(x1)) -> Xp2 (packed bf16)
    dw3_direct<32><<<dim3(4, 16, 8), 256, 0, stream>>>(x1, scale1, shift1, to_kv_dw, Xp2, 512, 32);
    // 5. kv = mfma(Xp2, Wkv) -> A (fp32 [8,512,1024]; x1c region dead after step 2)
    mfma_pw<0><<<dim3(16, 4, 8), 256, 0, stream>>>(Xp2, Wkv, nullptr, nullptr, kv, 512, 512, 1024);
    // 6. k16, v16 = resize to 16x16
    resize_bilinear<<<2048, 256, 0, stream>>>(kv, k16, 256, 512 * 1024, 32, 32, 16, 16);
    resize_bilinear<<<2048, 256, 0, stream>>>(kv + 256 * 1024, v16, 256, 512 * 1024, 32, 32, 16, 16);
    // 7. BN stats x2
    bn_stats<<<256, 256, 0, stream>>>(x2, norm_h_g, norm_h_b, scale2, shift2, 256, 4096, 1e-5f);
    // 8. q_dw = dw3(BN(x2)) -> Xp (packed bf16; Xp1/Xp2 dead after step 5)
    dw3_direct<64><<<dim3(16, 8, 8), 256, 0, stream>>>(x2, scale2, shift2, to_q_dw, Xp, 256, 64);
    // 9. q = mfma(Xp, Wq) -> A (fp32 conv layout; kv dead after step 6)
    mfma_pw<0><<<dim3(64, 2, 8), 256, 0, stream>>>(Xp, Wq, nullptr, nullptr, A, 256, 256, 4096);
    // 10. kn = LN(split(k16)); vh = split(v16)
    ln_split<<<2048, 256, 0, stream>>>(k16, normk_g, normk_b, kn, 256, 1, 1e-6f);
    ln_split<<<2048, 256, 0, stream>>>(v16, nullptr, nullptr, vh, 256, 0, 0.f);
    // 11. M = k^T v
    kv_outer<<<64, dim3(32, 32), 0, stream>>>(kn, vh, Mm);
    // 12. Bv = bias @ v
    bias_v<<<2048, 256, 0, stream>>>(rel_table, vh, Bv);
    // 13. o = (LN(q) @ M + Bv)/32, in-place on A
    attn_out<<<1024, 256, 0, stream>>>(A, normq_g, normq_b, Mm, Bv, A);
    // 14. out_dw = dw3(o) -> Xp (packed bf16)
    dw3_direct<64><<<dim3(16, 8, 8), 256, 0, stream>>>(A, nullptr, nullptr, to_out_dw, Xp, 256, 64);
    // 15. o2 = mfma(Xp, Wo) + RES -> A  (res2)
    mfma_pw<1><<<dim3(64, 2, 8), 256, 0, stream>>>(Xp, Wo, nullptr, RES, A, 256, 256, 4096);
    // 16. BN stats o2
    bn_stats<<<256, 256, 0, stream>>>(A, norm2_g, norm2_b, scale3, shift3, 256, 4096, 1e-5f);
    // 17. r = relu(BN(o2)) -> Xp (packed bf16)
    pack_tile<1><<<dim3(16, 8, 8), 256, 0, stream>>>(A, scale3, shift3, Xp, 256, 4096);
    // 18. out = mfma(Xp, Wm) + res2(A) -> d_out
    mfma_pw<1><<<dim3(64, 2, 8), 256, 0, stream>>>(Xp, Wm, nullptr, A, Dout, 256, 256, 4096);
}

// Round 8
// 385.787 us; speedup vs baseline: 2.5032x; 1.1338x over previous
//
#include <hip/hip_runtime.h>
#include <math.h>

#define NB_   8
#define INCH  512
#define OUTCH 256
#define NHEAD 8
#define DHEAD 32

typedef __attribute__((ext_vector_type(8))) short short8v;
typedef __attribute__((ext_vector_type(4))) short short4v;
typedef __attribute__((ext_vector_type(4))) float f32x4;

__device__ inline short f2bf(float f) {
    unsigned u = __float_as_uint(f);
    unsigned r = u + 0x7FFFu + ((u >> 16) & 1u);
    return (short)(r >> 16);
}

// ---------------- pack fp32 weight [Co][Ci] -> bf16 packed-k layout ----------------
// packed pos within 32-k tile: (q = (k%16)/4, h = k/16, r = k%4) -> q*8 + h*4 + r
__global__ void pack_w(const float* __restrict__ W, short* __restrict__ Wp, int Co, int Ci) {
    const int idx = blockIdx.x * 256 + threadIdx.x;
    if (idx >= Co * Ci) return;
    const int m = idx / Ci, i = idx % Ci;
    const int kt = i >> 5, w32 = i & 31;
    const int h = w32 >> 4, q = (w32 & 15) >> 2, r = w32 & 3;
    Wp[m * Ci + kt * 32 + q * 8 + h * 4 + r] = f2bf(W[idx]);
}

// ---------------- LDS-staged pack: fp32 [B][C][P] -> packed bf16 [B][P][C] ----------------
// optional BN(scale/shift) + ReLU at staging. grid: (P/256, C/32, B)
template <int BN_RELU>
__global__ __launch_bounds__(256, 4)
void pack_tile(const float* __restrict__ in, const float* __restrict__ scale,
               const float* __restrict__ shift, short* __restrict__ outp, int C, int P) {
    __shared__ float s[32][256];
    const int tid = threadIdx.x;
    const int p0 = blockIdx.x * 256;
    const int kt = blockIdx.y;
    const int b  = blockIdx.z;
#pragma unroll
    for (int c = 0; c < 32; ++c) {
        const int gc = kt * 32 + c;
        float v = in[((size_t)b * C + gc) * P + p0 + tid];
        if (BN_RELU) {
            v = v * scale[gc] + shift[gc];
            v = v > 0.f ? v : 0.f;
        }
        s[c][tid] = v;
    }
    __syncthreads();
    short* op = outp + ((size_t)b * P + p0 + tid) * C + kt * 32;
#pragma unroll
    for (int q = 0; q < 4; ++q) {
        short8v v;
#pragma unroll
        for (int h = 0; h < 2; ++h)
#pragma unroll
            for (int r = 0; r < 4; ++r)
                v[h * 4 + r] = f2bf(s[h * 16 + q * 4 + r][tid]);
        *reinterpret_cast<short8v*>(op + q * 8) = v;
    }
}

// ---------------- direct (optional BN) + depthwise 3x3 -> packed bf16 ----------------
// thread = 8 consecutive x-pixels of one row x 4 channels; register window, L2 serves reuse.
// LDS only for output transpose (packed 64B stores). grid: (H/RT, C/32, B)
template <int W_>
__global__ __launch_bounds__(256, 4)
void dw3_direct(const float* __restrict__ in, const float* __restrict__ scale,
                const float* __restrict__ shift, const float* __restrict__ dw,
                short* __restrict__ outp, int C, int H) {
    constexpr int XG = W_ / 8;    // x-groups per row
    constexpr int RT = 256 / W_;  // rows per block tile
    __shared__ __align__(16) short so[256][40];
    const int tid = threadIdx.x;
    const int cg  = tid & 7;       // channel group of 4
    const int pxg = tid >> 3;      // 0..31 (8-px group)
    const int row = pxg / XG;
    const int xg  = pxg % XG;
    const int x0  = xg * 8;
    const int y   = blockIdx.x * RT + row;
    const int kt  = blockIdx.y;
    const int b   = blockIdx.z;
    const int P   = H * W_;

    float acc[4][8];
#pragma unroll
    for (int r = 0; r < 4; ++r)
#pragma unroll
        for (int j = 0; j < 8; ++j) acc[r][j] = 0.f;

#pragma unroll
    for (int r = 0; r < 4; ++r) {
        const int gc = kt * 32 + cg * 4 + r;
        const float sc = scale ? scale[gc] : 1.f;
        const float sh = scale ? shift[gc] : 0.f;
        const float* wp = dw + gc * 9;
#pragma unroll
        for (int dy = 0; dy < 3; ++dy) {
            const int gy = y - 1 + dy;
            if (gy < 0 || gy >= H) continue;
            const float* bp = in + ((size_t)b * C + gc) * P + gy * W_;
            float w[10];
            w[0] = (x0 > 0) ? bp[x0 - 1] : 0.f;
            const float4 m0 = *reinterpret_cast<const float4*>(bp + x0);
            const float4 m1 = *reinterpret_cast<const float4*>(bp + x0 + 4);
            w[1] = m0.x; w[2] = m0.y; w[3] = m0.z; w[4] = m0.w;
            w[5] = m1.x; w[6] = m1.y; w[7] = m1.z; w[8] = m1.w;
            w[9] = (x0 + 8 < W_) ? bp[x0 + 8] : 0.f;
            if (scale) {
#pragma unroll
                for (int t = 0; t < 10; ++t) w[t] = w[t] * sc + sh;
                if (x0 == 0) w[0] = 0.f;          // zero-pad is pre-BN zero
                if (x0 + 8 >= W_) w[9] = 0.f;
            }
            const float t0 = wp[dy * 3 + 0], t1 = wp[dy * 3 + 1], t2 = wp[dy * 3 + 2];
#pragma unroll
            for (int j = 0; j < 8; ++j)
                acc[r][j] += t0 * w[j] + t1 * w[j + 1] + t2 * w[j + 2];
        }
    }

    // packed-k position for this thread's 4 channels (contiguous in r)
    const int posb = (cg & 3) * 8 + (cg >> 2) * 4;
#pragma unroll
    for (int j = 0; j < 8; ++j) {
        short4v v;
#pragma unroll
        for (int r = 0; r < 4; ++r) v[r] = f2bf(acc[r][j]);
        *reinterpret_cast<short4v*>(&so[pxg * 8 + j][posb]) = v;
    }
    __syncthreads();
    short* op = outp + ((size_t)b * P + blockIdx.x * 256 + tid) * C + kt * 32;
#pragma unroll
    for (int q = 0; q < 4; ++q)
        *reinterpret_cast<short8v*>(op + q * 8) = *reinterpret_cast<const short8v*>(&so[tid][q * 8]);
}

// ---------------- MFMA bf16 pointwise conv (GEMM): out[b,m,p] = sum_i W[m,i] X[b,i,p] ----------------
// Xp: [B][P][Ci] bf16 packed-k; Wp: [Co][Ci] bf16 packed-k.
// BM=128, BN=64, BK=32; 4 waves (2x2), wave tile 64x32.
template <int HAS_RES>
__global__ __launch_bounds__(256, 4)
void mfma_pw(const short* __restrict__ Xp, const short* __restrict__ Wp,
             const float* __restrict__ bias, const float* __restrict__ res,
             float* __restrict__ out, int Ci, int Co, int P) {
    __shared__ short Ash[4096];  // [q(4)][m(128)] 16B chunks = 8KB
    __shared__ short Bsh[2048];  // [q(4)][n(64)]  16B chunks = 4KB
    const int b   = blockIdx.z;
    const int m0  = blockIdx.y * 128;
    const int n0  = blockIdx.x * 64;
    const int tid = threadIdx.x;
    const int lane = tid & 63;
    const int wid  = tid >> 6;
    const int wr = wid >> 1, wc = wid & 1;
    const int ql = lane >> 4, l16 = lane & 15;

    f32x4 acc[4][2];
#pragma unroll
    for (int mb = 0; mb < 4; ++mb)
#pragma unroll
        for (int nb = 0; nb < 2; ++nb) acc[mb][nb] = (f32x4){0.f, 0.f, 0.f, 0.f};

    const int sm_ = tid & 127;  // A stage: m
    const int sq_ = tid >> 7;   // A stage: q sub
    const int bn_ = tid & 63;   // B stage: n
    const int bq_ = tid >> 6;   // B stage: q

    const size_t wrow = (size_t)(m0 + sm_) * Ci;
    const size_t xrow = ((size_t)b * P + n0 + bn_) * Ci;

    const int nkt = Ci >> 5;
    for (int kt = 0; kt < nkt; ++kt) {
        const int kof = kt * 32;
#pragma unroll
        for (int r = 0; r < 2; ++r) {
            const int q = r * 2 + sq_;
            __builtin_amdgcn_global_load_lds(Wp + wrow + kof + q * 8, &Ash[r * 2048 + tid * 8], 16, 0, 0);
        }
        __builtin_amdgcn_global_load_lds(Xp + xrow + kof + bq_ * 8, &Bsh[tid * 8], 16, 0, 0);
        __syncthreads();

        short8v a[4], bf[2];
#pragma unroll
        for (int mb = 0; mb < 4; ++mb)
            a[mb] = *reinterpret_cast<const short8v*>(&Ash[ql * 1024 + (wr * 64 + mb * 16 + l16) * 8]);
#pragma unroll
        for (int nb = 0; nb < 2; ++nb)
            bf[nb] = *reinterpret_cast<const short8v*>(&Bsh[ql * 512 + (wc * 32 + nb * 16 + l16) * 8]);
#pragma unroll
        for (int mb = 0; mb < 4; ++mb)
#pragma unroll
            for (int nb = 0; nb < 2; ++nb)
                acc[mb][nb] = __builtin_amdgcn_mfma_f32_16x16x32_bf16(a[mb], bf[nb], acc[mb][nb], 0, 0, 0);
        __syncthreads();
    }

#pragma unroll
    for (int mb = 0; mb < 4; ++mb) {
        const int row = m0 + wr * 64 + mb * 16 + ql * 4;
#pragma unroll
        for (int nb = 0; nb < 2; ++nb) {
            const int col = n0 + wc * 32 + nb * 16 + l16;
            const size_t base = ((size_t)b * Co + row) * P + col;
#pragma unroll
            for (int j = 0; j < 4; ++j) {
                float v = acc[mb][nb][j];
                if (bias) v += bias[row + j];
                if (HAS_RES) v += res[base + (size_t)j * P];
                out[base + (size_t)j * P] = v;
            }
        }
    }
}

// ---------------- bilinear resize ----------------
__global__ void resize_bilinear(const float* __restrict__ in, float* __restrict__ out,
                                int C, int ibs, int Hi, int Wi, int Ho, int Wo) {
    const int idx = blockIdx.x * 256 + threadIdx.x;
    const int total = NB_ * C * Ho * Wo;
    if (idx >= total) return;
    const int x = idx % Wo;
    const int y = (idx / Wo) % Ho;
    const int c = (idx / (Wo * Ho)) % C;
    const int b = idx / (Wo * Ho * C);
    const float fy = (float)y * (float)(Hi - 1) / (float)(Ho - 1);
    const float fx = (float)x * (float)(Wi - 1) / (float)(Wo - 1);
    int y0 = (int)floorf(fy); int y1 = min(y0 + 1, Hi - 1); const float wy = fy - (float)y0;
    int x0 = (int)floorf(fx); int x1 = min(x0 + 1, Wi - 1); const float wx = fx - (float)x0;
    const float* pc = in + (size_t)b * ibs + (size_t)c * Hi * Wi;
    const float r0 = pc[y0 * Wi + x0] * (1.f - wx) + pc[y0 * Wi + x1] * wx;
    const float r1 = pc[y1 * Wi + x0] * (1.f - wx) + pc[y1 * Wi + x1] * wx;
    out[idx] = r0 * (1.f - wy) + r1 * wy;
}

// ---------------- BN stats, two-phase ----------------
// phase 1: one block per (b,c) plane -> per-plane (sum, sumsq). grid (B, C)
__global__ __launch_bounds__(256, 8)
void bn_stats_part(const float* __restrict__ in, float* __restrict__ part, int C, int HW) {
    const int b = blockIdx.x;
    const int c = blockIdx.y;
    const float* p = in + ((size_t)b * C + c) * HW;
    float s1 = 0.f, s2 = 0.f;
    for (int i = threadIdx.x * 4; i < HW; i += 1024) {
        const float4 v = *reinterpret_cast<const float4*>(p + i);
        s1 += v.x + v.y + v.z + v.w;
        s2 += v.x * v.x + v.y * v.y + v.z * v.z + v.w * v.w;
    }
#pragma unroll
    for (int o = 32; o >= 1; o >>= 1) {
        s1 += __shfl_xor(s1, o);
        s2 += __shfl_xor(s2, o);
    }
    __shared__ float sh1[4], sh2[4];
    if ((threadIdx.x & 63) == 0) { sh1[threadIdx.x >> 6] = s1; sh2[threadIdx.x >> 6] = s2; }
    __syncthreads();
    if (threadIdx.x == 0) {
        part[((size_t)c * gridDim.x + b) * 2 + 0] = sh1[0] + sh1[1] + sh1[2] + sh1[3];
        part[((size_t)c * gridDim.x + b) * 2 + 1] = sh2[0] + sh2[1] + sh2[2] + sh2[3];
    }
}

// phase 2: per-channel scale/shift from partials
__global__ void bn_finish(const float* __restrict__ part, const float* __restrict__ g,
                          const float* __restrict__ bt, float* __restrict__ scale,
                          float* __restrict__ shift, int C, int HW, float eps) {
    const int c = blockIdx.x * 256 + threadIdx.x;
    if (c >= C) return;
    float s1 = 0.f, s2 = 0.f;
#pragma unroll
    for (int b = 0; b < NB_; ++b) {
        s1 += part[((size_t)c * NB_ + b) * 2 + 0];
        s2 += part[((size_t)c * NB_ + b) * 2 + 1];
    }
    const float invN = 1.f / (float)(NB_ * HW);
    const float m = s1 * invN;
    const float var = s2 * invN - m * m;
    const float sc = g[c] * rsqrtf(var + eps);
    scale[c] = sc;
    shift[c] = bt[c] - m * sc;
}

// ---------------- LN (optional) + split heads ----------------
__global__ void ln_split(const float* __restrict__ in, const float* __restrict__ g,
                         const float* __restrict__ bt, float* __restrict__ out,
                         int HW, int applyLN, float eps) {
    const int row = blockIdx.x * 8 + (threadIdx.x >> 5);
    const int d = threadIdx.x & 31;
    const int j = row % HW;
    const int h = (row / HW) % NHEAD;
    const int b = row / (HW * NHEAD);
    float v = in[((size_t)b * OUTCH + d * NHEAD + h) * HW + j];
    if (applyLN) {
        float s1 = v, s2 = v * v;
#pragma unroll
        for (int o = 16; o >= 1; o >>= 1) {
            s1 += __shfl_xor(s1, o, 32);
            s2 += __shfl_xor(s2, o, 32);
        }
        const float m = s1 * (1.f / 32.f);
        const float var = s2 * (1.f / 32.f) - m * m;
        v = (v - m) * rsqrtf(var + eps) * g[h * 32 + d] + bt[h * 32 + d];
    }
    out[((size_t)(b * NHEAD + h) * HW + j) * 32 + d] = v;
}

// ---------------- M = k^T v ----------------
__global__ void kv_outer(const float* __restrict__ kn, const float* __restrict__ vh,
                         float* __restrict__ M) {
    __shared__ float vs[256][32];
    const int bh = blockIdx.x;
    const float* kp = kn + (size_t)bh * 256 * 32;
    const float* vp = vh + (size_t)bh * 256 * 32;
    const int tid = threadIdx.y * 32 + threadIdx.x;
    for (int t = tid; t < 256 * 32; t += 1024) vs[t >> 5][t & 31] = vp[t];
    __syncthreads();
    const int e = threadIdx.x, dd = threadIdx.y;
    float acc = 0.f;
    for (int j = 0; j < 256; ++j) acc += kp[j * 32 + e] * vs[j][dd];
    M[((size_t)bh * 32 + e) * 32 + dd] = acc;
}

// ---------------- Bv = bias @ v ----------------
__global__ void bias_v(const float* __restrict__ rel, const float* __restrict__ vh,
                       float* __restrict__ Bv) {
    const int gid = blockIdx.x * 8 + (threadIdx.x >> 5);
    const int d = threadIdx.x & 31;
    const int qb = gid % 256;
    const int h = (gid / 256) % NHEAD;
    const int b = gid / (256 * NHEAD);
    const int qy = qb >> 4, qx = qb & 15;
    const float* vp = vh + (size_t)(b * NHEAD + h) * 256 * 32;
    float acc = 0.f;
    for (int j = 0; j < 256; ++j) {
        const int ky = j >> 4, kx = j & 15;
        const float bias = rel[((qy - ky + 15) * 31 + (qx - kx + 15)) * NHEAD + h];
        acc += bias * vp[j * 32 + d];
    }
    Bv[((size_t)(b * NHEAD + h) * 256 + qb) * 32 + d] = acc;
}

// ---------------- attention out: o = (LN(q) @ M + Bv)/32 (in-place safe) ----------------
__global__ void attn_out(const float* __restrict__ q, const float* __restrict__ gq,
                         const float* __restrict__ bq, const float* __restrict__ M,
                         const float* __restrict__ Bv, float* __restrict__ o) {
    const int gid = blockIdx.x * 256 + threadIdx.x;
    const int i = gid % 4096;
    const int h = (gid / 4096) % NHEAD;
    const int b = gid / (4096 * NHEAD);
    const int y = i >> 6, x = i & 63;
    const int qb = (y >> 2) * 16 + (x >> 2);

    const float* qp = q + (size_t)b * OUTCH * 4096 + h * 4096 + i;
    float qv[32];
    float s1 = 0.f, s2 = 0.f;
#pragma unroll
    for (int d = 0; d < 32; ++d) {
        const float v = qp[(size_t)d * NHEAD * 4096];
        qv[d] = v; s1 += v; s2 += v * v;
    }
    const float m = s1 * (1.f / 32.f);
    const float var = s2 * (1.f / 32.f) - m * m;
    const float rs = rsqrtf(var + 1e-6f);
#pragma unroll
    for (int d = 0; d < 32; ++d)
        qv[d] = (qv[d] - m) * rs * gq[h * 32 + d] + bq[h * 32 + d];

    const float* Mp = M + (size_t)(b * NHEAD + h) * 32 * 32;
    const float* Bp = Bv + ((size_t)(b * NHEAD + h) * 256 + qb) * 32;
    float acc[32];
#pragma unroll
    for (int d = 0; d < 32; ++d) acc[d] = Bp[d];
#pragma unroll
    for (int e = 0; e < 32; ++e) {
        const float qe = qv[e];
#pragma unroll
        for (int d = 0; d < 32; ++d) acc[d] += qe * Mp[e * 32 + d];
    }
    float* op = o + (size_t)b * OUTCH * 4096 + h * 4096 + i;
#pragma unroll
    for (int d = 0; d < 32; ++d) op[(size_t)d * NHEAD * 4096] = acc[d] * (1.f / 32.f);
}

extern "C" void kernel_launch(void* const* d_in, const int* in_sizes, int n_in,
                              void* d_out, int out_size, void* d_ws, size_t ws_size,
                              hipStream_t stream) {
    const float* x1        = (const float*)d_in[0];
    const float* x2        = (const float*)d_in[1];
    const float* conv_ch_w = (const float*)d_in[2];
    const float* conv_ch_b = (const float*)d_in[3];
    const float* norm_l_g  = (const float*)d_in[4];
    const float* norm_l_b  = (const float*)d_in[5];
    const float* norm_h_g  = (const float*)d_in[6];
    const float* norm_h_b  = (const float*)d_in[7];
    const float* to_kv_dw  = (const float*)d_in[8];
    const float* to_kv_pw  = (const float*)d_in[9];
    const float* to_q_dw   = (const float*)d_in[10];
    const float* to_q_pw   = (const float*)d_in[11];
    const float* to_out_dw = (const float*)d_in[12];
    const float* to_out_pw = (const float*)d_in[13];
    const float* rel_table = (const float*)d_in[14];
    const float* normq_g   = (const float*)d_in[15];
    const float* normq_b   = (const float*)d_in[16];
    const float* normk_g   = (const float*)d_in[17];
    const float* normk_b   = (const float*)d_in[18];
    const float* norm2_g   = (const float*)d_in[19];
    const float* norm2_b   = (const float*)d_in[20];
    const float* mlp_w     = (const float*)d_in[21];
    float* Dout = (float*)d_out;

    float* ws = (float*)d_ws;
    const size_t NBIG = (size_t)NB_ * OUTCH * 4096;  // 8388608 floats (32 MB)
    float* RES = ws;
    float* A   = ws + NBIG;
    float* Bb  = ws + 2 * NBIG;
    float* sm  = ws + 3 * NBIG;
    float* scale1 = sm;            float* shift1 = sm + 512;
    float* scale2 = sm + 1024;     float* shift2 = sm + 1280;
    float* scale3 = sm + 1536;     float* shift3 = sm + 1792;
    float* k16 = sm + 2048;
    float* v16 = k16 + 524288;
    float* kn  = v16 + 524288;
    float* vh  = kn  + 524288;
    float* Mm  = vh  + 524288;
    float* Bv  = Mm  + 65536;
    short* Wq  = (short*)(Bv + 524288);
    short* Wo  = Wq + 65536;
    short* Wm  = Wo + 65536;
    short* Wc  = Wm + 65536;       // conv_ch_w packed: 256x512
    short* Wkv = Wc + 131072;      // to_kv_pw packed: 512x512
    float* bnpart = (float*)(Wkv + 262144);  // 8192 floats max (C=512 x 8 x 2)

    short* Xp1 = (short*)Bb;             // x1 packed: 8 MB (4M shorts)
    short* Xp2 = (short*)Bb + 4194304;   // kv_dw packed: 8 MB
    short* Xp  = (short*)Bb;             // big packed X (16 MB), used steps 8+
    float* kv  = A;                      // 16 MB fp32 [8,512,1024] (after x1c dead)

    // 0. pack the five pointwise weights to bf16 packed layout
    pack_w<<<256, 256, 0, stream>>>(to_q_pw, Wq, 256, 256);
    pack_w<<<256, 256, 0, stream>>>(to_out_pw, Wo, 256, 256);
    pack_w<<<256, 256, 0, stream>>>(mlp_w, Wm, 256, 256);
    pack_w<<<512, 256, 0, stream>>>(conv_ch_w, Wc, 256, 512);
    pack_w<<<1024, 256, 0, stream>>>(to_kv_pw, Wkv, 512, 512);

    // 1. x1 -> packed bf16; x1c = mfma(x1p, Wc) + bias -> A (fp32 [8,256,1024])
    pack_tile<0><<<dim3(4, 16, 8), 256, 0, stream>>>(x1, nullptr, nullptr, Xp1, 512, 1024);
    mfma_pw<0><<<dim3(16, 2, 8), 256, 0, stream>>>(Xp1, Wc, conv_ch_b, nullptr, A, 512, 256, 1024);
    // 2. residue = resize(x1c, 64,64) -> RES
    resize_bilinear<<<32768, 256, 0, stream>>>(A, RES, 256, 256 * 1024, 32, 32, 64, 64);
    // 3. BN stats x1 (two-phase)
    bn_stats_part<<<dim3(8, 512), 256, 0, stream>>>(x1, bnpart, 512, 1024);
    bn_finish<<<2, 256, 0, stream>>>(bnpart, norm_l_g, norm_l_b, scale1, shift1, 512, 1024, 1e-5f);
    // 4. kv_dw = dw3(BN(x1)) -> Xp2 (packed bf16)
    dw3_direct<32><<<dim3(4, 16, 8), 256, 0, stream>>>(x1, scale1, shift1, to_kv_dw, Xp2, 512, 32);
    // 5. kv = mfma(Xp2, Wkv) -> A (fp32 [8,512,1024]; x1c region dead after step 2)
    mfma_pw<0><<<dim3(16, 4, 8), 256, 0, stream>>>(Xp2, Wkv, nullptr, nullptr, kv, 512, 512, 1024);
    // 6. k16, v16 = resize to 16x16
    resize_bilinear<<<2048, 256, 0, stream>>>(kv, k16, 256, 512 * 1024, 32, 32, 16, 16);
    resize_bilinear<<<2048, 256, 0, stream>>>(kv + 256 * 1024, v16, 256, 512 * 1024, 32, 32, 16, 16);
    // 7. BN stats x2 (two-phase)
    bn_stats_part<<<dim3(8, 256), 256, 0, stream>>>(x2, bnpart, 256, 4096);
    bn_finish<<<1, 256, 0, stream>>>(bnpart, norm_h_g, norm_h_b, scale2, shift2, 256, 4096, 1e-5f);
    // 8. q_dw = dw3(BN(x2)) -> Xp (packed bf16; Xp1/Xp2 dead after step 5)
    dw3_direct<64><<<dim3(16, 8, 8), 256, 0, stream>>>(x2, scale2, shift2, to_q_dw, Xp, 256, 64);
    // 9. q = mfma(Xp, Wq) -> A (fp32 conv layout; kv dead after step 6)
    mfma_pw<0><<<dim3(64, 2, 8), 256, 0, stream>>>(Xp, Wq, nullptr, nullptr, A, 256, 256, 4096);
    // 10. kn = LN(split(k16)); vh = split(v16)
    ln_split<<<2048, 256, 0, stream>>>(k16, normk_g, normk_b, kn, 256, 1, 1e-6f);
    ln_split<<<2048, 256, 0, stream>>>(v16, nullptr, nullptr, vh, 256, 0, 0.f);
    // 11. M = k^T v
    kv_outer<<<64, dim3(32, 32), 0, stream>>>(kn, vh, Mm);
    // 12. Bv = bias @ v
    bias_v<<<2048, 256, 0, stream>>>(rel_table, vh, Bv);
    // 13. o = (LN(q) @ M + Bv)/32, in-place on A
    attn_out<<<1024, 256, 0, stream>>>(A, normq_g, normq_b, Mm, Bv, A);
    // 14. out_dw = dw3(o) -> Xp (packed bf16)
    dw3_direct<64><<<dim3(16, 8, 8), 256, 0, stream>>>(A, nullptr, nullptr, to_out_dw, Xp, 256, 64);
    // 15. o2 = mfma(Xp, Wo) + RES -> A  (res2)
    mfma_pw<1><<<dim3(64, 2, 8), 256, 0, stream>>>(Xp, Wo, nullptr, RES, A, 256, 256, 4096);
    // 16. BN stats o2 (two-phase)
    bn_stats_part<<<dim3(8, 256), 256, 0, stream>>>(A, bnpart, 256, 4096);
    bn_finish<<<1, 256, 0, stream>>>(bnpart, norm2_g, norm2_b, scale3, shift3, 256, 4096, 1e-5f);
    // 17. r = relu(BN(o2)) -> Xp (packed bf16)
    pack_tile<1><<<dim3(16, 8, 8), 256, 0, stream>>>(A, scale3, shift3, Xp, 256, 4096);
    // 18. out = mfma(Xp, Wm) + res2(A) -> d_out
    mfma_pw<1><<<dim3(64, 2, 8), 256, 0, stream>>>(Xp, Wm, nullptr, A, Dout, 256, 256, 4096);
}

// Round 9
// 347.028 us; speedup vs baseline: 2.7828x; 1.1117x over previous
//
#include <hip/hip_runtime.h>
#include <math.h>

#define NB_   8
#define INCH  512
#define OUTCH 256
#define NHEAD 8
#define DHEAD 32

typedef __attribute__((ext_vector_type(8))) short short8v;
typedef __attribute__((ext_vector_type(4))) short short4v;
typedef __attribute__((ext_vector_type(4))) float f32x4;

__device__ inline short f2bf(float f) {
    unsigned u = __float_as_uint(f);
    unsigned r = u + 0x7FFFu + ((u >> 16) & 1u);
    return (short)(r >> 16);
}

// ---------------- pack fp32 weight [Co][Ci] -> bf16 packed-k layout ----------------
// packed pos within 32-k tile: (q = (k%16)/4, h = k/16, r = k%4) -> q*8 + h*4 + r
__global__ void pack_w(const float* __restrict__ W, short* __restrict__ Wp, int Co, int Ci) {
    const int idx = blockIdx.x * 256 + threadIdx.x;
    if (idx >= Co * Ci) return;
    const int m = idx / Ci, i = idx % Ci;
    const int kt = i >> 5, w32 = i & 31;
    const int h = w32 >> 4, q = (w32 & 15) >> 2, r = w32 & 3;
    Wp[m * Ci + kt * 32 + q * 8 + h * 4 + r] = f2bf(W[idx]);
}

// ---------------- LDS-staged pack: fp32 [B][C][P] -> packed bf16 [B][P][C] ----------------
// optional BN(scale/shift) + ReLU at staging. grid: (P/256, C/32, B)
template <int BN_RELU>
__global__ __launch_bounds__(256, 4)
void pack_tile(const float* __restrict__ in, const float* __restrict__ scale,
               const float* __restrict__ shift, short* __restrict__ outp, int C, int P) {
    __shared__ float s[32][256];
    const int tid = threadIdx.x;
    const int p0 = blockIdx.x * 256;
    const int kt = blockIdx.y;
    const int b  = blockIdx.z;
#pragma unroll
    for (int c = 0; c < 32; ++c) {
        const int gc = kt * 32 + c;
        float v = in[((size_t)b * C + gc) * P + p0 + tid];
        if (BN_RELU) {
            v = v * scale[gc] + shift[gc];
            v = v > 0.f ? v : 0.f;
        }
        s[c][tid] = v;
    }
    __syncthreads();
    short* op = outp + ((size_t)b * P + p0 + tid) * C + kt * 32;
#pragma unroll
    for (int q = 0; q < 4; ++q) {
        short8v v;
#pragma unroll
        for (int h = 0; h < 2; ++h)
#pragma unroll
            for (int r = 0; r < 4; ++r)
                v[h * 4 + r] = f2bf(s[h * 16 + q * 4 + r][tid]);
        *reinterpret_cast<short8v*>(op + q * 8) = v;
    }
}

// ---------------- direct (optional BN) + depthwise 3x3 -> packed bf16 ----------------
// thread = 8 consecutive x-pixels of one row x 4 channels; register window, L2 serves reuse.
// LDS only for output transpose (packed 64B stores). grid: (H/RT, C/32, B)
template <int W_>
__global__ __launch_bounds__(256, 4)
void dw3_direct(const float* __restrict__ in, const float* __restrict__ scale,
                const float* __restrict__ shift, const float* __restrict__ dw,
                short* __restrict__ outp, int C, int H) {
    constexpr int XG = W_ / 8;    // x-groups per row
    constexpr int RT = 256 / W_;  // rows per block tile
    __shared__ __align__(16) short so[256][40];
    const int tid = threadIdx.x;
    const int cg  = tid & 7;       // channel group of 4
    const int pxg = tid >> 3;      // 0..31 (8-px group)
    const int row = pxg / XG;
    const int xg  = pxg % XG;
    const int x0  = xg * 8;
    const int y   = blockIdx.x * RT + row;
    const int kt  = blockIdx.y;
    const int b   = blockIdx.z;
    const int P   = H * W_;

    float acc[4][8];
#pragma unroll
    for (int r = 0; r < 4; ++r)
#pragma unroll
        for (int j = 0; j < 8; ++j) acc[r][j] = 0.f;

#pragma unroll
    for (int r = 0; r < 4; ++r) {
        const int gc = kt * 32 + cg * 4 + r;
        const float sc = scale ? scale[gc] : 1.f;
        const float sh = scale ? shift[gc] : 0.f;
        const float* wp = dw + gc * 9;
#pragma unroll
        for (int dy = 0; dy < 3; ++dy) {
            const int gy = y - 1 + dy;
            if (gy < 0 || gy >= H) continue;
            const float* bp = in + ((size_t)b * C + gc) * P + gy * W_;
            float w[10];
            w[0] = (x0 > 0) ? bp[x0 - 1] : 0.f;
            const float4 m0 = *reinterpret_cast<const float4*>(bp + x0);
            const float4 m1 = *reinterpret_cast<const float4*>(bp + x0 + 4);
            w[1] = m0.x; w[2] = m0.y; w[3] = m0.z; w[4] = m0.w;
            w[5] = m1.x; w[6] = m1.y; w[7] = m1.z; w[8] = m1.w;
            w[9] = (x0 + 8 < W_) ? bp[x0 + 8] : 0.f;
            if (scale) {
#pragma unroll
                for (int t = 0; t < 10; ++t) w[t] = w[t] * sc + sh;
                if (x0 == 0) w[0] = 0.f;          // zero-pad is pre-BN zero
                if (x0 + 8 >= W_) w[9] = 0.f;
            }
            const float t0 = wp[dy * 3 + 0], t1 = wp[dy * 3 + 1], t2 = wp[dy * 3 + 2];
#pragma unroll
            for (int j = 0; j < 8; ++j)
                acc[r][j] += t0 * w[j] + t1 * w[j + 1] + t2 * w[j + 2];
        }
    }

    // packed-k position for this thread's 4 channels (contiguous in r)
    const int posb = (cg & 3) * 8 + (cg >> 2) * 4;
#pragma unroll
    for (int j = 0; j < 8; ++j) {
        short4v v;
#pragma unroll
        for (int r = 0; r < 4; ++r) v[r] = f2bf(acc[r][j]);
        *reinterpret_cast<short4v*>(&so[pxg * 8 + j][posb]) = v;
    }
    __syncthreads();
    short* op = outp + ((size_t)b * P + blockIdx.x * 256 + tid) * C + kt * 32;
#pragma unroll
    for (int q = 0; q < 4; ++q)
        *reinterpret_cast<short8v*>(op + q * 8) = *reinterpret_cast<const short8v*>(&so[tid][q * 8]);
}

// ---------------- MFMA bf16 pointwise conv (GEMM): out[b,m,p] = sum_i W[m,i] X[b,i,p] ----------------
// Xp: [B][P][Ci] bf16 packed-k; Wp: [Co][Ci] bf16 packed-k.
// BM=128, BN=64, BK=32; 4 waves (2x2), wave tile 64x32.
template <int HAS_RES>
__global__ __launch_bounds__(256, 4)
void mfma_pw(const short* __restrict__ Xp, const short* __restrict__ Wp,
             const float* __restrict__ bias, const float* __restrict__ res,
             float* __restrict__ out, int Ci, int Co, int P) {
    __shared__ short Ash[4096];  // [q(4)][m(128)] 16B chunks = 8KB
    __shared__ short Bsh[2048];  // [q(4)][n(64)]  16B chunks = 4KB
    const int b   = blockIdx.z;
    const int m0  = blockIdx.y * 128;
    const int n0  = blockIdx.x * 64;
    const int tid = threadIdx.x;
    const int lane = tid & 63;
    const int wid  = tid >> 6;
    const int wr = wid >> 1, wc = wid & 1;
    const int ql = lane >> 4, l16 = lane & 15;

    f32x4 acc[4][2];
#pragma unroll
    for (int mb = 0; mb < 4; ++mb)
#pragma unroll
        for (int nb = 0; nb < 2; ++nb) acc[mb][nb] = (f32x4){0.f, 0.f, 0.f, 0.f};

    const int sm_ = tid & 127;  // A stage: m
    const int sq_ = tid >> 7;   // A stage: q sub
    const int bn_ = tid & 63;   // B stage: n
    const int bq_ = tid >> 6;   // B stage: q

    const size_t wrow = (size_t)(m0 + sm_) * Ci;
    const size_t xrow = ((size_t)b * P + n0 + bn_) * Ci;

    const int nkt = Ci >> 5;
    for (int kt = 0; kt < nkt; ++kt) {
        const int kof = kt * 32;
#pragma unroll
        for (int r = 0; r < 2; ++r) {
            const int q = r * 2 + sq_;
            __builtin_amdgcn_global_load_lds(Wp + wrow + kof + q * 8, &Ash[r * 2048 + tid * 8], 16, 0, 0);
        }
        __builtin_amdgcn_global_load_lds(Xp + xrow + kof + bq_ * 8, &Bsh[tid * 8], 16, 0, 0);
        __syncthreads();

        short8v a[4], bf[2];
#pragma unroll
        for (int mb = 0; mb < 4; ++mb)
            a[mb] = *reinterpret_cast<const short8v*>(&Ash[ql * 1024 + (wr * 64 + mb * 16 + l16) * 8]);
#pragma unroll
        for (int nb = 0; nb < 2; ++nb)
            bf[nb] = *reinterpret_cast<const short8v*>(&Bsh[ql * 512 + (wc * 32 + nb * 16 + l16) * 8]);
#pragma unroll
        for (int mb = 0; mb < 4; ++mb)
#pragma unroll
            for (int nb = 0; nb < 2; ++nb)
                acc[mb][nb] = __builtin_amdgcn_mfma_f32_16x16x32_bf16(a[mb], bf[nb], acc[mb][nb], 0, 0, 0);
        __syncthreads();
    }

#pragma unroll
    for (int mb = 0; mb < 4; ++mb) {
        const int row = m0 + wr * 64 + mb * 16 + ql * 4;
#pragma unroll
        for (int nb = 0; nb < 2; ++nb) {
            const int col = n0 + wc * 32 + nb * 16 + l16;
            const size_t base = ((size_t)b * Co + row) * P + col;
#pragma unroll
            for (int j = 0; j < 4; ++j) {
                float v = acc[mb][nb][j];
                if (bias) v += bias[row + j];
                if (HAS_RES) v += res[base + (size_t)j * P];
                out[base + (size_t)j * P] = v;
            }
        }
    }
}

// ---------------- bilinear resize (compile-time dims; all pow2) ----------------
template <int C, int Hi, int Wi, int Ho, int Wo>
__global__ void resize_bilinear(const float* __restrict__ in, float* __restrict__ out, int ibs) {
    const int idx = blockIdx.x * 256 + threadIdx.x;
    const int x = idx & (Wo - 1);
    const int y = (idx / Wo) & (Ho - 1);
    const int c = (idx / (Wo * Ho)) & (C - 1);
    const int b = idx / (Wo * Ho * C);
    const float fy = (float)y * (float)(Hi - 1) / (float)(Ho - 1);
    const float fx = (float)x * (float)(Wi - 1) / (float)(Wo - 1);
    int y0 = (int)floorf(fy); int y1 = min(y0 + 1, Hi - 1); const float wy = fy - (float)y0;
    int x0 = (int)floorf(fx); int x1 = min(x0 + 1, Wi - 1); const float wx = fx - (float)x0;
    const float* pc = in + (size_t)b * ibs + (size_t)c * Hi * Wi;
    const float r0 = pc[y0 * Wi + x0] * (1.f - wx) + pc[y0 * Wi + x1] * wx;
    const float r1 = pc[y1 * Wi + x0] * (1.f - wx) + pc[y1 * Wi + x1] * wx;
    out[idx] = r0 * (1.f - wy) + r1 * wy;
}

// ---------------- BN stats, two-phase ----------------
// phase 1: one block per (b,c) plane -> per-plane (sum, sumsq). grid (B, C)
__global__ __launch_bounds__(256, 8)
void bn_stats_part(const float* __restrict__ in, float* __restrict__ part, int C, int HW) {
    const int b = blockIdx.x;
    const int c = blockIdx.y;
    const float* p = in + ((size_t)b * C + c) * HW;
    float s1 = 0.f, s2 = 0.f;
    for (int i = threadIdx.x * 4; i < HW; i += 1024) {
        const float4 v = *reinterpret_cast<const float4*>(p + i);
        s1 += v.x + v.y + v.z + v.w;
        s2 += v.x * v.x + v.y * v.y + v.z * v.z + v.w * v.w;
    }
#pragma unroll
    for (int o = 32; o >= 1; o >>= 1) {
        s1 += __shfl_xor(s1, o);
        s2 += __shfl_xor(s2, o);
    }
    __shared__ float sh1[4], sh2[4];
    if ((threadIdx.x & 63) == 0) { sh1[threadIdx.x >> 6] = s1; sh2[threadIdx.x >> 6] = s2; }
    __syncthreads();
    if (threadIdx.x == 0) {
        part[((size_t)c * gridDim.x + b) * 2 + 0] = sh1[0] + sh1[1] + sh1[2] + sh1[3];
        part[((size_t)c * gridDim.x + b) * 2 + 1] = sh2[0] + sh2[1] + sh2[2] + sh2[3];
    }
}

// phase 2: per-channel scale/shift from partials
__global__ void bn_finish(const float* __restrict__ part, const float* __restrict__ g,
                          const float* __restrict__ bt, float* __restrict__ scale,
                          float* __restrict__ shift, int C, int HW, float eps) {
    const int c = blockIdx.x * 256 + threadIdx.x;
    if (c >= C) return;
    float s1 = 0.f, s2 = 0.f;
#pragma unroll
    for (int b = 0; b < NB_; ++b) {
        s1 += part[((size_t)c * NB_ + b) * 2 + 0];
        s2 += part[((size_t)c * NB_ + b) * 2 + 1];
    }
    const float invN = 1.f / (float)(NB_ * HW);
    const float m = s1 * invN;
    const float var = s2 * invN - m * m;
    const float sc = g[c] * rsqrtf(var + eps);
    scale[c] = sc;
    shift[c] = bt[c] - m * sc;
}

// ---------------- LN (optional) + split heads ----------------
__global__ void ln_split(const float* __restrict__ in, const float* __restrict__ g,
                         const float* __restrict__ bt, float* __restrict__ out,
                         int HW, int applyLN, float eps) {
    const int row = blockIdx.x * 8 + (threadIdx.x >> 5);
    const int d = threadIdx.x & 31;
    const int j = row % HW;
    const int h = (row / HW) % NHEAD;
    const int b = row / (HW * NHEAD);
    float v = in[((size_t)b * OUTCH + d * NHEAD + h) * HW + j];
    if (applyLN) {
        float s1 = v, s2 = v * v;
#pragma unroll
        for (int o = 16; o >= 1; o >>= 1) {
            s1 += __shfl_xor(s1, o, 32);
            s2 += __shfl_xor(s2, o, 32);
        }
        const float m = s1 * (1.f / 32.f);
        const float var = s2 * (1.f / 32.f) - m * m;
        v = (v - m) * rsqrtf(var + eps) * g[h * 32 + d] + bt[h * 32 + d];
    }
    out[((size_t)(b * NHEAD + h) * HW + j) * 32 + d] = v;
}

// ---------------- M = k^T v ----------------
__global__ void kv_outer(const float* __restrict__ kn, const float* __restrict__ vh,
                         float* __restrict__ M) {
    __shared__ float vs[256][32];
    const int bh = blockIdx.x;
    const float* kp = kn + (size_t)bh * 256 * 32;
    const float* vp = vh + (size_t)bh * 256 * 32;
    const int tid = threadIdx.y * 32 + threadIdx.x;
    for (int t = tid; t < 256 * 32; t += 1024) vs[t >> 5][t & 31] = vp[t];
    __syncthreads();
    const int e = threadIdx.x, dd = threadIdx.y;
    float acc = 0.f;
    for (int j = 0; j < 256; ++j) acc += kp[j * 32 + e] * vs[j][dd];
    M[((size_t)bh * 32 + e) * 32 + dd] = acc;
}

// ---------------- Bv = bias @ v ----------------
__global__ void bias_v(const float* __restrict__ rel, const float* __restrict__ vh,
                       float* __restrict__ Bv) {
    const int gid = blockIdx.x * 8 + (threadIdx.x >> 5);
    const int d = threadIdx.x & 31;
    const int qb = gid % 256;
    const int h = (gid / 256) % NHEAD;
    const int b = gid / (256 * NHEAD);
    const int qy = qb >> 4, qx = qb & 15;
    const float* vp = vh + (size_t)(b * NHEAD + h) * 256 * 32;
    float acc = 0.f;
    for (int j = 0; j < 256; ++j) {
        const int ky = j >> 4, kx = j & 15;
        const float bias = rel[((qy - ky + 15) * 31 + (qx - kx + 15)) * NHEAD + h];
        acc += bias * vp[j * 32 + d];
    }
    Bv[((size_t)(b * NHEAD + h) * 256 + qb) * 32 + d] = acc;
}

// ---------------- attention out: o = (LN(q) @ M + Bv)/32, 2 px/thread, SGPR-M ----------------
__global__ __launch_bounds__(256, 2)
void attn_out(const float* __restrict__ q, const float* __restrict__ gq,
              const float* __restrict__ bq, const float* __restrict__ M,
              const float* __restrict__ Bv, float* __restrict__ o) {
    const int gid = blockIdx.x * 256 + threadIdx.x;   // 131072 threads
    const int ip = (gid & 2047) * 2;                  // pixel pair
    const int h  = (gid >> 11) & 7;
    const int b  = gid >> 14;

    // wave-uniform M pointer -> scalar loads + SGPR-operand FMAs
    const float* Mp = M + ((size_t)(b * NHEAD + h) << 10);
    {
        uint64_t a = (uint64_t)Mp;
        uint32_t lo = __builtin_amdgcn_readfirstlane((uint32_t)a);
        uint32_t hi = __builtin_amdgcn_readfirstlane((uint32_t)(a >> 32));
        Mp = (const float*)((((uint64_t)hi) << 32) | lo);
    }

    const float* qp = q + (size_t)b * OUTCH * 4096 + h * 4096 + ip;
    float q0[32], q1[32];
    float a1 = 0.f, a2 = 0.f, b1 = 0.f, b2 = 0.f;
#pragma unroll
    for (int d = 0; d < 32; ++d) {
        const float2 v = *reinterpret_cast<const float2*>(qp + (size_t)d * NHEAD * 4096);
        q0[d] = v.x; q1[d] = v.y;
        a1 += v.x; a2 += v.x * v.x;
        b1 += v.y; b2 += v.y * v.y;
    }
    {
        const float m0 = a1 * (1.f / 32.f);
        const float r0 = rsqrtf(a2 * (1.f / 32.f) - m0 * m0 + 1e-6f);
        const float m1 = b1 * (1.f / 32.f);
        const float r1 = rsqrtf(b2 * (1.f / 32.f) - m1 * m1 + 1e-6f);
#pragma unroll
        for (int d = 0; d < 32; ++d) {
            const float gg = gq[h * 32 + d], bb = bq[h * 32 + d];
            q0[d] = (q0[d] - m0) * r0 * gg + bb;
            q1[d] = (q1[d] - m1) * r1 * gg + bb;
        }
    }

    const int y = ip >> 6, x = ip & 63;
    const int qb0 = (y >> 2) * 16 + (x >> 2);
    const int qb1 = (y >> 2) * 16 + ((x + 1) >> 2);
    const float* Bp0 = Bv + (((size_t)(b * NHEAD + h) * 256 + qb0) << 5);
    const float* Bp1 = Bv + (((size_t)(b * NHEAD + h) * 256 + qb1) << 5);
    float acc0[32], acc1[32];
#pragma unroll
    for (int t = 0; t < 8; ++t) {
        const float4 v0 = *reinterpret_cast<const float4*>(Bp0 + t * 4);
        const float4 v1 = *reinterpret_cast<const float4*>(Bp1 + t * 4);
        acc0[t * 4 + 0] = v0.x; acc0[t * 4 + 1] = v0.y; acc0[t * 4 + 2] = v0.z; acc0[t * 4 + 3] = v0.w;
        acc1[t * 4 + 0] = v1.x; acc1[t * 4 + 1] = v1.y; acc1[t * 4 + 2] = v1.z; acc1[t * 4 + 3] = v1.w;
    }

    for (int e = 0; e < 32; ++e) {
        const float qe0 = q0[e], qe1 = q1[e];
#pragma unroll
        for (int d = 0; d < 32; ++d) {
            const float m = Mp[e * 32 + d];
            acc0[d] += qe0 * m;
            acc1[d] += qe1 * m;
        }
    }

    float* op = o + (size_t)b * OUTCH * 4096 + h * 4096 + ip;
#pragma unroll
    for (int d = 0; d < 32; ++d) {
        float2 v;
        v.x = acc0[d] * (1.f / 32.f);
        v.y = acc1[d] * (1.f / 32.f);
        *reinterpret_cast<float2*>(op + (size_t)d * NHEAD * 4096) = v;
    }
}

extern "C" void kernel_launch(void* const* d_in, const int* in_sizes, int n_in,
                              void* d_out, int out_size, void* d_ws, size_t ws_size,
                              hipStream_t stream) {
    const float* x1        = (const float*)d_in[0];
    const float* x2        = (const float*)d_in[1];
    const float* conv_ch_w = (const float*)d_in[2];
    const float* conv_ch_b = (const float*)d_in[3];
    const float* norm_l_g  = (const float*)d_in[4];
    const float* norm_l_b  = (const float*)d_in[5];
    const float* norm_h_g  = (const float*)d_in[6];
    const float* norm_h_b  = (const float*)d_in[7];
    const float* to_kv_dw  = (const float*)d_in[8];
    const float* to_kv_pw  = (const float*)d_in[9];
    const float* to_q_dw   = (const float*)d_in[10];
    const float* to_q_pw   = (const float*)d_in[11];
    const float* to_out_dw = (const float*)d_in[12];
    const float* to_out_pw = (const float*)d_in[13];
    const float* rel_table = (const float*)d_in[14];
    const float* normq_g   = (const float*)d_in[15];
    const float* normq_b   = (const float*)d_in[16];
    const float* normk_g   = (const float*)d_in[17];
    const float* normk_b   = (const float*)d_in[18];
    const float* norm2_g   = (const float*)d_in[19];
    const float* norm2_b   = (const float*)d_in[20];
    const float* mlp_w     = (const float*)d_in[21];
    float* Dout = (float*)d_out;

    float* ws = (float*)d_ws;
    const size_t NBIG = (size_t)NB_ * OUTCH * 4096;  // 8388608 floats (32 MB)
    float* RES = ws;
    float* A   = ws + NBIG;
    float* Bb  = ws + 2 * NBIG;
    float* sm  = ws + 3 * NBIG;
    float* scale1 = sm;            float* shift1 = sm + 512;
    float* scale2 = sm + 1024;     float* shift2 = sm + 1280;
    float* scale3 = sm + 1536;     float* shift3 = sm + 1792;
    float* k16 = sm + 2048;
    float* v16 = k16 + 524288;
    float* kn  = v16 + 524288;
    float* vh  = kn  + 524288;
    float* Mm  = vh  + 524288;
    float* Bv  = Mm  + 65536;
    short* Wq  = (short*)(Bv + 524288);
    short* Wo  = Wq + 65536;
    short* Wm  = Wo + 65536;
    short* Wc  = Wm + 65536;       // conv_ch_w packed: 256x512
    short* Wkv = Wc + 131072;      // to_kv_pw packed: 512x512
    float* bnpart = (float*)(Wkv + 262144);  // 8192 floats max (C=512 x 8 x 2)

    short* Xp1 = (short*)Bb;             // x1 packed: 8 MB (4M shorts)
    short* Xp2 = (short*)Bb + 4194304;   // kv_dw packed: 8 MB
    short* Xp  = (short*)Bb;             // big packed X (16 MB), used steps 8+
    float* kv  = A;                      // 16 MB fp32 [8,512,1024] (after x1c dead)

    // 0. pack the five pointwise weights to bf16 packed layout
    pack_w<<<256, 256, 0, stream>>>(to_q_pw, Wq, 256, 256);
    pack_w<<<256, 256, 0, stream>>>(to_out_pw, Wo, 256, 256);
    pack_w<<<256, 256, 0, stream>>>(mlp_w, Wm, 256, 256);
    pack_w<<<512, 256, 0, stream>>>(conv_ch_w, Wc, 256, 512);
    pack_w<<<1024, 256, 0, stream>>>(to_kv_pw, Wkv, 512, 512);

    // 1. x1 -> packed bf16; x1c = mfma(x1p, Wc) + bias -> A (fp32 [8,256,1024])
    pack_tile<0><<<dim3(4, 16, 8), 256, 0, stream>>>(x1, nullptr, nullptr, Xp1, 512, 1024);
    mfma_pw<0><<<dim3(16, 2, 8), 256, 0, stream>>>(Xp1, Wc, conv_ch_b, nullptr, A, 512, 256, 1024);
    // 2. residue = resize(x1c, 64,64) -> RES
    resize_bilinear<256, 32, 32, 64, 64><<<32768, 256, 0, stream>>>(A, RES, 256 * 1024);
    // 3. BN stats x1 (two-phase)
    bn_stats_part<<<dim3(8, 512), 256, 0, stream>>>(x1, bnpart, 512, 1024);
    bn_finish<<<2, 256, 0, stream>>>(bnpart, norm_l_g, norm_l_b, scale1, shift1, 512, 1024, 1e-5f);
    // 4. kv_dw = dw3(BN(x1)) -> Xp2 (packed bf16)
    dw3_direct<32><<<dim3(4, 16, 8), 256, 0, stream>>>(x1, scale1, shift1, to_kv_dw, Xp2, 512, 32);
    // 5. kv = mfma(Xp2, Wkv) -> A (fp32 [8,512,1024]; x1c region dead after step 2)
    mfma_pw<0><<<dim3(16, 4, 8), 256, 0, stream>>>(Xp2, Wkv, nullptr, nullptr, kv, 512, 512, 1024);
    // 6. k16, v16 = resize to 16x16
    resize_bilinear<256, 32, 32, 16, 16><<<2048, 256, 0, stream>>>(kv, k16, 512 * 1024);
    resize_bilinear<256, 32, 32, 16, 16><<<2048, 256, 0, stream>>>(kv + 256 * 1024, v16, 512 * 1024);
    // 7. BN stats x2 (two-phase)
    bn_stats_part<<<dim3(8, 256), 256, 0, stream>>>(x2, bnpart, 256, 4096);
    bn_finish<<<1, 256, 0, stream>>>(bnpart, norm_h_g, norm_h_b, scale2, shift2, 256, 4096, 1e-5f);
    // 8. q_dw = dw3(BN(x2)) -> Xp (packed bf16; Xp1/Xp2 dead after step 5)
    dw3_direct<64><<<dim3(16, 8, 8), 256, 0, stream>>>(x2, scale2, shift2, to_q_dw, Xp, 256, 64);
    // 9. q = mfma(Xp, Wq) -> A (fp32 conv layout; kv dead after step 6)
    mfma_pw<0><<<dim3(64, 2, 8), 256, 0, stream>>>(Xp, Wq, nullptr, nullptr, A, 256, 256, 4096);
    // 10. kn = LN(split(k16)); vh = split(v16)
    ln_split<<<2048, 256, 0, stream>>>(k16, normk_g, normk_b, kn, 256, 1, 1e-6f);
    ln_split<<<2048, 256, 0, stream>>>(v16, nullptr, nullptr, vh, 256, 0, 0.f);
    // 11. M = k^T v
    kv_outer<<<64, dim3(32, 32), 0, stream>>>(kn, vh, Mm);
    // 12. Bv = bias @ v
    bias_v<<<2048, 256, 0, stream>>>(rel_table, vh, Bv);
    // 13. o = (LN(q) @ M + Bv)/32, in-place on A (2 px/thread)
    attn_out<<<512, 256, 0, stream>>>(A, normq_g, normq_b, Mm, Bv, A);
    // 14. out_dw = dw3(o) -> Xp (packed bf16)
    dw3_direct<64><<<dim3(16, 8, 8), 256, 0, stream>>>(A, nullptr, nullptr, to_out_dw, Xp, 256, 64);
    // 15. o2 = mfma(Xp, Wo) + RES -> A  (res2)
    mfma_pw<1><<<dim3(64, 2, 8), 256, 0, stream>>>(Xp, Wo, nullptr, RES, A, 256, 256, 4096);
    // 16. BN stats o2 (two-phase)
    bn_stats_part<<<dim3(8, 256), 256, 0, stream>>>(A, bnpart, 256, 4096);
    bn_finish<<<1, 256, 0, stream>>>(bnpart, norm2_g, norm2_b, scale3, shift3, 256, 4096, 1e-5f);
    // 17. r = relu(BN(o2)) -> Xp (packed bf16)
    pack_tile<1><<<dim3(16, 8, 8), 256, 0, stream>>>(A, scale3, shift3, Xp, 256, 4096);
    // 18. out = mfma(Xp, Wm) + res2(A) -> d_out
    mfma_pw<1><<<dim3(64, 2, 8), 256, 0, stream>>>(Xp, Wm, nullptr, A, Dout, 256, 256, 4096);
}

// Round 10
// 324.217 us; speedup vs baseline: 2.9786x; 1.0704x over previous
//
#include <hip/hip_runtime.h>
#include <math.h>

#define NB_   8
#define INCH  512
#define OUTCH 256
#define NHEAD 8
#define DHEAD 32

typedef __attribute__((ext_vector_type(8))) short short8v;
typedef __attribute__((ext_vector_type(4))) short short4v;
typedef __attribute__((ext_vector_type(4))) float f32x4;

__device__ inline short f2bf(float f) {
    unsigned u = __float_as_uint(f);
    unsigned r = u + 0x7FFFu + ((u >> 16) & 1u);
    return (short)(r >> 16);
}

// ---------------- pack fp32 weight [Co][Ci] -> bf16 packed-k layout ----------------
// packed pos within 32-k tile: (q = (k%16)/4, h = k/16, r = k%4) -> q*8 + h*4 + r
__global__ void pack_w(const float* __restrict__ W, short* __restrict__ Wp, int Co, int Ci) {
    const int idx = blockIdx.x * 256 + threadIdx.x;
    if (idx >= Co * Ci) return;
    const int m = idx / Ci, i = idx % Ci;
    const int kt = i >> 5, w32 = i & 31;
    const int h = w32 >> 4, q = (w32 & 15) >> 2, r = w32 & 3;
    Wp[m * Ci + kt * 32 + q * 8 + h * 4 + r] = f2bf(W[idx]);
}

// ---------------- bias matrix: Bm[h][qb][j] packed bf16 from rel_table ----------------
__global__ void bias_mat(const float* __restrict__ rel, short* __restrict__ Bm) {
    const int idx = blockIdx.x * 256 + threadIdx.x;   // 8*256*256
    const int h  = idx >> 16;
    const int qb = (idx >> 8) & 255;
    const int pp = idx & 255;
    const int kt = pp >> 5, w = pp & 31;
    const int q = w >> 3, hh = (w >> 2) & 1, r = w & 3;
    const int j = kt * 32 + hh * 16 + q * 4 + r;
    const int qy = qb >> 4, qx = qb & 15;
    const int ky = j >> 4, kx = j & 15;
    Bm[idx] = f2bf(rel[((qy - ky + 15) * 31 + (qx - kx + 15)) * NHEAD + h]);
}

// ---------------- pack v16 (conv layout) -> Xpv[h][(b*32+d)][j packed] bf16 ----------------
// grid (8 h, 8 b), 256 threads, 4 chunks each
__global__ void pack_vT(const float* __restrict__ v16, short* __restrict__ Xpv) {
    const int h = blockIdx.x;
    const int b = blockIdx.y;
    const int tid = threadIdx.x;
#pragma unroll
    for (int cc = 0; cc < 4; ++cc) {
        const int c  = tid * 4 + cc;      // 0..1023
        const int d  = c >> 5;
        const int ck = c & 31;
        const int kt = ck >> 2, q = ck & 3;
        const float* vp = v16 + ((size_t)(b * 256 + d * NHEAD + h)) * 256;
        short8v v;
#pragma unroll
        for (int hh = 0; hh < 2; ++hh)
#pragma unroll
            for (int r = 0; r < 4; ++r)
                v[hh * 4 + r] = f2bf(vp[kt * 32 + hh * 16 + q * 4 + r]);
        *reinterpret_cast<short8v*>(&Xpv[(size_t)h * 65536 + (b * 32 + d) * 256 + kt * 32 + q * 8]) = v;
    }
}

// ---------------- LDS-staged pack: fp32 [B][C][P] -> packed bf16 [B][P][C] ----------------
// optional BN(scale/shift) + ReLU at staging. grid: (P/256, C/32, B)
template <int BN_RELU>
__global__ __launch_bounds__(256, 4)
void pack_tile(const float* __restrict__ in, const float* __restrict__ scale,
               const float* __restrict__ shift, short* __restrict__ outp, int C, int P) {
    __shared__ float s[32][256];
    const int tid = threadIdx.x;
    const int p0 = blockIdx.x * 256;
    const int kt = blockIdx.y;
    const int b  = blockIdx.z;
#pragma unroll
    for (int c = 0; c < 32; ++c) {
        const int gc = kt * 32 + c;
        float v = in[((size_t)b * C + gc) * P + p0 + tid];
        if (BN_RELU) {
            v = v * scale[gc] + shift[gc];
            v = v > 0.f ? v : 0.f;
        }
        s[c][tid] = v;
    }
    __syncthreads();
    short* op = outp + ((size_t)b * P + p0 + tid) * C + kt * 32;
#pragma unroll
    for (int q = 0; q < 4; ++q) {
        short8v v;
#pragma unroll
        for (int h = 0; h < 2; ++h)
#pragma unroll
            for (int r = 0; r < 4; ++r)
                v[h * 4 + r] = f2bf(s[h * 16 + q * 4 + r][tid]);
        *reinterpret_cast<short8v*>(op + q * 8) = v;
    }
}

// ---------------- direct (optional BN) + depthwise 3x3 -> packed bf16 ----------------
template <int W_>
__global__ __launch_bounds__(256, 4)
void dw3_direct(const float* __restrict__ in, const float* __restrict__ scale,
                const float* __restrict__ shift, const float* __restrict__ dw,
                short* __restrict__ outp, int C, int H) {
    constexpr int XG = W_ / 8;
    constexpr int RT = 256 / W_;
    __shared__ __align__(16) short so[256][40];
    const int tid = threadIdx.x;
    const int cg  = tid & 7;
    const int pxg = tid >> 3;
    const int row = pxg / XG;
    const int xg  = pxg % XG;
    const int x0  = xg * 8;
    const int y   = blockIdx.x * RT + row;
    const int kt  = blockIdx.y;
    const int b   = blockIdx.z;
    const int P   = H * W_;

    float acc[4][8];
#pragma unroll
    for (int r = 0; r < 4; ++r)
#pragma unroll
        for (int j = 0; j < 8; ++j) acc[r][j] = 0.f;

#pragma unroll
    for (int r = 0; r < 4; ++r) {
        const int gc = kt * 32 + cg * 4 + r;
        const float sc = scale ? scale[gc] : 1.f;
        const float sh = scale ? shift[gc] : 0.f;
        const float* wp = dw + gc * 9;
#pragma unroll
        for (int dy = 0; dy < 3; ++dy) {
            const int gy = y - 1 + dy;
            if (gy < 0 || gy >= H) continue;
            const float* bp = in + ((size_t)b * C + gc) * P + gy * W_;
            float w[10];
            w[0] = (x0 > 0) ? bp[x0 - 1] : 0.f;
            const float4 m0 = *reinterpret_cast<const float4*>(bp + x0);
            const float4 m1 = *reinterpret_cast<const float4*>(bp + x0 + 4);
            w[1] = m0.x; w[2] = m0.y; w[3] = m0.z; w[4] = m0.w;
            w[5] = m1.x; w[6] = m1.y; w[7] = m1.z; w[8] = m1.w;
            w[9] = (x0 + 8 < W_) ? bp[x0 + 8] : 0.f;
            if (scale) {
#pragma unroll
                for (int t = 0; t < 10; ++t) w[t] = w[t] * sc + sh;
                if (x0 == 0) w[0] = 0.f;
                if (x0 + 8 >= W_) w[9] = 0.f;
            }
            const float t0 = wp[dy * 3 + 0], t1 = wp[dy * 3 + 1], t2 = wp[dy * 3 + 2];
#pragma unroll
            for (int j = 0; j < 8; ++j)
                acc[r][j] += t0 * w[j] + t1 * w[j + 1] + t2 * w[j + 2];
        }
    }

    const int posb = (cg & 3) * 8 + (cg >> 2) * 4;
#pragma unroll
    for (int j = 0; j < 8; ++j) {
        short4v v;
#pragma unroll
        for (int r = 0; r < 4; ++r) v[r] = f2bf(acc[r][j]);
        *reinterpret_cast<short4v*>(&so[pxg * 8 + j][posb]) = v;
    }
    __syncthreads();
    short* op = outp + ((size_t)b * P + blockIdx.x * 256 + tid) * C + kt * 32;
#pragma unroll
    for (int q = 0; q < 4; ++q)
        *reinterpret_cast<short8v*>(op + q * 8) = *reinterpret_cast<const short8v*>(&so[tid][q * 8]);
}

// ---------------- MFMA bf16 pointwise conv (GEMM): out[b,m,p] = sum_i W[m,i] X[b,i,p] ----------------
// BATCH_W: W also offsets by blockIdx.z (per-batch weight matrix)
template <int HAS_RES, int BATCH_W>
__global__ __launch_bounds__(256, 4)
void mfma_pw(const short* __restrict__ Xp, const short* __restrict__ Wp,
             const float* __restrict__ bias, const float* __restrict__ res,
             float* __restrict__ out, int Ci, int Co, int P) {
    __shared__ short Ash[4096];
    __shared__ short Bsh[2048];
    const int b   = blockIdx.z;
    const int m0  = blockIdx.y * 128;
    const int n0  = blockIdx.x * 64;
    const int tid = threadIdx.x;
    const int lane = tid & 63;
    const int wid  = tid >> 6;
    const int wr = wid >> 1, wc = wid & 1;
    const int ql = lane >> 4, l16 = lane & 15;

    f32x4 acc[4][2];
#pragma unroll
    for (int mb = 0; mb < 4; ++mb)
#pragma unroll
        for (int nb = 0; nb < 2; ++nb) acc[mb][nb] = (f32x4){0.f, 0.f, 0.f, 0.f};

    const int sm_ = tid & 127;
    const int sq_ = tid >> 7;
    const int bn_ = tid & 63;
    const int bq_ = tid >> 6;

    const size_t wrow = (size_t)(m0 + sm_) * Ci + (BATCH_W ? (size_t)b * Co * Ci : 0);
    const size_t xrow = ((size_t)b * P + n0 + bn_) * Ci;

    const int nkt = Ci >> 5;
    for (int kt = 0; kt < nkt; ++kt) {
        const int kof = kt * 32;
#pragma unroll
        for (int r = 0; r < 2; ++r) {
            const int q = r * 2 + sq_;
            __builtin_amdgcn_global_load_lds(Wp + wrow + kof + q * 8, &Ash[r * 2048 + tid * 8], 16, 0, 0);
        }
        __builtin_amdgcn_global_load_lds(Xp + xrow + kof + bq_ * 8, &Bsh[tid * 8], 16, 0, 0);
        __syncthreads();

        short8v a[4], bf[2];
#pragma unroll
        for (int mb = 0; mb < 4; ++mb)
            a[mb] = *reinterpret_cast<const short8v*>(&Ash[ql * 1024 + (wr * 64 + mb * 16 + l16) * 8]);
#pragma unroll
        for (int nb = 0; nb < 2; ++nb)
            bf[nb] = *reinterpret_cast<const short8v*>(&Bsh[ql * 512 + (wc * 32 + nb * 16 + l16) * 8]);
#pragma unroll
        for (int mb = 0; mb < 4; ++mb)
#pragma unroll
            for (int nb = 0; nb < 2; ++nb)
                acc[mb][nb] = __builtin_amdgcn_mfma_f32_16x16x32_bf16(a[mb], bf[nb], acc[mb][nb], 0, 0, 0);
        __syncthreads();
    }

#pragma unroll
    for (int mb = 0; mb < 4; ++mb) {
        const int row = m0 + wr * 64 + mb * 16 + ql * 4;
#pragma unroll
        for (int nb = 0; nb < 2; ++nb) {
            const int col = n0 + wc * 32 + nb * 16 + l16;
            const size_t base = ((size_t)b * Co + row) * P + col;
#pragma unroll
            for (int j = 0; j < 4; ++j) {
                float v = acc[mb][nb][j];
                if (bias) v += bias[row + j];
                if (HAS_RES) v += res[base + (size_t)j * P];
                out[base + (size_t)j * P] = v;
            }
        }
    }
}

// ---------------- bilinear resize (compile-time dims; all pow2) ----------------
template <int C, int Hi, int Wi, int Ho, int Wo>
__global__ void resize_bilinear(const float* __restrict__ in, float* __restrict__ out, int ibs) {
    const int idx = blockIdx.x * 256 + threadIdx.x;
    const int x = idx & (Wo - 1);
    const int y = (idx / Wo) & (Ho - 1);
    const int c = (idx / (Wo * Ho)) & (C - 1);
    const int b = idx / (Wo * Ho * C);
    const float fy = (float)y * (float)(Hi - 1) / (float)(Ho - 1);
    const float fx = (float)x * (float)(Wi - 1) / (float)(Wo - 1);
    int y0 = (int)floorf(fy); int y1 = min(y0 + 1, Hi - 1); const float wy = fy - (float)y0;
    int x0 = (int)floorf(fx); int x1 = min(x0 + 1, Wi - 1); const float wx = fx - (float)x0;
    const float* pc = in + (size_t)b * ibs + (size_t)c * Hi * Wi;
    const float r0 = pc[y0 * Wi + x0] * (1.f - wx) + pc[y0 * Wi + x1] * wx;
    const float r1 = pc[y1 * Wi + x0] * (1.f - wx) + pc[y1 * Wi + x1] * wx;
    out[idx] = r0 * (1.f - wy) + r1 * wy;
}

// ---------------- BN stats, two-phase ----------------
__global__ __launch_bounds__(256, 8)
void bn_stats_part(const float* __restrict__ in, float* __restrict__ part, int C, int HW) {
    const int b = blockIdx.x;
    const int c = blockIdx.y;
    const float* p = in + ((size_t)b * C + c) * HW;
    float s1 = 0.f, s2 = 0.f;
    for (int i = threadIdx.x * 4; i < HW; i += 1024) {
        const float4 v = *reinterpret_cast<const float4*>(p + i);
        s1 += v.x + v.y + v.z + v.w;
        s2 += v.x * v.x + v.y * v.y + v.z * v.z + v.w * v.w;
    }
#pragma unroll
    for (int o = 32; o >= 1; o >>= 1) {
        s1 += __shfl_xor(s1, o);
        s2 += __shfl_xor(s2, o);
    }
    __shared__ float sh1[4], sh2[4];
    if ((threadIdx.x & 63) == 0) { sh1[threadIdx.x >> 6] = s1; sh2[threadIdx.x >> 6] = s2; }
    __syncthreads();
    if (threadIdx.x == 0) {
        part[((size_t)c * gridDim.x + b) * 2 + 0] = sh1[0] + sh1[1] + sh1[2] + sh1[3];
        part[((size_t)c * gridDim.x + b) * 2 + 1] = sh2[0] + sh2[1] + sh2[2] + sh2[3];
    }
}

__global__ void bn_finish(const float* __restrict__ part, const float* __restrict__ g,
                          const float* __restrict__ bt, float* __restrict__ scale,
                          float* __restrict__ shift, int C, int HW, float eps) {
    const int c = blockIdx.x * 256 + threadIdx.x;
    if (c >= C) return;
    float s1 = 0.f, s2 = 0.f;
#pragma unroll
    for (int b = 0; b < NB_; ++b) {
        s1 += part[((size_t)c * NB_ + b) * 2 + 0];
        s2 += part[((size_t)c * NB_ + b) * 2 + 1];
    }
    const float invN = 1.f / (float)(NB_ * HW);
    const float m = s1 * invN;
    const float var = s2 * invN - m * m;
    const float sc = g[c] * rsqrtf(var + eps);
    scale[c] = sc;
    shift[c] = bt[c] - m * sc;
}

// ---------------- LN (optional) + split heads ----------------
__global__ void ln_split(const float* __restrict__ in, const float* __restrict__ g,
                         const float* __restrict__ bt, float* __restrict__ out,
                         int HW, int applyLN, float eps) {
    const int row = blockIdx.x * 8 + (threadIdx.x >> 5);
    const int d = threadIdx.x & 31;
    const int j = row % HW;
    const int h = (row / HW) % NHEAD;
    const int b = row / (HW * NHEAD);
    float v = in[((size_t)b * OUTCH + d * NHEAD + h) * HW + j];
    if (applyLN) {
        float s1 = v, s2 = v * v;
#pragma unroll
        for (int o = 16; o >= 1; o >>= 1) {
            s1 += __shfl_xor(s1, o, 32);
            s2 += __shfl_xor(s2, o, 32);
        }
        const float m = s1 * (1.f / 32.f);
        const float var = s2 * (1.f / 32.f) - m * m;
        v = (v - m) * rsqrtf(var + eps) * g[h * 32 + d] + bt[h * 32 + d];
    }
    out[((size_t)(b * NHEAD + h) * HW + j) * 32 + d] = v;
}

// ---------------- M = k^T v ----------------
__global__ void kv_outer(const float* __restrict__ kn, const float* __restrict__ vh,
                         float* __restrict__ M) {
    __shared__ float vs[256][32];
    const int bh = blockIdx.x;
    const float* kp = kn + (size_t)bh * 256 * 32;
    const float* vp = vh + (size_t)bh * 256 * 32;
    const int tid = threadIdx.y * 32 + threadIdx.x;
    for (int t = tid; t < 256 * 32; t += 1024) vs[t >> 5][t & 31] = vp[t];
    __syncthreads();
    const int e = threadIdx.x, dd = threadIdx.y;
    float acc = 0.f;
    for (int j = 0; j < 256; ++j) acc += kp[j * 32 + e] * vs[j][dd];
    M[((size_t)bh * 32 + e) * 32 + dd] = acc;
}

// ---------------- attention out: o = (LN(q) @ M + Bv)/32, 2 px/thread, SGPR-M ----------------
// Bv2 layout: [h][qb][b*32+d]
__global__ __launch_bounds__(256, 2)
void attn_out(const float* __restrict__ q, const float* __restrict__ gq,
              const float* __restrict__ bq, const float* __restrict__ M,
              const float* __restrict__ Bv, float* __restrict__ o) {
    const int gid = blockIdx.x * 256 + threadIdx.x;
    const int ip = (gid & 2047) * 2;
    const int h  = (gid >> 11) & 7;
    const int b  = gid >> 14;

    const float* Mp = M + ((size_t)(b * NHEAD + h) << 10);
    {
        uint64_t a = (uint64_t)Mp;
        uint32_t lo = __builtin_amdgcn_readfirstlane((uint32_t)a);
        uint32_t hi = __builtin_amdgcn_readfirstlane((uint32_t)(a >> 32));
        Mp = (const float*)((((uint64_t)hi) << 32) | lo);
    }

    const float* qp = q + (size_t)b * OUTCH * 4096 + h * 4096 + ip;
    float q0[32], q1[32];
    float a1 = 0.f, a2 = 0.f, b1 = 0.f, b2 = 0.f;
#pragma unroll
    for (int d = 0; d < 32; ++d) {
        const float2 v = *reinterpret_cast<const float2*>(qp + (size_t)d * NHEAD * 4096);
        q0[d] = v.x; q1[d] = v.y;
        a1 += v.x; a2 += v.x * v.x;
        b1 += v.y; b2 += v.y * v.y;
    }
    {
        const float m0 = a1 * (1.f / 32.f);
        const float r0 = rsqrtf(a2 * (1.f / 32.f) - m0 * m0 + 1e-6f);
        const float m1 = b1 * (1.f / 32.f);
        const float r1 = rsqrtf(b2 * (1.f / 32.f) - m1 * m1 + 1e-6f);
#pragma unroll
        for (int d = 0; d < 32; ++d) {
            const float gg = gq[h * 32 + d], bb = bq[h * 32 + d];
            q0[d] = (q0[d] - m0) * r0 * gg + bb;
            q1[d] = (q1[d] - m1) * r1 * gg + bb;
        }
    }

    const int y = ip >> 6, x = ip & 63;
    const int qb0 = (y >> 2) * 16 + (x >> 2);
    const int qb1 = (y >> 2) * 16 + ((x + 1) >> 2);
    const float* Bp0 = Bv + ((size_t)h * 256 + qb0) * 256 + b * 32;
    const float* Bp1 = Bv + ((size_t)h * 256 + qb1) * 256 + b * 32;
    float acc0[32], acc1[32];
#pragma unroll
    for (int t = 0; t < 8; ++t) {
        const float4 v0 = *reinterpret_cast<const float4*>(Bp0 + t * 4);
        const float4 v1 = *reinterpret_cast<const float4*>(Bp1 + t * 4);
        acc0[t * 4 + 0] = v0.x; acc0[t * 4 + 1] = v0.y; acc0[t * 4 + 2] = v0.z; acc0[t * 4 + 3] = v0.w;
        acc1[t * 4 + 0] = v1.x; acc1[t * 4 + 1] = v1.y; acc1[t * 4 + 2] = v1.z; acc1[t * 4 + 3] = v1.w;
    }

    for (int e = 0; e < 32; ++e) {
        const float qe0 = q0[e], qe1 = q1[e];
#pragma unroll
        for (int d = 0; d < 32; ++d) {
            const float m = Mp[e * 32 + d];
            acc0[d] += qe0 * m;
            acc1[d] += qe1 * m;
        }
    }

    float* op = o + (size_t)b * OUTCH * 4096 + h * 4096 + ip;
#pragma unroll
    for (int d = 0; d < 32; ++d) {
        float2 v;
        v.x = acc0[d] * (1.f / 32.f);
        v.y = acc1[d] * (1.f / 32.f);
        *reinterpret_cast<float2*>(op + (size_t)d * NHEAD * 4096) = v;
    }
}

extern "C" void kernel_launch(void* const* d_in, const int* in_sizes, int n_in,
                              void* d_out, int out_size, void* d_ws, size_t ws_size,
                              hipStream_t stream) {
    const float* x1        = (const float*)d_in[0];
    const float* x2        = (const float*)d_in[1];
    const float* conv_ch_w = (const float*)d_in[2];
    const float* conv_ch_b = (const float*)d_in[3];
    const float* norm_l_g  = (const float*)d_in[4];
    const float* norm_l_b  = (const float*)d_in[5];
    const float* norm_h_g  = (const float*)d_in[6];
    const float* norm_h_b  = (const float*)d_in[7];
    const float* to_kv_dw  = (const float*)d_in[8];
    const float* to_kv_pw  = (const float*)d_in[9];
    const float* to_q_dw   = (const float*)d_in[10];
    const float* to_q_pw   = (const float*)d_in[11];
    const float* to_out_dw = (const float*)d_in[12];
    const float* to_out_pw = (const float*)d_in[13];
    const float* rel_table = (const float*)d_in[14];
    const float* normq_g   = (const float*)d_in[15];
    const float* normq_b   = (const float*)d_in[16];
    const float* normk_g   = (const float*)d_in[17];
    const float* normk_b   = (const float*)d_in[18];
    const float* norm2_g   = (const float*)d_in[19];
    const float* norm2_b   = (const float*)d_in[20];
    const float* mlp_w     = (const float*)d_in[21];
    float* Dout = (float*)d_out;

    float* ws = (float*)d_ws;
    const size_t NBIG = (size_t)NB_ * OUTCH * 4096;  // 8388608 floats (32 MB)
    float* RES = ws;
    float* A   = ws + NBIG;
    float* Bb  = ws + 2 * NBIG;
    float* sm  = ws + 3 * NBIG;
    float* scale1 = sm;            float* shift1 = sm + 512;
    float* scale2 = sm + 1024;     float* shift2 = sm + 1280;
    float* scale3 = sm + 1536;     float* shift3 = sm + 1792;
    float* k16 = sm + 2048;
    float* v16 = k16 + 524288;
    float* kn  = v16 + 524288;
    float* vh  = kn  + 524288;
    float* Mm  = vh  + 524288;
    float* Bv  = Mm  + 65536;      // now Bv2: [h][qb][b*32+d], 524288 floats
    short* Wq  = (short*)(Bv + 524288);
    short* Wo  = Wq + 65536;
    short* Wm  = Wo + 65536;
    short* Wc  = Wm + 65536;       // conv_ch_w packed: 256x512
    short* Wkv = Wc + 131072;      // to_kv_pw packed: 512x512
    float* bnpart = (float*)(Wkv + 262144);  // 8192 floats max

    short* Xp1 = (short*)Bb;             // x1 packed: 8 MB
    short* Xp2 = (short*)Bb + 4194304;   // kv_dw packed: 8 MB
    short* Xp  = (short*)Bb;             // big packed X (16 MB), steps 8+
    short* Bmp = (short*)Bb + 8388608;   // bias matrices: 1 MB (upper half of Bb, always free)
    short* Xpv = Bmp + 524288;           // packed v^T: 1 MB
    float* kv  = A;                      // 16 MB fp32 [8,512,1024]

    // 0. pack weights + bias matrix
    pack_w<<<256, 256, 0, stream>>>(to_q_pw, Wq, 256, 256);
    pack_w<<<256, 256, 0, stream>>>(to_out_pw, Wo, 256, 256);
    pack_w<<<256, 256, 0, stream>>>(mlp_w, Wm, 256, 256);
    pack_w<<<512, 256, 0, stream>>>(conv_ch_w, Wc, 256, 512);
    pack_w<<<1024, 256, 0, stream>>>(to_kv_pw, Wkv, 512, 512);
    bias_mat<<<2048, 256, 0, stream>>>(rel_table, Bmp);

    // 1. x1 -> packed bf16; x1c = mfma(x1p, Wc) + bias -> A (fp32 [8,256,1024])
    pack_tile<0><<<dim3(4, 16, 8), 256, 0, stream>>>(x1, nullptr, nullptr, Xp1, 512, 1024);
    mfma_pw<0, 0><<<dim3(16, 2, 8), 256, 0, stream>>>(Xp1, Wc, conv_ch_b, nullptr, A, 512, 256, 1024);
    // 2. residue = resize(x1c, 64,64) -> RES
    resize_bilinear<256, 32, 32, 64, 64><<<32768, 256, 0, stream>>>(A, RES, 256 * 1024);
    // 3. BN stats x1 (two-phase)
    bn_stats_part<<<dim3(8, 512), 256, 0, stream>>>(x1, bnpart, 512, 1024);
    bn_finish<<<2, 256, 0, stream>>>(bnpart, norm_l_g, norm_l_b, scale1, shift1, 512, 1024, 1e-5f);
    // 4. kv_dw = dw3(BN(x1)) -> Xp2 (packed bf16)
    dw3_direct<32><<<dim3(4, 16, 8), 256, 0, stream>>>(x1, scale1, shift1, to_kv_dw, Xp2, 512, 32);
    // 5. kv = mfma(Xp2, Wkv) -> A
    mfma_pw<0, 0><<<dim3(16, 4, 8), 256, 0, stream>>>(Xp2, Wkv, nullptr, nullptr, kv, 512, 512, 1024);
    // 6. k16, v16 = resize to 16x16
    resize_bilinear<256, 32, 32, 16, 16><<<2048, 256, 0, stream>>>(kv, k16, 512 * 1024);
    resize_bilinear<256, 32, 32, 16, 16><<<2048, 256, 0, stream>>>(kv + 256 * 1024, v16, 512 * 1024);
    // 7. BN stats x2 (two-phase)
    bn_stats_part<<<dim3(8, 256), 256, 0, stream>>>(x2, bnpart, 256, 4096);
    bn_finish<<<1, 256, 0, stream>>>(bnpart, norm_h_g, norm_h_b, scale2, shift2, 256, 4096, 1e-5f);
    // 8. q_dw = dw3(BN(x2)) -> Xp (packed bf16)
    dw3_direct<64><<<dim3(16, 8, 8), 256, 0, stream>>>(x2, scale2, shift2, to_q_dw, Xp, 256, 64);
    // 9. q = mfma(Xp, Wq) -> A
    mfma_pw<0, 0><<<dim3(64, 2, 8), 256, 0, stream>>>(Xp, Wq, nullptr, nullptr, A, 256, 256, 4096);
    // 10. kn = LN(split(k16)); vh = split(v16); Xpv = packed v^T
    ln_split<<<2048, 256, 0, stream>>>(k16, normk_g, normk_b, kn, 256, 1, 1e-6f);
    ln_split<<<2048, 256, 0, stream>>>(v16, nullptr, nullptr, vh, 256, 0, 0.f);
    pack_vT<<<dim3(8, 8), 256, 0, stream>>>(v16, Xpv);
    // 11. M = k^T v
    kv_outer<<<64, dim3(32, 32), 0, stream>>>(kn, vh, Mm);
    // 12. Bv2[h][qb][b*32+d] = bias_h @ V_h  (batched MFMA GEMM)
    mfma_pw<0, 1><<<dim3(4, 2, 8), 256, 0, stream>>>(Xpv, Bmp, nullptr, nullptr, Bv, 256, 256, 256);
    // 13. o = (LN(q) @ M + Bv)/32, in-place on A
    attn_out<<<512, 256, 0, stream>>>(A, normq_g, normq_b, Mm, Bv, A);
    // 14. out_dw = dw3(o) -> Xp (packed bf16)
    dw3_direct<64><<<dim3(16, 8, 8), 256, 0, stream>>>(A, nullptr, nullptr, to_out_dw, Xp, 256, 64);
    // 15. o2 = mfma(Xp, Wo) + RES -> A  (res2)
    mfma_pw<1, 0><<<dim3(64, 2, 8), 256, 0, stream>>>(Xp, Wo, nullptr, RES, A, 256, 256, 4096);
    // 16. BN stats o2 (two-phase)
    bn_stats_part<<<dim3(8, 256), 256, 0, stream>>>(A, bnpart, 256, 4096);
    bn_finish<<<1, 256, 0, stream>>>(bnpart, norm2_g, norm2_b, scale3, shift3, 256, 4096, 1e-5f);
    // 17. r = relu(BN(o2)) -> Xp (packed bf16)
    pack_tile<1><<<dim3(16, 8, 8), 256, 0, stream>>>(A, scale3, shift3, Xp, 256, 4096);
    // 18. out = mfma(Xp, Wm) + res2(A) -> d_out
    mfma_pw<1, 0><<<dim3(64, 2, 8), 256, 0, stream>>>(Xp, Wm, nullptr, A, Dout, 256, 256, 4096);
}